// Round 1
// baseline (1010.282 us; speedup 1.0000x reference)
//
#include <hip/hip_runtime.h>
#include <hip/hip_fp16.h>
#include <math.h>

#define BB 4
#define NN 4096
#define DMM 768
#define HHH 12
#define LHH 4
#define GHH 8
#define DH 64
#define MM 256
#define WW 128
#define NWIN (NN/WW)
#define EPSF 1.0e-4f
#define NRM 0.35355339059327373f   /* 64^-0.25 */
#define NRM2 0.125f                /* 64^-0.5  */
#define RATIO 0.0625f              /* 256^-0.5 */
#define LN1E4_32 0.28782313662425572f  /* ln(10000)/32 */

using bf16x8 = __attribute__((ext_vector_type(8))) short;
using fp16x8 = __attribute__((ext_vector_type(8))) _Float16;
using f32x4  = __attribute__((ext_vector_type(4))) float;

static __device__ __forceinline__ unsigned enc_f32(float f) {
  unsigned u = __float_as_uint(f);
  return (u & 0x80000000u) ? ~u : (u | 0x80000000u);
}
static __device__ __forceinline__ float dec_f32(unsigned u) {
  unsigned b = (u & 0x80000000u) ? (u ^ 0x80000000u) : ~u;
  return __uint_as_float(b);
}
static __device__ __forceinline__ unsigned short f2h(float x) {
  return __half_as_ushort(__float2half(x));
}

/* ------- W prep: transpose to [n][k] and split into bf16 hi/lo planes ----- */
__global__ __launch_bounds__(256) void w_split(
    const float* __restrict__ W, unsigned short* __restrict__ Whi,
    unsigned short* __restrict__ Wlo)
{
  int o = blockIdx.x * 256 + threadIdx.x;     /* 768*768 */
  int k = o / DMM, n = o % DMM;
  float x = W[o];
  unsigned u = __float_as_uint(x);
  unsigned h = u & 0xFFFF0000u;
  float lf = x - __uint_as_float(h);
  Whi[(size_t)n * DMM + k] = (unsigned short)(u >> 16);
  Wlo[(size_t)n * DMM + k] = (unsigned short)(__float_as_uint(lf) >> 16);
}

/* ------- activation prep: split fp32 [M][K] into bf16 hi/lo planes -------- */
__global__ __launch_bounds__(256) void a_split(
    const float* __restrict__ A, unsigned short* __restrict__ Ahi,
    unsigned short* __restrict__ Alo)
{
  size_t o = ((size_t)blockIdx.x * 256 + threadIdx.x) * 4;
  float4 v = *(const float4*)(A + o);
  float f[4] = {v.x, v.y, v.z, v.w};
  unsigned short hi[4], lo[4];
#pragma unroll
  for (int i = 0; i < 4; ++i) {
    unsigned u = __float_as_uint(f[i]);
    unsigned h = u & 0xFFFF0000u;
    float l = f[i] - __uint_as_float(h);
    hi[i] = (unsigned short)(u >> 16);
    lo[i] = (unsigned short)(__float_as_uint(l) >> 16);
  }
  *(uint2*)(Ahi + o) = *(uint2*)&hi[0];
  *(uint2*)(Alo + o) = *(uint2*)&lo[0];
}

/* ------- split-bf16 MFMA GEMM: C = A(fp32 MxK) @ W(from hi/lo NxK) + bias --
 * fallback path: converts A tiles in-kernel (used only if ws too small).    */
__global__ __launch_bounds__(256) void gemm_mfma(
    const float* __restrict__ A,
    const unsigned short* __restrict__ Bhi, const unsigned short* __restrict__ Blo,
    const float* __restrict__ bias, float* __restrict__ C, int K, int Nc)
{
  __shared__ unsigned short Ah[128][40];
  __shared__ unsigned short Al[128][40];
  __shared__ unsigned short Bh[128][40];
  __shared__ unsigned short Bl[128][40];

  const int tid = threadIdx.x;
  const int wid = tid >> 6, lane = tid & 63;
  const int quad = lane >> 4, l16 = lane & 15;
  const int row0 = blockIdx.y * 128;
  const int col0 = blockIdx.x * 128;
  const int wm = (wid & 1) * 64, wn = (wid >> 1) * 64;
  const int sr = tid >> 1;
  const int sk = (tid & 1) * 16;

  f32x4 acc[4][4];
  const f32x4 zf = {0.f, 0.f, 0.f, 0.f};
#pragma unroll
  for (int i = 0; i < 4; ++i)
#pragma unroll
    for (int j = 0; j < 4; ++j) acc[i][j] = zf;

  for (int k0 = 0; k0 < K; k0 += 32) {
    __syncthreads();
    {
      const float* a = A + (size_t)(row0 + sr) * K + k0 + sk;
      float fv[16];
      *(float4*)&fv[0]  = *(const float4*)(a);
      *(float4*)&fv[4]  = *(const float4*)(a + 4);
      *(float4*)&fv[8]  = *(const float4*)(a + 8);
      *(float4*)&fv[12] = *(const float4*)(a + 12);
      unsigned hw[8], lw[8];
#pragma unroll
      for (int p = 0; p < 8; ++p) {
        float x0 = fv[2 * p], x1 = fv[2 * p + 1];
        unsigned u0 = __float_as_uint(x0), u1 = __float_as_uint(x1);
        unsigned h0 = u0 & 0xFFFF0000u, h1 = u1 & 0xFFFF0000u;
        float l0 = x0 - __uint_as_float(h0);
        float l1 = x1 - __uint_as_float(h1);
        hw[p] = (u0 >> 16) | h1;
        lw[p] = (__float_as_uint(l0) >> 16) | (__float_as_uint(l1) & 0xFFFF0000u);
      }
      *(uint4*)&Ah[sr][sk]     = *(uint4*)&hw[0];
      *(uint4*)&Ah[sr][sk + 8] = *(uint4*)&hw[4];
      *(uint4*)&Al[sr][sk]     = *(uint4*)&lw[0];
      *(uint4*)&Al[sr][sk + 8] = *(uint4*)&lw[4];
    }
    {
      const unsigned short* bh = Bhi + (size_t)(col0 + sr) * DMM + k0 + sk;
      const unsigned short* bl = Blo + (size_t)(col0 + sr) * DMM + k0 + sk;
      *(uint4*)&Bh[sr][sk]     = *(const uint4*)(bh);
      *(uint4*)&Bh[sr][sk + 8] = *(const uint4*)(bh + 8);
      *(uint4*)&Bl[sr][sk]     = *(const uint4*)(bl);
      *(uint4*)&Bl[sr][sk + 8] = *(const uint4*)(bl + 8);
    }
    __syncthreads();

    bf16x8 afh[4], afl[4], bfh[4], bfl[4];
#pragma unroll
    for (int t = 0; t < 4; ++t) {
      afh[t] = *(const bf16x8*)&Ah[wm + t * 16 + l16][quad * 8];
      afl[t] = *(const bf16x8*)&Al[wm + t * 16 + l16][quad * 8];
      bfh[t] = *(const bf16x8*)&Bh[wn + t * 16 + l16][quad * 8];
      bfl[t] = *(const bf16x8*)&Bl[wn + t * 16 + l16][quad * 8];
    }
#pragma unroll
    for (int ti = 0; ti < 4; ++ti)
#pragma unroll
      for (int tj = 0; tj < 4; ++tj) {
        acc[ti][tj] = __builtin_amdgcn_mfma_f32_16x16x32_bf16(afh[ti], bfh[tj], acc[ti][tj], 0, 0, 0);
        acc[ti][tj] = __builtin_amdgcn_mfma_f32_16x16x32_bf16(afh[ti], bfl[tj], acc[ti][tj], 0, 0, 0);
        acc[ti][tj] = __builtin_amdgcn_mfma_f32_16x16x32_bf16(afl[ti], bfh[tj], acc[ti][tj], 0, 0, 0);
      }
  }

  float bv[4] = {0.f, 0.f, 0.f, 0.f};
  if (bias) {
#pragma unroll
    for (int tj = 0; tj < 4; ++tj) bv[tj] = bias[col0 + wn + tj * 16 + l16];
  }
#pragma unroll
  for (int ti = 0; ti < 4; ++ti) {
    const int gr = row0 + wm + ti * 16 + quad * 4;
#pragma unroll
    for (int tj = 0; tj < 4; ++tj) {
      const int gc = col0 + wn + tj * 16 + l16;
      float* cp = C + (size_t)gr * Nc + gc;
#pragma unroll
      for (int r = 0; r < 4; ++r)
        cp[(size_t)r * Nc] = acc[ti][tj][r] + bv[tj];
    }
  }
}

/* ------- split-bf16 MFMA GEMM, pre-split A planes (hot path) --------------- */
__global__ __launch_bounds__(256) void gemm_mfma_pre(
    const unsigned short* __restrict__ Ahi, const unsigned short* __restrict__ Alo,
    const unsigned short* __restrict__ Bhi, const unsigned short* __restrict__ Blo,
    const float* __restrict__ bias, float* __restrict__ C, int K, int Nc)
{
  __shared__ unsigned short Ah[128][40];
  __shared__ unsigned short Al[128][40];
  __shared__ unsigned short Bh[128][40];
  __shared__ unsigned short Bl[128][40];

  const int tid = threadIdx.x;
  const int wid = tid >> 6, lane = tid & 63;
  const int quad = lane >> 4, l16 = lane & 15;
  const int row0 = blockIdx.y * 128;
  const int col0 = blockIdx.x * 128;
  const int wm = (wid & 1) * 64, wn = (wid >> 1) * 64;
  const int sr = tid >> 1;
  const int sk = (tid & 1) * 16;

  f32x4 acc[4][4];
  const f32x4 zf = {0.f, 0.f, 0.f, 0.f};
#pragma unroll
  for (int i = 0; i < 4; ++i)
#pragma unroll
    for (int j = 0; j < 4; ++j) acc[i][j] = zf;

  for (int k0 = 0; k0 < K; k0 += 32) {
    __syncthreads();
    {
      const unsigned short* ah = Ahi + (size_t)(row0 + sr) * K + k0 + sk;
      const unsigned short* al = Alo + (size_t)(row0 + sr) * K + k0 + sk;
      *(uint4*)&Ah[sr][sk]     = *(const uint4*)(ah);
      *(uint4*)&Ah[sr][sk + 8] = *(const uint4*)(ah + 8);
      *(uint4*)&Al[sr][sk]     = *(const uint4*)(al);
      *(uint4*)&Al[sr][sk + 8] = *(const uint4*)(al + 8);
      const unsigned short* bh = Bhi + (size_t)(col0 + sr) * K + k0 + sk;
      const unsigned short* bl = Blo + (size_t)(col0 + sr) * K + k0 + sk;
      *(uint4*)&Bh[sr][sk]     = *(const uint4*)(bh);
      *(uint4*)&Bh[sr][sk + 8] = *(const uint4*)(bh + 8);
      *(uint4*)&Bl[sr][sk]     = *(const uint4*)(bl);
      *(uint4*)&Bl[sr][sk + 8] = *(const uint4*)(bl + 8);
    }
    __syncthreads();

    bf16x8 afh[4], afl[4], bfh[4], bfl[4];
#pragma unroll
    for (int t = 0; t < 4; ++t) {
      afh[t] = *(const bf16x8*)&Ah[wm + t * 16 + l16][quad * 8];
      afl[t] = *(const bf16x8*)&Al[wm + t * 16 + l16][quad * 8];
      bfh[t] = *(const bf16x8*)&Bh[wn + t * 16 + l16][quad * 8];
      bfl[t] = *(const bf16x8*)&Bl[wn + t * 16 + l16][quad * 8];
    }
#pragma unroll
    for (int ti = 0; ti < 4; ++ti)
#pragma unroll
      for (int tj = 0; tj < 4; ++tj) {
        acc[ti][tj] = __builtin_amdgcn_mfma_f32_16x16x32_bf16(afh[ti], bfh[tj], acc[ti][tj], 0, 0, 0);
        acc[ti][tj] = __builtin_amdgcn_mfma_f32_16x16x32_bf16(afh[ti], bfl[tj], acc[ti][tj], 0, 0, 0);
        acc[ti][tj] = __builtin_amdgcn_mfma_f32_16x16x32_bf16(afl[ti], bfh[tj], acc[ti][tj], 0, 0, 0);
      }
  }

  float bv[4] = {0.f, 0.f, 0.f, 0.f};
  if (bias) {
#pragma unroll
    for (int tj = 0; tj < 4; ++tj) bv[tj] = bias[col0 + wn + tj * 16 + l16];
  }
#pragma unroll
  for (int ti = 0; ti < 4; ++ti) {
    const int gr = row0 + wm + ti * 16 + quad * 4;
#pragma unroll
    for (int tj = 0; tj < 4; ++tj) {
      const int gc = col0 + wn + tj * 16 + l16;
      float* cp = C + (size_t)gr * Nc + gc;
#pragma unroll
      for (int r = 0; r < 4; ++r)
        cp[(size_t)r * Nc] = acc[ti][tj][r] + bv[tj];
    }
  }
}

/* ---------------- init global stabilizer ---------------------------------- */
__global__ void init_stab(unsigned* stab_enc) {
  if (threadIdx.x == 0 && blockIdx.x == 0) *stab_enc = 0x00800000u; /* enc(-FLT_MAX) */
}

/* ---------------- transpose proj (64 KB, once per launch) ------------------ */
__global__ __launch_bounds__(256) void transpose_proj(
    const float* __restrict__ proj, float* __restrict__ projT)
{
  int o = blockIdx.x * 256 + threadIdx.x;   /* 16384 */
  int k = o >> 8, m = o & 255;
  projT[k * 256 + m] = proj[m * 64 + k];
}

/* ---------------- rotary prep for local heads: Q(scaled)/K -> fp16 --------- */
__global__ __launch_bounds__(256) void rot_qk(
    const float* __restrict__ Qb, const float* __restrict__ Kb,
    unsigned short* __restrict__ Qlh, unsigned short* __restrict__ Klh)
{
  int idx = blockIdx.x * 256 + threadIdx.x;    /* (b*LHH+h)*NN + n : 65536 */
  int n = idx & (NN - 1);
  int bh = idx >> 12;
  int b = bh >> 2, h = bh & 3;
  const float* qs = Qb + ((size_t)(b * NN + n)) * DMM + GHH * DH + h * DH;
  const float* ks = Kb + ((size_t)(b * NN + n)) * DMM + GHH * DH + h * DH;
  float q[64], k[64];
#pragma unroll
  for (int t = 0; t < 16; ++t) {
    *(float4*)&q[t * 4] = *(const float4*)(qs + t * 4);
    *(float4*)&k[t * 4] = *(const float4*)(ks + t * 4);
  }
  unsigned short qo[64], ko[64];
#pragma unroll
  for (int i = 0; i < 32; ++i) {
    float invf = __expf((float)i * -LN1E4_32);
    float th = (float)n * invf;
    float s, c;
    sincosf(th, &s, &c);
    qo[i]      = f2h(fmaf(q[i], c, -q[i + 32] * s) * NRM2);
    qo[i + 32] = f2h(fmaf(q[i + 32], c, q[i] * s) * NRM2);
    ko[i]      = f2h(fmaf(k[i], c, -k[i + 32] * s));
    ko[i + 32] = f2h(fmaf(k[i + 32], c, k[i] * s));
  }
  unsigned short* qd = Qlh + (size_t)idx * 64;
  unsigned short* kd = Klh + (size_t)idx * 64;
#pragma unroll
  for (int t = 0; t < 8; ++t) {
    *(uint4*)(qd + t * 8) = *(uint4*)&qo[t * 8];
    *(uint4*)(kd + t * 8) = *(uint4*)&ko[t * 8];
  }
}

/* ---------------- V transpose for local heads: fp16 [b][h][d][n] ----------- */
__global__ __launch_bounds__(256) void v_trans(
    const float* __restrict__ Vb, unsigned short* __restrict__ Vt)
{
  __shared__ unsigned short T[64][72];
  const int nb = blockIdx.x, h = blockIdx.y, b = blockIdx.z;
  const int n0 = nb * 64;
  const int tid = threadIdx.x;
  {
    int r = tid >> 2, g = tid & 3;
    const float* src = Vb + ((size_t)(b * NN + n0 + r)) * DMM + GHH * DH + h * DH + g * 16;
#pragma unroll
    for (int t = 0; t < 4; ++t) {
      float4 v = *(const float4*)(src + t * 4);
      T[g * 16 + t * 4 + 0][r] = f2h(v.x);
      T[g * 16 + t * 4 + 1][r] = f2h(v.y);
      T[g * 16 + t * 4 + 2][r] = f2h(v.z);
      T[g * 16 + t * 4 + 3][r] = f2h(v.w);
    }
  }
  __syncthreads();
  {
    int d = tid >> 2, g = tid & 3;
    unsigned short* dst = Vt + ((size_t)(b * LHH + h) * DH + d) * NN + n0 + g * 16;
    *(uint4*)dst       = *(uint4*)&T[d][g * 16];
    *(uint4*)(dst + 8) = *(uint4*)&T[d][g * 16 + 8];
  }
}

/* ---------------- local attention via f16 MFMA (flash-style) --------------- */
__global__ __launch_bounds__(256) void local_attn2(
    const unsigned short* __restrict__ Qlh, const unsigned short* __restrict__ Klh,
    const unsigned short* __restrict__ Vt, float* __restrict__ Qb)
{
  __shared__ unsigned short Pl[4][32][72];
  const int w = blockIdx.x, h = blockIdx.y, b = blockIdx.z;
  const int tid = threadIdx.x;
  const int wid = tid >> 6, lane = tid & 63;
  const int quad = lane >> 4, l16 = lane & 15;
  const int bh = b * LHH + h;
  const int qn0 = w * WW + wid * 32;

  fp16x8 Aq[2][2];
#pragma unroll
  for (int mt = 0; mt < 2; ++mt)
#pragma unroll
    for (int ks = 0; ks < 2; ++ks)
      Aq[mt][ks] = *(const fp16x8*)(Qlh + ((size_t)bh * NN + qn0 + mt * 16 + l16) * 64 + ks * 32 + quad * 8);

  float m_run[8], l_run[8];
  f32x4 Oacc[2][4];
  const f32x4 zf = {0.f, 0.f, 0.f, 0.f};
#pragma unroll
  for (int r = 0; r < 8; ++r) { m_run[r] = -3.4e38f; l_run[r] = 0.f; }
#pragma unroll
  for (int mt = 0; mt < 2; ++mt)
#pragma unroll
    for (int nt = 0; nt < 4; ++nt) Oacc[mt][nt] = zf;

  const int wb_lo = (w == 0) ? 0 : w - 1;
  const int wb_hi = (w == NWIN - 1) ? w : w + 1;
  for (int wb = wb_lo; wb <= wb_hi; ++wb) {
    for (int half = 0; half < 2; ++half) {
      const int kn0 = wb * WW + half * 64;
      f32x4 sacc[2][4];
#pragma unroll
      for (int mt = 0; mt < 2; ++mt)
#pragma unroll
        for (int nt = 0; nt < 4; ++nt) sacc[mt][nt] = zf;

#pragma unroll
      for (int ks = 0; ks < 2; ++ks) {
        fp16x8 Bk[4];
#pragma unroll
        for (int nt = 0; nt < 4; ++nt)
          Bk[nt] = *(const fp16x8*)(Klh + ((size_t)bh * NN + kn0 + nt * 16 + l16) * 64 + ks * 32 + quad * 8);
#pragma unroll
        for (int mt = 0; mt < 2; ++mt)
#pragma unroll
          for (int nt = 0; nt < 4; ++nt)
            sacc[mt][nt] = __builtin_amdgcn_mfma_f32_16x16x32_f16(Aq[mt][ks], Bk[nt], sacc[mt][nt], 0, 0, 0);
      }

      /* online softmax per row (row = mt*16 + quad*4 + reg) */
#pragma unroll
      for (int mt = 0; mt < 2; ++mt) {
#pragma unroll
        for (int reg = 0; reg < 4; ++reg) {
          const int r8 = mt * 4 + reg;
          float v = fmaxf(fmaxf(sacc[mt][0][reg], sacc[mt][1][reg]),
                          fmaxf(sacc[mt][2][reg], sacc[mt][3][reg]));
          v = fmaxf(v, __shfl_xor(v, 1));
          v = fmaxf(v, __shfl_xor(v, 2));
          v = fmaxf(v, __shfl_xor(v, 4));
          v = fmaxf(v, __shfl_xor(v, 8));
          float mnew = fmaxf(m_run[r8], v);
          float alpha = __expf(m_run[r8] - mnew);
          m_run[r8] = mnew;
          float ps = 0.f;
#pragma unroll
          for (int nt = 0; nt < 4; ++nt) {
            float p = __expf(sacc[mt][nt][reg] - mnew);
            sacc[mt][nt][reg] = p;
            ps += p;
          }
          ps += __shfl_xor(ps, 1);
          ps += __shfl_xor(ps, 2);
          ps += __shfl_xor(ps, 4);
          ps += __shfl_xor(ps, 8);
          l_run[r8] = l_run[r8] * alpha + ps;
#pragma unroll
          for (int nt = 0; nt < 4; ++nt) Oacc[mt][nt][reg] *= alpha;
        }
      }

      /* write P fp16 (C-layout -> [qrow][key] in LDS, wave-local) */
#pragma unroll
      for (int mt = 0; mt < 2; ++mt)
#pragma unroll
        for (int nt = 0; nt < 4; ++nt)
#pragma unroll
          for (int reg = 0; reg < 4; ++reg)
            Pl[wid][mt * 16 + quad * 4 + reg][nt * 16 + l16] = f2h(sacc[mt][nt][reg]);

      /* PV */
#pragma unroll
      for (int kstep = 0; kstep < 2; ++kstep) {
        fp16x8 Ap[2];
#pragma unroll
        for (int mt = 0; mt < 2; ++mt)
          Ap[mt] = *(const fp16x8*)&Pl[wid][mt * 16 + l16][kstep * 32 + quad * 8];
        fp16x8 Bv[4];
#pragma unroll
        for (int nt = 0; nt < 4; ++nt)
          Bv[nt] = *(const fp16x8*)(Vt + ((size_t)bh * DH + nt * 16 + l16) * NN + kn0 + kstep * 32 + quad * 8);
#pragma unroll
        for (int mt = 0; mt < 2; ++mt)
#pragma unroll
          for (int nt = 0; nt < 4; ++nt)
            Oacc[mt][nt] = __builtin_amdgcn_mfma_f32_16x16x32_f16(Ap[mt], Bv[nt], Oacc[mt][nt], 0, 0, 0);
      }
    }
  }

  /* epilogue: divide by l, store fp32 into Qb local-head columns */
#pragma unroll
  for (int mt = 0; mt < 2; ++mt)
#pragma unroll
    for (int reg = 0; reg < 4; ++reg) {
      const float inv = 1.0f / l_run[mt * 4 + reg];
      const int n = qn0 + mt * 16 + quad * 4 + reg;
      float* dst = Qb + ((size_t)(b * NN + n)) * DMM + GHH * DH + h * DH;
#pragma unroll
      for (int nt = 0; nt < 4; ++nt)
        dst[nt * 16 + l16] = Oacc[mt][nt][reg] * inv;
    }
}

/* ---------------- FAVOR: global max of dd_k (GEMM-tiled) ------------------- */
__global__ __launch_bounds__(256) void favor_kstab2(
    const float* __restrict__ Kg, const float* __restrict__ projT,
    unsigned* __restrict__ stab_enc)
{
  __shared__ __half Kt[64][72];
  __shared__ float Ps[8][256];
  __shared__ float wred[4];
  const int tid = threadIdx.x;
  const int wid = tid >> 6, lane = tid & 63;
  const int ry = lane >> 3, rx = lane & 7;
  const int chunk = blockIdx.x & 63;
  const int bh = blockIdx.x >> 6;
  const int b = bh >> 3, h = bh & 7;
  const int n0 = chunk * 64;

  {
    const int r = tid >> 2, s2 = tid & 3;
    const float* ksrc = Kg + ((size_t)(b * NN + n0 + r)) * DMM + h * DH + s2 * 16;
#pragma unroll
    for (int t4 = 0; t4 < 4; ++t4) {
      float4 kv = *(const float4*)(ksrc + t4 * 4);
      Kt[s2 * 16 + t4 * 4 + 0][r] = __float2half(kv.x * NRM);
      Kt[s2 * 16 + t4 * 4 + 1][r] = __float2half(kv.y * NRM);
      Kt[s2 * 16 + t4 * 4 + 2][r] = __float2half(kv.z * NRM);
      Kt[s2 * 16 + t4 * 4 + 3][r] = __float2half(kv.w * NRM);
    }
  }
  __syncthreads();

  float dacc[8][8] = {};
  for (int kc = 0; kc < 8; ++kc) {
    if (kc) __syncthreads();
    {
      const int kk = tid >> 5, cc = (tid & 31) * 8;
      const float* pt = projT + (size_t)(kc * 8 + kk) * 256 + cc;
      *(float4*)&Ps[kk][cc] = *(const float4*)pt;
      *(float4*)&Ps[kk][cc + 4] = *(const float4*)(pt + 4);
    }
    __syncthreads();
#pragma unroll
    for (int kk = 0; kk < 8; ++kk) {
      const int k = kc * 8 + kk;
      float av[8], bv[8];
      uint4 raw = *(const uint4*)&Kt[k][ry * 8];
      float2 f0 = __half22float2(*(const __half2*)&raw.x);
      float2 f1 = __half22float2(*(const __half2*)&raw.y);
      float2 f2 = __half22float2(*(const __half2*)&raw.z);
      float2 f3 = __half22float2(*(const __half2*)&raw.w);
      av[0]=f0.x; av[1]=f0.y; av[2]=f1.x; av[3]=f1.y;
      av[4]=f2.x; av[5]=f2.y; av[6]=f3.x; av[7]=f3.y;
      *(float4*)&bv[0] = *(const float4*)&Ps[kk][wid * 64 + rx * 8];
      *(float4*)&bv[4] = *(const float4*)&Ps[kk][wid * 64 + rx * 8 + 4];
#pragma unroll
      for (int i = 0; i < 8; ++i)
#pragma unroll
        for (int j = 0; j < 8; ++j)
          dacc[i][j] = fmaf(av[i], bv[j], dacc[i][j]);
    }
  }
  float mx = dacc[0][0];
#pragma unroll
  for (int i = 0; i < 8; ++i)
#pragma unroll
    for (int j = 0; j < 8; ++j) mx = fmaxf(mx, dacc[i][j]);
#pragma unroll
  for (int off = 32; off; off >>= 1) mx = fmaxf(mx, __shfl_xor(mx, off));
  if (lane == 0) wred[wid] = mx;
  __syncthreads();
  if (tid == 0) {
    float m2 = fmaxf(fmaxf(wred[0], wred[1]), fmaxf(wred[2], wred[3]));
    atomicMax(stab_enc, enc_f32(m2));
  }
}

/* ---------------- FAVOR: context & k_sum partials (GEMM-tiled) ------------- */
__global__ __launch_bounds__(256, 2) void favor_ctx2(
    const float* __restrict__ Kg, const float* __restrict__ Vg,
    const float* __restrict__ projT, const unsigned* __restrict__ stab_enc,
    float* __restrict__ ctxp, float* __restrict__ ksump, int split)
{
  __shared__ __half Kt[64][72];
  __shared__ __half Vt[64][72];
  __shared__ float Ps[8][256];
  __shared__ __half kps[64][260];
  __shared__ float diag4[64][4];
  __shared__ float diag_s[64];

  const int tid = threadIdx.x;
  const int wid = tid >> 6, lane = tid & 63;
  const int ry = lane >> 3, rx = lane & 7;
  const int sidx = blockIdx.x % split;
  const int bh = blockIdx.x / split;
  const int b = bh >> 3, h = bh & 7;
  const int rows = NN / split, nch = rows / 64;
  const float stab = dec_f32(*stab_enc);

  float cacc[8][8] = {};
  float ksacc[8] = {};

  for (int c = 0; c < nch; ++c) {
    const int n0 = sidx * rows + c * 64;
    __syncthreads();
    {
      const int r = tid >> 2, s2 = tid & 3;
      const float* ksrc = Kg + ((size_t)(b * NN + n0 + r)) * DMM + h * DH + s2 * 16;
      const float* vsrc = Vg + ((size_t)(b * NN + n0 + r)) * DMM + h * DH + s2 * 16;
      float kq = 0.f;
      __half2 vb[8];
#pragma unroll
      for (int t4 = 0; t4 < 4; ++t4) {
        float4 kv = *(const float4*)(ksrc + t4 * 4);
        kv.x *= NRM; kv.y *= NRM; kv.z *= NRM; kv.w *= NRM;
        kq = fmaf(kv.x, kv.x, kq); kq = fmaf(kv.y, kv.y, kq);
        kq = fmaf(kv.z, kv.z, kq); kq = fmaf(kv.w, kv.w, kq);
        Kt[s2 * 16 + t4 * 4 + 0][r] = __float2half(kv.x);
        Kt[s2 * 16 + t4 * 4 + 1][r] = __float2half(kv.y);
        Kt[s2 * 16 + t4 * 4 + 2][r] = __float2half(kv.z);
        Kt[s2 * 16 + t4 * 4 + 3][r] = __float2half(kv.w);
        float4 vv = *(const float4*)(vsrc + t4 * 4);
        vb[t4 * 2 + 0] = __floats2half2_rn(vv.x, vv.y);
        vb[t4 * 2 + 1] = __floats2half2_rn(vv.z, vv.w);
      }
      diag4[r][s2] = kq;
      *(uint4*)&Vt[r][s2 * 16] = *(uint4*)&vb[0];
      *(uint4*)&Vt[r][s2 * 16 + 8] = *(uint4*)&vb[4];
    }
    __syncthreads();
    if (tid < 64)
      diag_s[tid] = 0.5f * (diag4[tid][0] + diag4[tid][1] + diag4[tid][2] + diag4[tid][3]);

    float dacc[8][8] = {};
    for (int kc = 0; kc < 8; ++kc) {
      if (kc) __syncthreads();
      {
        const int kk = tid >> 5, cc = (tid & 31) * 8;
        const float* pt = projT + (size_t)(kc * 8 + kk) * 256 + cc;
        *(float4*)&Ps[kk][cc] = *(const float4*)pt;
        *(float4*)&Ps[kk][cc + 4] = *(const float4*)(pt + 4);
      }
      __syncthreads();
#pragma unroll
      for (int kk = 0; kk < 8; ++kk) {
        const int k = kc * 8 + kk;
        float av[8], bv[8];
        uint4 raw = *(const uint4*)&Kt[k][ry * 8];
        float2 f0 = __half22float2(*(const __half2*)&raw.x);
        float2 f1 = __half22float2(*(const __half2*)&raw.y);
        float2 f2 = __half22float2(*(const __half2*)&raw.z);
        float2 f3 = __half22float2(*(const __half2*)&raw.w);
        av[0]=f0.x; av[1]=f0.y; av[2]=f1.x; av[3]=f1.y;
        av[4]=f2.x; av[5]=f2.y; av[6]=f3.x; av[7]=f3.y;
        *(float4*)&bv[0] = *(const float4*)&Ps[kk][wid * 64 + rx * 8];
        *(float4*)&bv[4] = *(const float4*)&Ps[kk][wid * 64 + rx * 8 + 4];
#pragma unroll
        for (int i = 0; i < 8; ++i)
#pragma unroll
          for (int j = 0; j < 8; ++j)
            dacc[i][j] = fmaf(av[i], bv[j], dacc[i][j]);
      }
    }

    float ks_i[8] = {};
#pragma unroll
    for (int i = 0; i < 8; ++i) {
      const int n = ry * 8 + i;
      const float base = diag_s[n] + stab;
      float kpv[8];
#pragma unroll
      for (int j = 0; j < 8; ++j) {
        kpv[j] = RATIO * (__expf(dacc[i][j] - base) + EPSF);
        ks_i[j] += kpv[j];
      }
      __half2 hp[4];
      hp[0] = __floats2half2_rn(kpv[0], kpv[1]);
      hp[1] = __floats2half2_rn(kpv[2], kpv[3]);
      hp[2] = __floats2half2_rn(kpv[4], kpv[5]);
      hp[3] = __floats2half2_rn(kpv[6], kpv[7]);
      *(uint2*)&kps[n][wid * 64 + rx * 8] = *(uint2*)&hp[0];
      *(uint2*)&kps[n][wid * 64 + rx * 8 + 4] = *(uint2*)&hp[2];
    }
#pragma unroll
    for (int j = 0; j < 8; ++j) {
      float s = ks_i[j];
      s += __shfl_xor(s, 8);
      s += __shfl_xor(s, 16);
      s += __shfl_xor(s, 32);
      if (ry == 0) ksacc[j] += s;
    }
    __syncthreads();

#pragma unroll 4
    for (int n = 0; n < 64; ++n) {
      float qw[8], cv[8];
      uint2 a0 = *(const uint2*)&kps[n][wid * 64 + ry * 8];
      uint2 a1 = *(const uint2*)&kps[n][wid * 64 + ry * 8 + 4];
      float2 g0 = __half22float2(*(const __half2*)&a0.x);
      float2 g1 = __half22float2(*(const __half2*)&a0.y);
      float2 g2 = __half22float2(*(const __half2*)&a1.x);
      float2 g3 = __half22float2(*(const __half2*)&a1.y);
      qw[0]=g0.x; qw[1]=g0.y; qw[2]=g1.x; qw[3]=g1.y;
      qw[4]=g2.x; qw[5]=g2.y; qw[6]=g3.x; qw[7]=g3.y;
      uint4 vr = *(const uint4*)&Vt[n][rx * 8];
      float2 h0 = __half22float2(*(const __half2*)&vr.x);
      float2 h1 = __half22float2(*(const __half2*)&vr.y);
      float2 h2 = __half22float2(*(const __half2*)&vr.z);
      float2 h3 = __half22float2(*(const __half2*)&vr.w);
      cv[0]=h0.x; cv[1]=h0.y; cv[2]=h1.x; cv[3]=h1.y;
      cv[4]=h2.x; cv[5]=h2.y; cv[6]=h3.x; cv[7]=h3.y;
#pragma unroll
      for (int i = 0; i < 8; ++i)
#pragma unroll
        for (int j = 0; j < 8; ++j)
          cacc[i][j] = fmaf(qw[i], cv[j], cacc[i][j]);
    }
  }

  {
    float* dst = ctxp + ((size_t)(bh * split + sidx)) * MM * DH;
#pragma unroll
    for (int i = 0; i < 8; ++i) {
      const int m = wid * 64 + ry * 8 + i;
      float4 v0, v1;
      v0.x = cacc[i][0]; v0.y = cacc[i][1]; v0.z = cacc[i][2]; v0.w = cacc[i][3];
      v1.x = cacc[i][4]; v1.y = cacc[i][5]; v1.z = cacc[i][6]; v1.w = cacc[i][7];
      *(float4*)(dst + (size_t)m * DH + rx * 8) = v0;
      *(float4*)(dst + (size_t)m * DH + rx * 8 + 4) = v1;
    }
    if (ry == 0) {
      float* kd = ksump + (size_t)(bh * split + sidx) * MM + wid * 64 + rx * 8;
#pragma unroll
      for (int j = 0; j < 8; ++j) kd[j] = ksacc[j];
    }
  }
}

/* ---------------- FAVOR: reduce partials ----------------------------------- */
__global__ __launch_bounds__(256) void favor_reduce(
    const float* __restrict__ ctxp, const float* __restrict__ ksump,
    float* __restrict__ ctx, float* __restrict__ ksum, int split)
{
  int i = blockIdx.x * 256 + threadIdx.x;
  if (i < BB * GHH * MM * DH) {
    int bh = i / (MM * DH);
    int md = i % (MM * DH);
    float s = 0.f;
    for (int k = 0; k < split; ++k) s += ctxp[((size_t)(bh * split + k)) * MM * DH + md];
    ctx[i] = s;
  }
  if (i < BB * GHH * MM) {
    int bh = i / MM, m = i % MM;
    float s = 0.f;
    for (int k = 0; k < split; ++k) s += ksump[(bh * split + k) * MM + m];
    ksum[i] = s;
  }
}

/* ---------------- FAVOR fused output: dd-GEMM -> qp(fp16 LDS) -> pv-GEMM ---- */
__global__ __launch_bounds__(256, 2) void favor_out_fused(
    float* __restrict__ Q, const float* __restrict__ projT,
    const float* __restrict__ ctx, const float* __restrict__ ksum)
{
  struct SM {
    union { float Qs[64][68]; float ctxs[64][68]; } A;
    union { float Ps[8][256]; float red[4][64]; } B;
    float outs[64][68];
    float ksum_s[256];
    float diag_s[64];
    float dinv_s[64];
  };
  __shared__ SM sm;
  __shared__ unsigned short qp_s[256][68];

  const int tid = threadIdx.x;
  const int wid = tid >> 6;
  const int lane = tid & 63;
  const int ry = lane >> 3;
  const int rx = lane & 7;
  const int bh = blockIdx.x >> 6;
  const int chunk = blockIdx.x & 63;
  const int b = bh >> 3, h = bh & 7;
  const int n0 = chunk * 64;

  {
    int r = tid >> 2, s2 = tid & 3;
    const float* src = Q + ((size_t)(b * NN + n0 + r)) * DMM + h * DH;
#pragma unroll
    for (int it = 0; it < 4; ++it) {
      int c4 = s2 + it * 4;
      float4 g = *(const float4*)(src + c4 * 4);
      sm.A.Qs[c4 * 4 + 0][r] = g.x * NRM;
      sm.A.Qs[c4 * 4 + 1][r] = g.y * NRM;
      sm.A.Qs[c4 * 4 + 2][r] = g.z * NRM;
      sm.A.Qs[c4 * 4 + 3][r] = g.w * NRM;
    }
    sm.ksum_s[tid] = ksum[bh * MM + tid];
  }
  __syncthreads();
  if (tid < 64) {
    float ss = 0.f;
#pragma unroll
    for (int k = 0; k < 64; ++k) { float q = sm.A.Qs[k][tid]; ss = fmaf(q, q, ss); }
    sm.diag_s[tid] = 0.5f * ss;
  }

  float acc[8][8] = {};
  for (int kc = 0; kc < 8; ++kc) {
    if (kc) __syncthreads();
    {
      const float* pt = projT + (size_t)(kc * 8 + (tid >> 5)) * 256 + (tid & 31) * 8;
      *(float4*)&sm.B.Ps[tid >> 5][(tid & 31) * 8] = *(const float4*)pt;
      *(float4*)&sm.B.Ps[tid >> 5][(tid & 31) * 8 + 4] = *(const float4*)(pt + 4);
    }
    __syncthreads();
#pragma unroll
    for (int kk = 0; kk < 8; ++kk) {
      const int k = kc * 8 + kk;
      float av[8], bv[8];
      *(float4*)&av[0] = *(const float4*)&sm.A.Qs[k][ry * 8];
      *(float4*)&av[4] = *(const float4*)&sm.A.Qs[k][ry * 8 + 4];
      *(float4*)&bv[0] = *(const float4*)&sm.B.Ps[kk][wid * 64 + rx * 8];
      *(float4*)&bv[4] = *(const float4*)&sm.B.Ps[kk][wid * 64 + rx * 8 + 4];
#pragma unroll
      for (int i = 0; i < 8; ++i)
#pragma unroll
        for (int j = 0; j < 8; ++j)
          acc[i][j] = fmaf(av[i], bv[j], acc[i][j]);
    }
  }

  float part[8];
#pragma unroll
  for (int i = 0; i < 8; ++i) {
    float mx = acc[i][0];
#pragma unroll
    for (int j = 1; j < 8; ++j) mx = fmaxf(mx, acc[i][j]);
    mx = fmaxf(mx, __shfl_xor(mx, 1));
    mx = fmaxf(mx, __shfl_xor(mx, 2));
    mx = fmaxf(mx, __shfl_xor(mx, 4));
    part[i] = mx;
  }
  __syncthreads();
  if (rx == 0)
#pragma unroll
    for (int i = 0; i < 8; ++i) sm.B.red[wid][ry * 8 + i] = part[i];
  __syncthreads();

  float ksv[8];
#pragma unroll
  for (int j = 0; j < 8; ++j) ksv[j] = sm.ksum_s[wid * 64 + rx * 8 + j];
#pragma unroll
  for (int i = 0; i < 8; ++i) {
    const int r = ry * 8 + i;
    float stab = fmaxf(fmaxf(sm.B.red[0][r], sm.B.red[1][r]),
                       fmaxf(sm.B.red[2][r], sm.B.red[3][r]));
    float base = sm.diag_s[r] + stab;
    float dsum = 0.f;
    float p[8];
#pragma unroll
    for (int j = 0; j < 8; ++j) {
      p[j] = RATIO * (__expf(acc[i][j] - base) + EPSF);
      dsum = fmaf(p[j], ksv[j], dsum);
    }
#pragma unroll
    for (int j = 0; j < 8; ++j) acc[i][j] = p[j];
    dsum += __shfl_xor(dsum, 1);
    dsum += __shfl_xor(dsum, 2);
    dsum += __shfl_xor(dsum, 4);
    part[i] = dsum;
  }
  __syncthreads();
  if (rx == 0)
#pragma unroll
    for (int i = 0; i < 8; ++i) sm.B.red[wid][ry * 8 + i] = part[i];
  __syncthreads();
  if (wid == 0 && rx == 0) {
#pragma unroll
    for (int i = 0; i < 8; ++i) {
      const int r = ry * 8 + i;
      sm.dinv_s[r] = 1.0f / (sm.B.red[0][r] + sm.B.red[1][r] + sm.B.red[2][r] + sm.B.red[3][r]);
    }
  }

#pragma unroll
  for (int j = 0; j < 8; ++j) {
    const int m = wid * 64 + rx * 8 + j;
    unsigned u0 = (unsigned)__half_as_ushort(__float2half(acc[0][j]))
                | ((unsigned)__half_as_ushort(__float2half(acc[1][j])) << 16);
    unsigned u1 = (unsigned)__half_as_ushort(__float2half(acc[2][j]))
                | ((unsigned)__half_as_ushort(__float2half(acc[3][j])) << 16);
    unsigned u2 = (unsigned)__half_as_ushort(__float2half(acc[4][j]))
                | ((unsigned)__half_as_ushort(__float2half(acc[5][j])) << 16);
    unsigned u3 = (unsigned)__half_as_ushort(__float2half(acc[6][j]))
                | ((unsigned)__half_as_ushort(__float2half(acc[7][j])) << 16);
    uint2 w01; w01.x = u0; w01.y = u1;
    uint2 w23; w23.x = u2; w23.y = u3;
    *(uint2*)&qp_s[m][ry * 8] = w01;
    *(uint2*)&qp_s[m][ry * 8 + 4] = w23;
  }

#pragma unroll
  for (int i = 0; i < 8; ++i)
#pragma unroll
    for (int j = 0; j < 8; ++j) acc[i][j] = 0.f;

  for (int mc = 0; mc < 4; ++mc) {
    __syncthreads();
    {
      int mm = tid >> 2, s2 = tid & 3;
      const float* src = ctx + ((size_t)(bh * MM + mc * 64 + mm)) * DH;
#pragma unroll
      for (int it = 0; it < 4; ++it) {
        int c4 = s2 + it * 4;
        *(float4*)&sm.A.ctxs[mm][c4 * 4] = *(const float4*)(src + c4 * 4);
      }
    }
    __syncthreads();
#pragma unroll 4
    for (int mm = 0; mm < 16; ++mm) {
      const int mrow = wid * 16 + mm;
      const int m2 = mc * 64 + mrow;
      uint2 v01 = *(const uint2*)&qp_s[m2][ry * 8];
      uint2 v23 = *(const uint2*)&qp_s[m2][ry * 8 + 4];
      float2 g0 = __half22float2(*(const __half2*)&v01.x);
      float2 g1 = __half22float2(*(const __half2*)&v01.y);
      float2 g2 = __half22float2(*(const __half2*)&v23.x);
      float2 g3 = __half22float2(*(const __half2*)&v23.y);
      float qw[8] = {g0.x, g0.y, g1.x, g1.y, g2.x, g2.y, g3.x, g3.y};
      float cv[8];
      *(float4*)&cv[0] = *(const float4*)&sm.A.ctxs[mrow][rx * 8];
      *(float4*)&cv[4] = *(const float4*)&sm.A.ctxs[mrow][rx * 8 + 4];
#pragma unroll
      for (int i = 0; i < 8; ++i)
#pragma unroll
        for (int j = 0; j < 8; ++j)
          acc[i][j] = fmaf(qw[i], cv[j], acc[i][j]);
    }
  }

  __syncthreads();
  for (int w = 0; w < 4; ++w) {
    if (wid == w) {
#pragma unroll
      for (int i = 0; i < 8; ++i) {
        float* row = &sm.outs[ry * 8 + i][rx * 8];
        if (w == 0) {
          *(float4*)row = *(float4*)&acc[i][0];
          *(float4*)(row + 4) = *(float4*)&acc[i][4];
        } else {
          float4 p0 = *(float4*)row;
          float4 p1 = *(float4*)(row + 4);
          p0.x += acc[i][0]; p0.y += acc[i][1]; p0.z += acc[i][2]; p0.w += acc[i][3];
          p1.x += acc[i][4]; p1.y += acc[i][5]; p1.z += acc[i][6]; p1.w += acc[i][7];
          *(float4*)row = p0;
          *(float4*)(row + 4) = p1;
        }
      }
    }
    __syncthreads();
  }

  {
    int r = tid >> 2, s2 = tid & 3;
    float di = sm.dinv_s[r];
    float* dst = Q + ((size_t)(b * NN + n0 + r)) * DMM + h * DH;
#pragma unroll
    for (int it = 0; it < 4; ++it) {
      int c4 = s2 + it * 4;
      float4 v = *(const float4*)&sm.outs[r][c4 * 4];
      v.x *= di; v.y *= di; v.z *= di; v.w *= di;
      *(float4*)(dst + c4 * 4) = v;
    }
  }
}

/* ---------------- launcher -------------------------------------------------- */
extern "C" void kernel_launch(void* const* d_in, const int* in_sizes, int n_in,
                              void* d_out, int out_size, void* d_ws, size_t ws_size,
                              hipStream_t stream)
{
  (void)in_sizes; (void)n_in; (void)out_size;
  const float* x    = (const float*)d_in[0];
  const float* Wq   = (const float*)d_in[2];
  const float* Wk   = (const float*)d_in[3];
  const float* Wv   = (const float*)d_in[4];
  const float* Wo   = (const float*)d_in[5];
  const float* bo   = (const float*)d_in[6];
  const float* proj = (const float*)d_in[7];
  float* out = (float*)d_out;

  const size_t WSZ = (size_t)DMM * DMM;
  const size_t XSP = (size_t)BB * NN * DMM;            /* ushort elems per activation plane */
  const size_t wbuf_f = (8 * WSZ * 2 + 3) / 4;
  const size_t LSZ = (size_t)BB * LHH * NN * DH;       /* u16 elems per local buf */
  const size_t lbuf_f = (3 * LSZ * 2 + 3) / 4;
  const size_t fixed_f = (size_t)3 * XSP + (size_t)BB * GHH * MM * DH
                       + (size_t)BB * GHH * MM + 16 + MM * DH + 16 + wbuf_f + 16
                       + lbuf_f + 16;

  /* region: time-shared between ctxp/ksump (FAVOR phase) and xH/xL split
   * activation planes (GEMM phases) — live ranges are disjoint.            */
  int split = 8, use_pre = 0;
  for (int s = 32; s >= 8; s >>= 1) {
    size_t part = (size_t)BB * GHH * s * (MM * DH + MM);
    size_t region = part > XSP ? part : XSP;
    if ((fixed_f + region) * 4 <= ws_size) { split = s; use_pre = 1; break; }
  }
  if (!use_pre) {
    for (int s = 32; s >= 8; s >>= 1) {
      size_t need = (fixed_f + (size_t)BB * GHH * s * (MM * DH + MM)) * 4;
      if (need <= ws_size) { split = s; break; }
    }
  }
  size_t part_f = (size_t)BB * GHH * split * (MM * DH + MM);
  size_t region_f = (use_pre && XSP > part_f) ? XSP : part_f;

  float* Qb    = (float*)d_ws;
  float* Kb    = Qb + XSP;
  float* Vb    = Kb + XSP;
  float* region = Vb + XSP;
  float* ctxp  = region;
  float* ksump = ctxp + (size_t)BB * GHH * split * MM * DH;
  unsigned short* xH = (unsigned short*)region;
  unsigned short* xL = xH + XSP;
  float* ctx   = region + region_f;
  float* ksum  = ctx + (size_t)BB * GHH * MM * DH;
  unsigned* stab = (unsigned*)(ksum + BB * GHH * MM);
  float* projT = (float*)(stab + 16);
  unsigned short* wsp = (unsigned short*)(projT + MM * DH);
  unsigned short* WqH = wsp;            unsigned short* WqL = wsp + WSZ;
  unsigned short* WkH = wsp + 2 * WSZ;  unsigned short* WkL = wsp + 3 * WSZ;
  unsigned short* WvH = wsp + 4 * WSZ;  unsigned short* WvL = wsp + 5 * WSZ;
  unsigned short* WoH = wsp + 6 * WSZ;  unsigned short* WoL = wsp + 7 * WSZ;
  unsigned short* Qlh = wsp + 8 * WSZ;
  unsigned short* Klh = Qlh + LSZ;
  unsigned short* Vtl = Klh + LSZ;

  dim3 blk(256);
  dim3 mg(DMM / 128, (BB * NN) / 128);
  const int wgrid = (int)(WSZ / 256);
  const int agrid = (int)(XSP / 1024);

  w_split<<<wgrid, blk, 0, stream>>>(Wq, WqH, WqL);
  w_split<<<wgrid, blk, 0, stream>>>(Wk, WkH, WkL);
  w_split<<<wgrid, blk, 0, stream>>>(Wv, WvH, WvL);
  w_split<<<wgrid, blk, 0, stream>>>(Wo, WoH, WoL);
  if (use_pre) {
    a_split<<<agrid, blk, 0, stream>>>(x, xH, xL);
    gemm_mfma_pre<<<mg, blk, 0, stream>>>(xH, xL, WqH, WqL, nullptr, Qb, DMM, DMM);
    gemm_mfma_pre<<<mg, blk, 0, stream>>>(xH, xL, WkH, WkL, nullptr, Kb, DMM, DMM);
    gemm_mfma_pre<<<mg, blk, 0, stream>>>(xH, xL, WvH, WvL, nullptr, Vb, DMM, DMM);
  } else {
    gemm_mfma<<<mg, blk, 0, stream>>>(x, WqH, WqL, nullptr, Qb, DMM, DMM);
    gemm_mfma<<<mg, blk, 0, stream>>>(x, WkH, WkL, nullptr, Kb, DMM, DMM);
    gemm_mfma<<<mg, blk, 0, stream>>>(x, WvH, WvL, nullptr, Vb, DMM, DMM);
  }
  rot_qk<<<(BB * LHH * NN) / 256, blk, 0, stream>>>(Qb, Kb, Qlh, Klh);
  v_trans<<<dim3(NN / 64, LHH, BB), blk, 0, stream>>>(Vb, Vtl);
  init_stab<<<1, 64, 0, stream>>>(stab);
  transpose_proj<<<64, blk, 0, stream>>>(proj, projT);
  favor_kstab2<<<BB * GHH * (NN / 64), blk, 0, stream>>>(Kb, projT, stab);
  favor_ctx2<<<BB * GHH * split, blk, 0, stream>>>(Kb, Vb, projT, stab, ctxp, ksump, split);
  favor_reduce<<<(BB * GHH * MM * DH) / 256, blk, 0, stream>>>(ctxp, ksump, ctx, ksum, split);
  favor_out_fused<<<BB * GHH * (NN / 64), blk, 0, stream>>>(Qb, projT, ctx, ksum);
  local_attn2<<<dim3(NWIN, LHH, BB), blk, 0, stream>>>(Qlh, Klh, Vtl, Qb);
  if (use_pre) {
    a_split<<<agrid, blk, 0, stream>>>(Qb, xH, xL);
    gemm_mfma_pre<<<mg, blk, 0, stream>>>(xH, xL, WoH, WoL, bo, out, DMM, DMM);
  } else {
    gemm_mfma<<<mg, blk, 0, stream>>>(Qb, WoH, WoL, bo, out, DMM, DMM);
  }
}

// Round 2
// 935.831 us; speedup vs baseline: 1.0796x; 1.0796x over previous
//
#include <hip/hip_runtime.h>
#include <hip/hip_fp16.h>
#include <math.h>

#define BB 4
#define NN 4096
#define DMM 768
#define HHH 12
#define LHH 4
#define GHH 8
#define DH 64
#define MM 256
#define WW 128
#define NWIN (NN/WW)
#define EPSF 1.0e-4f
#define NRM 0.35355339059327373f   /* 64^-0.25 */
#define NRM2 0.125f                /* 64^-0.5  */
#define RATIO 0.0625f              /* 256^-0.5 */
#define LN1E4_32 0.28782313662425572f  /* ln(10000)/32 */

using bf16x8 = __attribute__((ext_vector_type(8))) short;
using fp16x8 = __attribute__((ext_vector_type(8))) _Float16;
using f32x4  = __attribute__((ext_vector_type(4))) float;

static __device__ __forceinline__ unsigned enc_f32(float f) {
  unsigned u = __float_as_uint(f);
  return (u & 0x80000000u) ? ~u : (u | 0x80000000u);
}
static __device__ __forceinline__ float dec_f32(unsigned u) {
  unsigned b = (u & 0x80000000u) ? (u ^ 0x80000000u) : ~u;
  return __uint_as_float(b);
}
static __device__ __forceinline__ unsigned short f2h(float x) {
  return __half_as_ushort(__float2half(x));
}

/* ------- W prep: transpose to [n][k] and split into bf16 hi/lo planes ----- */
__global__ __launch_bounds__(256) void w_split(
    const float* __restrict__ W, unsigned short* __restrict__ Whi,
    unsigned short* __restrict__ Wlo)
{
  int o = blockIdx.x * 256 + threadIdx.x;     /* 768*768 */
  int k = o / DMM, n = o % DMM;
  float x = W[o];
  unsigned u = __float_as_uint(x);
  unsigned h = u & 0xFFFF0000u;
  float lf = x - __uint_as_float(h);
  Whi[(size_t)n * DMM + k] = (unsigned short)(u >> 16);
  Wlo[(size_t)n * DMM + k] = (unsigned short)(__float_as_uint(lf) >> 16);
}

/* ------- activation prep: split fp32 [M][K] into bf16 hi/lo planes -------- */
__global__ __launch_bounds__(256) void a_split(
    const float* __restrict__ A, unsigned short* __restrict__ Ahi,
    unsigned short* __restrict__ Alo)
{
  size_t o = ((size_t)blockIdx.x * 256 + threadIdx.x) * 4;
  float4 v = *(const float4*)(A + o);
  float f[4] = {v.x, v.y, v.z, v.w};
  unsigned short hi[4], lo[4];
#pragma unroll
  for (int i = 0; i < 4; ++i) {
    unsigned u = __float_as_uint(f[i]);
    unsigned h = u & 0xFFFF0000u;
    float l = f[i] - __uint_as_float(h);
    hi[i] = (unsigned short)(u >> 16);
    lo[i] = (unsigned short)(__float_as_uint(l) >> 16);
  }
  *(uint2*)(Ahi + o) = *(uint2*)&hi[0];
  *(uint2*)(Alo + o) = *(uint2*)&lo[0];
}

/* ------- split-bf16 MFMA GEMM: C = A(fp32 MxK) @ W(from hi/lo NxK) + bias --
 * fallback path: converts A tiles in-kernel (used only if ws too small).    */
__global__ __launch_bounds__(256) void gemm_mfma(
    const float* __restrict__ A,
    const unsigned short* __restrict__ Bhi, const unsigned short* __restrict__ Blo,
    const float* __restrict__ bias, float* __restrict__ C, int K, int Nc)
{
  __shared__ unsigned short Ah[128][40];
  __shared__ unsigned short Al[128][40];
  __shared__ unsigned short Bh[128][40];
  __shared__ unsigned short Bl[128][40];

  const int tid = threadIdx.x;
  const int wid = tid >> 6, lane = tid & 63;
  const int quad = lane >> 4, l16 = lane & 15;
  const int row0 = blockIdx.y * 128;
  const int col0 = blockIdx.x * 128;
  const int wm = (wid & 1) * 64, wn = (wid >> 1) * 64;
  const int sr = tid >> 1;
  const int sk = (tid & 1) * 16;

  f32x4 acc[4][4];
  const f32x4 zf = {0.f, 0.f, 0.f, 0.f};
#pragma unroll
  for (int i = 0; i < 4; ++i)
#pragma unroll
    for (int j = 0; j < 4; ++j) acc[i][j] = zf;

  for (int k0 = 0; k0 < K; k0 += 32) {
    __syncthreads();
    {
      const float* a = A + (size_t)(row0 + sr) * K + k0 + sk;
      float fv[16];
      *(float4*)&fv[0]  = *(const float4*)(a);
      *(float4*)&fv[4]  = *(const float4*)(a + 4);
      *(float4*)&fv[8]  = *(const float4*)(a + 8);
      *(float4*)&fv[12] = *(const float4*)(a + 12);
      unsigned hw[8], lw[8];
#pragma unroll
      for (int p = 0; p < 8; ++p) {
        float x0 = fv[2 * p], x1 = fv[2 * p + 1];
        unsigned u0 = __float_as_uint(x0), u1 = __float_as_uint(x1);
        unsigned h0 = u0 & 0xFFFF0000u, h1 = u1 & 0xFFFF0000u;
        float l0 = x0 - __uint_as_float(h0);
        float l1 = x1 - __uint_as_float(h1);
        hw[p] = (u0 >> 16) | h1;
        lw[p] = (__float_as_uint(l0) >> 16) | (__float_as_uint(l1) & 0xFFFF0000u);
      }
      *(uint4*)&Ah[sr][sk]     = *(uint4*)&hw[0];
      *(uint4*)&Ah[sr][sk + 8] = *(uint4*)&hw[4];
      *(uint4*)&Al[sr][sk]     = *(uint4*)&lw[0];
      *(uint4*)&Al[sr][sk + 8] = *(uint4*)&lw[4];
    }
    {
      const unsigned short* bh = Bhi + (size_t)(col0 + sr) * DMM + k0 + sk;
      const unsigned short* bl = Blo + (size_t)(col0 + sr) * DMM + k0 + sk;
      *(uint4*)&Bh[sr][sk]     = *(const uint4*)(bh);
      *(uint4*)&Bh[sr][sk + 8] = *(const uint4*)(bh + 8);
      *(uint4*)&Bl[sr][sk]     = *(const uint4*)(bl);
      *(uint4*)&Bl[sr][sk + 8] = *(const uint4*)(bl + 8);
    }
    __syncthreads();

    bf16x8 afh[4], afl[4], bfh[4], bfl[4];
#pragma unroll
    for (int t = 0; t < 4; ++t) {
      afh[t] = *(const bf16x8*)&Ah[wm + t * 16 + l16][quad * 8];
      afl[t] = *(const bf16x8*)&Al[wm + t * 16 + l16][quad * 8];
      bfh[t] = *(const bf16x8*)&Bh[wn + t * 16 + l16][quad * 8];
      bfl[t] = *(const bf16x8*)&Bl[wn + t * 16 + l16][quad * 8];
    }
#pragma unroll
    for (int ti = 0; ti < 4; ++ti)
#pragma unroll
      for (int tj = 0; tj < 4; ++tj) {
        acc[ti][tj] = __builtin_amdgcn_mfma_f32_16x16x32_bf16(afh[ti], bfh[tj], acc[ti][tj], 0, 0, 0);
        acc[ti][tj] = __builtin_amdgcn_mfma_f32_16x16x32_bf16(afh[ti], bfl[tj], acc[ti][tj], 0, 0, 0);
        acc[ti][tj] = __builtin_amdgcn_mfma_f32_16x16x32_bf16(afl[ti], bfh[tj], acc[ti][tj], 0, 0, 0);
      }
  }

  float bv[4] = {0.f, 0.f, 0.f, 0.f};
  if (bias) {
#pragma unroll
    for (int tj = 0; tj < 4; ++tj) bv[tj] = bias[col0 + wn + tj * 16 + l16];
  }
#pragma unroll
  for (int ti = 0; ti < 4; ++ti) {
    const int gr = row0 + wm + ti * 16 + quad * 4;
#pragma unroll
    for (int tj = 0; tj < 4; ++tj) {
      const int gc = col0 + wn + tj * 16 + l16;
      float* cp = C + (size_t)gr * Nc + gc;
#pragma unroll
      for (int r = 0; r < 4; ++r)
        cp[(size_t)r * Nc] = acc[ti][tj][r] + bv[tj];
    }
  }
}

/* ------- split-bf16 MFMA GEMM, pre-split A planes (hot path) --------------- */
__global__ __launch_bounds__(256) void gemm_mfma_pre(
    const unsigned short* __restrict__ Ahi, const unsigned short* __restrict__ Alo,
    const unsigned short* __restrict__ Bhi, const unsigned short* __restrict__ Blo,
    const float* __restrict__ bias, float* __restrict__ C, int K, int Nc)
{
  __shared__ unsigned short Ah[128][40];
  __shared__ unsigned short Al[128][40];
  __shared__ unsigned short Bh[128][40];
  __shared__ unsigned short Bl[128][40];

  const int tid = threadIdx.x;
  const int wid = tid >> 6, lane = tid & 63;
  const int quad = lane >> 4, l16 = lane & 15;
  const int row0 = blockIdx.y * 128;
  const int col0 = blockIdx.x * 128;
  const int wm = (wid & 1) * 64, wn = (wid >> 1) * 64;
  const int sr = tid >> 1;
  const int sk = (tid & 1) * 16;

  f32x4 acc[4][4];
  const f32x4 zf = {0.f, 0.f, 0.f, 0.f};
#pragma unroll
  for (int i = 0; i < 4; ++i)
#pragma unroll
    for (int j = 0; j < 4; ++j) acc[i][j] = zf;

  for (int k0 = 0; k0 < K; k0 += 32) {
    __syncthreads();
    {
      const unsigned short* ah = Ahi + (size_t)(row0 + sr) * K + k0 + sk;
      const unsigned short* al = Alo + (size_t)(row0 + sr) * K + k0 + sk;
      *(uint4*)&Ah[sr][sk]     = *(const uint4*)(ah);
      *(uint4*)&Ah[sr][sk + 8] = *(const uint4*)(ah + 8);
      *(uint4*)&Al[sr][sk]     = *(const uint4*)(al);
      *(uint4*)&Al[sr][sk + 8] = *(const uint4*)(al + 8);
      const unsigned short* bh = Bhi + (size_t)(col0 + sr) * K + k0 + sk;
      const unsigned short* bl = Blo + (size_t)(col0 + sr) * K + k0 + sk;
      *(uint4*)&Bh[sr][sk]     = *(const uint4*)(bh);
      *(uint4*)&Bh[sr][sk + 8] = *(const uint4*)(bh + 8);
      *(uint4*)&Bl[sr][sk]     = *(const uint4*)(bl);
      *(uint4*)&Bl[sr][sk + 8] = *(const uint4*)(bl + 8);
    }
    __syncthreads();

    bf16x8 afh[4], afl[4], bfh[4], bfl[4];
#pragma unroll
    for (int t = 0; t < 4; ++t) {
      afh[t] = *(const bf16x8*)&Ah[wm + t * 16 + l16][quad * 8];
      afl[t] = *(const bf16x8*)&Al[wm + t * 16 + l16][quad * 8];
      bfh[t] = *(const bf16x8*)&Bh[wn + t * 16 + l16][quad * 8];
      bfl[t] = *(const bf16x8*)&Bl[wn + t * 16 + l16][quad * 8];
    }
#pragma unroll
    for (int ti = 0; ti < 4; ++ti)
#pragma unroll
      for (int tj = 0; tj < 4; ++tj) {
        acc[ti][tj] = __builtin_amdgcn_mfma_f32_16x16x32_bf16(afh[ti], bfh[tj], acc[ti][tj], 0, 0, 0);
        acc[ti][tj] = __builtin_amdgcn_mfma_f32_16x16x32_bf16(afh[ti], bfl[tj], acc[ti][tj], 0, 0, 0);
        acc[ti][tj] = __builtin_amdgcn_mfma_f32_16x16x32_bf16(afl[ti], bfh[tj], acc[ti][tj], 0, 0, 0);
      }
  }

  float bv[4] = {0.f, 0.f, 0.f, 0.f};
  if (bias) {
#pragma unroll
    for (int tj = 0; tj < 4; ++tj) bv[tj] = bias[col0 + wn + tj * 16 + l16];
  }
#pragma unroll
  for (int ti = 0; ti < 4; ++ti) {
    const int gr = row0 + wm + ti * 16 + quad * 4;
#pragma unroll
    for (int tj = 0; tj < 4; ++tj) {
      const int gc = col0 + wn + tj * 16 + l16;
      float* cp = C + (size_t)gr * Nc + gc;
#pragma unroll
      for (int r = 0; r < 4; ++r)
        cp[(size_t)r * Nc] = acc[ti][tj][r] + bv[tj];
    }
  }
}

/* ---------------- init global stabilizer ---------------------------------- */
__global__ void init_stab(unsigned* stab_enc) {
  if (threadIdx.x == 0 && blockIdx.x == 0) *stab_enc = 0x00800000u; /* enc(-FLT_MAX) */
}

/* ---------------- proj prep: projT fp32 + [m][d] fp16 hi/lo planes --------- */
__global__ __launch_bounds__(256) void transpose_proj(
    const float* __restrict__ proj, float* __restrict__ projT,
    unsigned short* __restrict__ phh, unsigned short* __restrict__ phl)
{
  int o = blockIdx.x * 256 + threadIdx.x;   /* 16384 */
  int k = o >> 8, m = o & 255;
  float v = proj[m * 64 + k];
  projT[k * 256 + m] = v;
  __half hh = __float2half(v);
  float lf = v - __half2float(hh);
  phh[m * 64 + k] = __half_as_ushort(hh);
  phl[m * 64 + k] = f2h(lf);
}

/* ---------------- rotary prep for local heads: Q(scaled)/K -> fp16 --------- */
__global__ __launch_bounds__(256) void rot_qk(
    const float* __restrict__ Qb, const float* __restrict__ Kb,
    unsigned short* __restrict__ Qlh, unsigned short* __restrict__ Klh)
{
  int idx = blockIdx.x * 256 + threadIdx.x;    /* (b*LHH+h)*NN + n : 65536 */
  int n = idx & (NN - 1);
  int bh = idx >> 12;
  int b = bh >> 2, h = bh & 3;
  const float* qs = Qb + ((size_t)(b * NN + n)) * DMM + GHH * DH + h * DH;
  const float* ks = Kb + ((size_t)(b * NN + n)) * DMM + GHH * DH + h * DH;
  float q[64], k[64];
#pragma unroll
  for (int t = 0; t < 16; ++t) {
    *(float4*)&q[t * 4] = *(const float4*)(qs + t * 4);
    *(float4*)&k[t * 4] = *(const float4*)(ks + t * 4);
  }
  unsigned short qo[64], ko[64];
#pragma unroll
  for (int i = 0; i < 32; ++i) {
    float invf = __expf((float)i * -LN1E4_32);
    float th = (float)n * invf;
    float s, c;
    sincosf(th, &s, &c);
    qo[i]      = f2h(fmaf(q[i], c, -q[i + 32] * s) * NRM2);
    qo[i + 32] = f2h(fmaf(q[i + 32], c, q[i] * s) * NRM2);
    ko[i]      = f2h(fmaf(k[i], c, -k[i + 32] * s));
    ko[i + 32] = f2h(fmaf(k[i + 32], c, k[i] * s));
  }
  unsigned short* qd = Qlh + (size_t)idx * 64;
  unsigned short* kd = Klh + (size_t)idx * 64;
#pragma unroll
  for (int t = 0; t < 8; ++t) {
    *(uint4*)(qd + t * 8) = *(uint4*)&qo[t * 8];
    *(uint4*)(kd + t * 8) = *(uint4*)&ko[t * 8];
  }
}

/* ---------------- V transpose for local heads: fp16 [b][h][d][n] ----------- */
__global__ __launch_bounds__(256) void v_trans(
    const float* __restrict__ Vb, unsigned short* __restrict__ Vt)
{
  __shared__ unsigned short T[64][72];
  const int nb = blockIdx.x, h = blockIdx.y, b = blockIdx.z;
  const int n0 = nb * 64;
  const int tid = threadIdx.x;
  {
    int r = tid >> 2, g = tid & 3;
    const float* src = Vb + ((size_t)(b * NN + n0 + r)) * DMM + GHH * DH + h * DH + g * 16;
#pragma unroll
    for (int t = 0; t < 4; ++t) {
      float4 v = *(const float4*)(src + t * 4);
      T[g * 16 + t * 4 + 0][r] = f2h(v.x);
      T[g * 16 + t * 4 + 1][r] = f2h(v.y);
      T[g * 16 + t * 4 + 2][r] = f2h(v.z);
      T[g * 16 + t * 4 + 3][r] = f2h(v.w);
    }
  }
  __syncthreads();
  {
    int d = tid >> 2, g = tid & 3;
    unsigned short* dst = Vt + ((size_t)(b * LHH + h) * DH + d) * NN + n0 + g * 16;
    *(uint4*)dst       = *(uint4*)&T[d][g * 16];
    *(uint4*)(dst + 8) = *(uint4*)&T[d][g * 16 + 8];
  }
}

/* ---------------- local attention via f16 MFMA (flash-style) --------------- */
__global__ __launch_bounds__(256) void local_attn2(
    const unsigned short* __restrict__ Qlh, const unsigned short* __restrict__ Klh,
    const unsigned short* __restrict__ Vt, float* __restrict__ Qb)
{
  __shared__ unsigned short Pl[4][32][72];
  const int w = blockIdx.x, h = blockIdx.y, b = blockIdx.z;
  const int tid = threadIdx.x;
  const int wid = tid >> 6, lane = tid & 63;
  const int quad = lane >> 4, l16 = lane & 15;
  const int bh = b * LHH + h;
  const int qn0 = w * WW + wid * 32;

  fp16x8 Aq[2][2];
#pragma unroll
  for (int mt = 0; mt < 2; ++mt)
#pragma unroll
    for (int ks = 0; ks < 2; ++ks)
      Aq[mt][ks] = *(const fp16x8*)(Qlh + ((size_t)bh * NN + qn0 + mt * 16 + l16) * 64 + ks * 32 + quad * 8);

  float m_run[8], l_run[8];
  f32x4 Oacc[2][4];
  const f32x4 zf = {0.f, 0.f, 0.f, 0.f};
#pragma unroll
  for (int r = 0; r < 8; ++r) { m_run[r] = -3.4e38f; l_run[r] = 0.f; }
#pragma unroll
  for (int mt = 0; mt < 2; ++mt)
#pragma unroll
    for (int nt = 0; nt < 4; ++nt) Oacc[mt][nt] = zf;

  const int wb_lo = (w == 0) ? 0 : w - 1;
  const int wb_hi = (w == NWIN - 1) ? w : w + 1;
  for (int wb = wb_lo; wb <= wb_hi; ++wb) {
    for (int half = 0; half < 2; ++half) {
      const int kn0 = wb * WW + half * 64;
      f32x4 sacc[2][4];
#pragma unroll
      for (int mt = 0; mt < 2; ++mt)
#pragma unroll
        for (int nt = 0; nt < 4; ++nt) sacc[mt][nt] = zf;

#pragma unroll
      for (int ks = 0; ks < 2; ++ks) {
        fp16x8 Bk[4];
#pragma unroll
        for (int nt = 0; nt < 4; ++nt)
          Bk[nt] = *(const fp16x8*)(Klh + ((size_t)bh * NN + kn0 + nt * 16 + l16) * 64 + ks * 32 + quad * 8);
#pragma unroll
        for (int mt = 0; mt < 2; ++mt)
#pragma unroll
          for (int nt = 0; nt < 4; ++nt)
            sacc[mt][nt] = __builtin_amdgcn_mfma_f32_16x16x32_f16(Aq[mt][ks], Bk[nt], sacc[mt][nt], 0, 0, 0);
      }

      /* online softmax per row (row = mt*16 + quad*4 + reg) */
#pragma unroll
      for (int mt = 0; mt < 2; ++mt) {
#pragma unroll
        for (int reg = 0; reg < 4; ++reg) {
          const int r8 = mt * 4 + reg;
          float v = fmaxf(fmaxf(sacc[mt][0][reg], sacc[mt][1][reg]),
                          fmaxf(sacc[mt][2][reg], sacc[mt][3][reg]));
          v = fmaxf(v, __shfl_xor(v, 1));
          v = fmaxf(v, __shfl_xor(v, 2));
          v = fmaxf(v, __shfl_xor(v, 4));
          v = fmaxf(v, __shfl_xor(v, 8));
          float mnew = fmaxf(m_run[r8], v);
          float alpha = __expf(m_run[r8] - mnew);
          m_run[r8] = mnew;
          float ps = 0.f;
#pragma unroll
          for (int nt = 0; nt < 4; ++nt) {
            float p = __expf(sacc[mt][nt][reg] - mnew);
            sacc[mt][nt][reg] = p;
            ps += p;
          }
          ps += __shfl_xor(ps, 1);
          ps += __shfl_xor(ps, 2);
          ps += __shfl_xor(ps, 4);
          ps += __shfl_xor(ps, 8);
          l_run[r8] = l_run[r8] * alpha + ps;
#pragma unroll
          for (int nt = 0; nt < 4; ++nt) Oacc[mt][nt][reg] *= alpha;
        }
      }

      /* write P fp16 (C-layout -> [qrow][key] in LDS, wave-local) */
#pragma unroll
      for (int mt = 0; mt < 2; ++mt)
#pragma unroll
        for (int nt = 0; nt < 4; ++nt)
#pragma unroll
          for (int reg = 0; reg < 4; ++reg)
            Pl[wid][mt * 16 + quad * 4 + reg][nt * 16 + l16] = f2h(sacc[mt][nt][reg]);

      /* PV */
#pragma unroll
      for (int kstep = 0; kstep < 2; ++kstep) {
        fp16x8 Ap[2];
#pragma unroll
        for (int mt = 0; mt < 2; ++mt)
          Ap[mt] = *(const fp16x8*)&Pl[wid][mt * 16 + l16][kstep * 32 + quad * 8];
        fp16x8 Bv[4];
#pragma unroll
        for (int nt = 0; nt < 4; ++nt)
          Bv[nt] = *(const fp16x8*)(Vt + ((size_t)bh * DH + nt * 16 + l16) * NN + kn0 + kstep * 32 + quad * 8);
#pragma unroll
        for (int mt = 0; mt < 2; ++mt)
#pragma unroll
          for (int nt = 0; nt < 4; ++nt)
            Oacc[mt][nt] = __builtin_amdgcn_mfma_f32_16x16x32_f16(Ap[mt], Bv[nt], Oacc[mt][nt], 0, 0, 0);
      }
    }
  }

  /* epilogue: divide by l, store fp32 into Qb local-head columns */
#pragma unroll
  for (int mt = 0; mt < 2; ++mt)
#pragma unroll
    for (int reg = 0; reg < 4; ++reg) {
      const float inv = 1.0f / l_run[mt * 4 + reg];
      const int n = qn0 + mt * 16 + quad * 4 + reg;
      float* dst = Qb + ((size_t)(b * NN + n)) * DMM + GHH * DH + h * DH;
#pragma unroll
      for (int nt = 0; nt < 4; ++nt)
        dst[nt * 16 + l16] = Oacc[mt][nt][reg] * inv;
    }
}

/* ---------------- FAVOR: global max of dd_k (GEMM-tiled) ------------------- */
__global__ __launch_bounds__(256) void favor_kstab2(
    const float* __restrict__ Kg, const float* __restrict__ projT,
    unsigned* __restrict__ stab_enc)
{
  __shared__ __half Kt[64][72];
  __shared__ float Ps[8][256];
  __shared__ float wred[4];
  const int tid = threadIdx.x;
  const int wid = tid >> 6, lane = tid & 63;
  const int ry = lane >> 3, rx = lane & 7;
  const int chunk = blockIdx.x & 63;
  const int bh = blockIdx.x >> 6;
  const int b = bh >> 3, h = bh & 7;
  const int n0 = chunk * 64;

  {
    const int r = tid >> 2, s2 = tid & 3;
    const float* ksrc = Kg + ((size_t)(b * NN + n0 + r)) * DMM + h * DH + s2 * 16;
#pragma unroll
    for (int t4 = 0; t4 < 4; ++t4) {
      float4 kv = *(const float4*)(ksrc + t4 * 4);
      Kt[s2 * 16 + t4 * 4 + 0][r] = __float2half(kv.x * NRM);
      Kt[s2 * 16 + t4 * 4 + 1][r] = __float2half(kv.y * NRM);
      Kt[s2 * 16 + t4 * 4 + 2][r] = __float2half(kv.z * NRM);
      Kt[s2 * 16 + t4 * 4 + 3][r] = __float2half(kv.w * NRM);
    }
  }
  __syncthreads();

  float dacc[8][8] = {};
  for (int kc = 0; kc < 8; ++kc) {
    if (kc) __syncthreads();
    {
      const int kk = tid >> 5, cc = (tid & 31) * 8;
      const float* pt = projT + (size_t)(kc * 8 + kk) * 256 + cc;
      *(float4*)&Ps[kk][cc] = *(const float4*)pt;
      *(float4*)&Ps[kk][cc + 4] = *(const float4*)(pt + 4);
    }
    __syncthreads();
#pragma unroll
    for (int kk = 0; kk < 8; ++kk) {
      const int k = kc * 8 + kk;
      float av[8], bv[8];
      uint4 raw = *(const uint4*)&Kt[k][ry * 8];
      float2 f0 = __half22float2(*(const __half2*)&raw.x);
      float2 f1 = __half22float2(*(const __half2*)&raw.y);
      float2 f2 = __half22float2(*(const __half2*)&raw.z);
      float2 f3 = __half22float2(*(const __half2*)&raw.w);
      av[0]=f0.x; av[1]=f0.y; av[2]=f1.x; av[3]=f1.y;
      av[4]=f2.x; av[5]=f2.y; av[6]=f3.x; av[7]=f3.y;
      *(float4*)&bv[0] = *(const float4*)&Ps[kk][wid * 64 + rx * 8];
      *(float4*)&bv[4] = *(const float4*)&Ps[kk][wid * 64 + rx * 8 + 4];
#pragma unroll
      for (int i = 0; i < 8; ++i)
#pragma unroll
        for (int j = 0; j < 8; ++j)
          dacc[i][j] = fmaf(av[i], bv[j], dacc[i][j]);
    }
  }
  float mx = dacc[0][0];
#pragma unroll
  for (int i = 0; i < 8; ++i)
#pragma unroll
    for (int j = 0; j < 8; ++j) mx = fmaxf(mx, dacc[i][j]);
#pragma unroll
  for (int off = 32; off; off >>= 1) mx = fmaxf(mx, __shfl_xor(mx, off));
  if (lane == 0) wred[wid] = mx;
  __syncthreads();
  if (tid == 0) {
    float m2 = fmaxf(fmaxf(wred[0], wred[1]), fmaxf(wred[2], wred[3]));
    atomicMax(stab_enc, enc_f32(m2));
  }
}

/* ---------------- FAVOR: context & k_sum partials (GEMM-tiled) ------------- */
__global__ __launch_bounds__(256, 2) void favor_ctx2(
    const float* __restrict__ Kg, const float* __restrict__ Vg,
    const float* __restrict__ projT, const unsigned* __restrict__ stab_enc,
    float* __restrict__ ctxp, float* __restrict__ ksump, int split)
{
  __shared__ __half Kt[64][72];
  __shared__ __half Vt[64][72];
  __shared__ float Ps[8][256];
  __shared__ __half kps[64][260];
  __shared__ float diag4[64][4];
  __shared__ float diag_s[64];

  const int tid = threadIdx.x;
  const int wid = tid >> 6, lane = tid & 63;
  const int ry = lane >> 3, rx = lane & 7;
  const int sidx = blockIdx.x % split;
  const int bh = blockIdx.x / split;
  const int b = bh >> 3, h = bh & 7;
  const int rows = NN / split, nch = rows / 64;
  const float stab = dec_f32(*stab_enc);

  float cacc[8][8] = {};
  float ksacc[8] = {};

  for (int c = 0; c < nch; ++c) {
    const int n0 = sidx * rows + c * 64;
    __syncthreads();
    {
      const int r = tid >> 2, s2 = tid & 3;
      const float* ksrc = Kg + ((size_t)(b * NN + n0 + r)) * DMM + h * DH + s2 * 16;
      const float* vsrc = Vg + ((size_t)(b * NN + n0 + r)) * DMM + h * DH + s2 * 16;
      float kq = 0.f;
      __half2 vb[8];
#pragma unroll
      for (int t4 = 0; t4 < 4; ++t4) {
        float4 kv = *(const float4*)(ksrc + t4 * 4);
        kv.x *= NRM; kv.y *= NRM; kv.z *= NRM; kv.w *= NRM;
        kq = fmaf(kv.x, kv.x, kq); kq = fmaf(kv.y, kv.y, kq);
        kq = fmaf(kv.z, kv.z, kq); kq = fmaf(kv.w, kv.w, kq);
        Kt[s2 * 16 + t4 * 4 + 0][r] = __float2half(kv.x);
        Kt[s2 * 16 + t4 * 4 + 1][r] = __float2half(kv.y);
        Kt[s2 * 16 + t4 * 4 + 2][r] = __float2half(kv.z);
        Kt[s2 * 16 + t4 * 4 + 3][r] = __float2half(kv.w);
        float4 vv = *(const float4*)(vsrc + t4 * 4);
        vb[t4 * 2 + 0] = __floats2half2_rn(vv.x, vv.y);
        vb[t4 * 2 + 1] = __floats2half2_rn(vv.z, vv.w);
      }
      diag4[r][s2] = kq;
      *(uint4*)&Vt[r][s2 * 16] = *(uint4*)&vb[0];
      *(uint4*)&Vt[r][s2 * 16 + 8] = *(uint4*)&vb[4];
    }
    __syncthreads();
    if (tid < 64)
      diag_s[tid] = 0.5f * (diag4[tid][0] + diag4[tid][1] + diag4[tid][2] + diag4[tid][3]);

    float dacc[8][8] = {};
    for (int kc = 0; kc < 8; ++kc) {
      if (kc) __syncthreads();
      {
        const int kk = tid >> 5, cc = (tid & 31) * 8;
        const float* pt = projT + (size_t)(kc * 8 + kk) * 256 + cc;
        *(float4*)&Ps[kk][cc] = *(const float4*)pt;
        *(float4*)&Ps[kk][cc + 4] = *(const float4*)(pt + 4);
      }
      __syncthreads();
#pragma unroll
      for (int kk = 0; kk < 8; ++kk) {
        const int k = kc * 8 + kk;
        float av[8], bv[8];
        uint4 raw = *(const uint4*)&Kt[k][ry * 8];
        float2 f0 = __half22float2(*(const __half2*)&raw.x);
        float2 f1 = __half22float2(*(const __half2*)&raw.y);
        float2 f2 = __half22float2(*(const __half2*)&raw.z);
        float2 f3 = __half22float2(*(const __half2*)&raw.w);
        av[0]=f0.x; av[1]=f0.y; av[2]=f1.x; av[3]=f1.y;
        av[4]=f2.x; av[5]=f2.y; av[6]=f3.x; av[7]=f3.y;
        *(float4*)&bv[0] = *(const float4*)&Ps[kk][wid * 64 + rx * 8];
        *(float4*)&bv[4] = *(const float4*)&Ps[kk][wid * 64 + rx * 8 + 4];
#pragma unroll
        for (int i = 0; i < 8; ++i)
#pragma unroll
          for (int j = 0; j < 8; ++j)
            dacc[i][j] = fmaf(av[i], bv[j], dacc[i][j]);
      }
    }

    float ks_i[8] = {};
#pragma unroll
    for (int i = 0; i < 8; ++i) {
      const int n = ry * 8 + i;
      const float base = diag_s[n] + stab;
      float kpv[8];
#pragma unroll
      for (int j = 0; j < 8; ++j) {
        kpv[j] = RATIO * (__expf(dacc[i][j] - base) + EPSF);
        ks_i[j] += kpv[j];
      }
      __half2 hp[4];
      hp[0] = __floats2half2_rn(kpv[0], kpv[1]);
      hp[1] = __floats2half2_rn(kpv[2], kpv[3]);
      hp[2] = __floats2half2_rn(kpv[4], kpv[5]);
      hp[3] = __floats2half2_rn(kpv[6], kpv[7]);
      *(uint2*)&kps[n][wid * 64 + rx * 8] = *(uint2*)&hp[0];
      *(uint2*)&kps[n][wid * 64 + rx * 8 + 4] = *(uint2*)&hp[2];
    }
#pragma unroll
    for (int j = 0; j < 8; ++j) {
      float s = ks_i[j];
      s += __shfl_xor(s, 8);
      s += __shfl_xor(s, 16);
      s += __shfl_xor(s, 32);
      if (ry == 0) ksacc[j] += s;
    }
    __syncthreads();

#pragma unroll 4
    for (int n = 0; n < 64; ++n) {
      float qw[8], cv[8];
      uint2 a0 = *(const uint2*)&kps[n][wid * 64 + ry * 8];
      uint2 a1 = *(const uint2*)&kps[n][wid * 64 + ry * 8 + 4];
      float2 g0 = __half22float2(*(const __half2*)&a0.x);
      float2 g1 = __half22float2(*(const __half2*)&a0.y);
      float2 g2 = __half22float2(*(const __half2*)&a1.x);
      float2 g3 = __half22float2(*(const __half2*)&a1.y);
      qw[0]=g0.x; qw[1]=g0.y; qw[2]=g1.x; qw[3]=g1.y;
      qw[4]=g2.x; qw[5]=g2.y; qw[6]=g3.x; qw[7]=g3.y;
      uint4 vr = *(const uint4*)&Vt[n][rx * 8];
      float2 h0 = __half22float2(*(const __half2*)&vr.x);
      float2 h1 = __half22float2(*(const __half2*)&vr.y);
      float2 h2 = __half22float2(*(const __half2*)&vr.z);
      float2 h3 = __half22float2(*(const __half2*)&vr.w);
      cv[0]=h0.x; cv[1]=h0.y; cv[2]=h1.x; cv[3]=h1.y;
      cv[4]=h2.x; cv[5]=h2.y; cv[6]=h3.x; cv[7]=h3.y;
#pragma unroll
      for (int i = 0; i < 8; ++i)
#pragma unroll
        for (int j = 0; j < 8; ++j)
          cacc[i][j] = fmaf(qw[i], cv[j], cacc[i][j]);
    }
  }

  {
    float* dst = ctxp + ((size_t)(bh * split + sidx)) * MM * DH;
#pragma unroll
    for (int i = 0; i < 8; ++i) {
      const int m = wid * 64 + ry * 8 + i;
      float4 v0, v1;
      v0.x = cacc[i][0]; v0.y = cacc[i][1]; v0.z = cacc[i][2]; v0.w = cacc[i][3];
      v1.x = cacc[i][4]; v1.y = cacc[i][5]; v1.z = cacc[i][6]; v1.w = cacc[i][7];
      *(float4*)(dst + (size_t)m * DH + rx * 8) = v0;
      *(float4*)(dst + (size_t)m * DH + rx * 8 + 4) = v1;
    }
    if (ry == 0) {
      float* kd = ksump + (size_t)(bh * split + sidx) * MM + wid * 64 + rx * 8;
#pragma unroll
      for (int j = 0; j < 8; ++j) kd[j] = ksacc[j];
    }
  }
}

/* ---------------- FAVOR: reduce partials -> ctxT fp16 [bh][d][m] + ksum ---- */
__global__ __launch_bounds__(256) void favor_reduce(
    const float* __restrict__ ctxp, const float* __restrict__ ksump,
    unsigned short* __restrict__ ctxT_h, float* __restrict__ ksum, int split)
{
  int i = blockIdx.x * 256 + threadIdx.x;
  if (i < BB * GHH * MM * DH) {
    int bh = i / (MM * DH);
    int md = i % (MM * DH);
    int m = md / DH, d = md % DH;
    float s = 0.f;
    for (int k = 0; k < split; ++k) s += ctxp[((size_t)(bh * split + k)) * MM * DH + md];
    ctxT_h[((size_t)bh * DH + d) * MM + m] = f2h(s);
  }
  if (i < BB * GHH * MM) {
    int bh = i / MM, m = i % MM;
    float s = 0.f;
    for (int k = 0; k < split; ++k) s += ksump[(bh * split + k) * MM + m];
    ksum[i] = s;
  }
}

/* ---------------- FAVOR fused output via MFMA ------------------------------
 * grid 2048 = bh(32) x chunk(64); 256 threads = 4 waves.
 * dd = (Q*NRM)[64x64] @ proj^T[64x256] via split-fp16 (3-MFMA) -> fp32 acc;
 * row-max/exp/dsum on VALU; qp fp16 -> LDS; out = qp[64x256] @ ctxT^T via
 * f16 MFMA; divide by dsum; store.                                          */
__global__ __launch_bounds__(256, 2) void favor_out_mfma(
    float* __restrict__ Q, const unsigned short* __restrict__ phh,
    const unsigned short* __restrict__ phl,
    const unsigned short* __restrict__ ctxT_h, const float* __restrict__ ksum)
{
  __shared__ unsigned short Qhh[64][72];
  __shared__ unsigned short Qhl[64][72];
  __shared__ unsigned short qp_s[64][264];
  __shared__ float red[4][64];
  __shared__ float dred[4][64];
  __shared__ float diag4[64][4];
  __shared__ float diag_s[64];
  __shared__ float dinv_s[64];
  __shared__ float ksum_s[256];

  const int tid = threadIdx.x;
  const int wid = tid >> 6, lane = tid & 63;
  const int quad = lane >> 4, l16 = lane & 15;
  const int bh = blockIdx.x >> 6;
  const int chunk = blockIdx.x & 63;
  const int b = bh >> 3, h = bh & 7;
  const int n0 = chunk * 64;
  const f32x4 zf = {0.f, 0.f, 0.f, 0.f};

  /* load Q chunk: scale, split fp16 hi/lo, diag partials */
  {
    const int r = tid >> 2, s2 = tid & 3;
    const float* src = Q + ((size_t)(b * NN + n0 + r)) * DMM + h * DH + s2 * 16;
    float sq = 0.f;
    unsigned short th[16], tl[16];
#pragma unroll
    for (int t = 0; t < 4; ++t) {
      float4 g = *(const float4*)(src + t * 4);
      float f[4] = {g.x * NRM, g.y * NRM, g.z * NRM, g.w * NRM};
#pragma unroll
      for (int j = 0; j < 4; ++j) {
        sq = fmaf(f[j], f[j], sq);
        __half hh = __float2half(f[j]);
        th[t * 4 + j] = __half_as_ushort(hh);
        tl[t * 4 + j] = f2h(f[j] - __half2float(hh));
      }
    }
    diag4[r][s2] = sq;
    *(uint4*)&Qhh[r][s2 * 16]     = *(uint4*)&th[0];
    *(uint4*)&Qhh[r][s2 * 16 + 8] = *(uint4*)&th[8];
    *(uint4*)&Qhl[r][s2 * 16]     = *(uint4*)&tl[0];
    *(uint4*)&Qhl[r][s2 * 16 + 8] = *(uint4*)&tl[8];
    ksum_s[tid] = ksum[bh * MM + tid];
  }
  __syncthreads();
  if (tid < 64)
    diag_s[tid] = 0.5f * (diag4[tid][0] + diag4[tid][1] + diag4[tid][2] + diag4[tid][3]);

  /* dd GEMM: rows 64 x wave's 64 feature-cols, K=64, split-fp16 (hh+hl+lh) */
  const int wn0 = wid * 64;
  f32x4 acc[4][4];
#pragma unroll
  for (int i = 0; i < 4; ++i)
#pragma unroll
    for (int j = 0; j < 4; ++j) acc[i][j] = zf;

#pragma unroll
  for (int ks = 0; ks < 2; ++ks) {
    fp16x8 afh[4], afl[4], bfh[4], bfl[4];
#pragma unroll
    for (int t = 0; t < 4; ++t) {
      afh[t] = *(const fp16x8*)&Qhh[t * 16 + l16][ks * 32 + quad * 8];
      afl[t] = *(const fp16x8*)&Qhl[t * 16 + l16][ks * 32 + quad * 8];
      const size_t po = (size_t)(wn0 + t * 16 + l16) * 64 + ks * 32 + quad * 8;
      bfh[t] = *(const fp16x8*)(phh + po);
      bfl[t] = *(const fp16x8*)(phl + po);
    }
#pragma unroll
    for (int mt = 0; mt < 4; ++mt)
#pragma unroll
      for (int nt = 0; nt < 4; ++nt) {
        acc[mt][nt] = __builtin_amdgcn_mfma_f32_16x16x32_f16(afh[mt], bfh[nt], acc[mt][nt], 0, 0, 0);
        acc[mt][nt] = __builtin_amdgcn_mfma_f32_16x16x32_f16(afh[mt], bfl[nt], acc[mt][nt], 0, 0, 0);
        acc[mt][nt] = __builtin_amdgcn_mfma_f32_16x16x32_f16(afl[mt], bfh[nt], acc[mt][nt], 0, 0, 0);
      }
  }

  /* per-row wave-local max -> LDS */
#pragma unroll
  for (int mt = 0; mt < 4; ++mt)
#pragma unroll
    for (int reg = 0; reg < 4; ++reg) {
      float v = fmaxf(fmaxf(acc[mt][0][reg], acc[mt][1][reg]),
                      fmaxf(acc[mt][2][reg], acc[mt][3][reg]));
      v = fmaxf(v, __shfl_xor(v, 1));
      v = fmaxf(v, __shfl_xor(v, 2));
      v = fmaxf(v, __shfl_xor(v, 4));
      v = fmaxf(v, __shfl_xor(v, 8));
      if (l16 == 0) red[wid][mt * 16 + quad * 4 + reg] = v;
    }
  __syncthreads();

  /* qp = RATIO*(exp(dd - diag - stab) + EPS); dsum partials; qp -> fp16 LDS */
  float ksv[4];
#pragma unroll
  for (int nt = 0; nt < 4; ++nt) ksv[nt] = ksum_s[wn0 + nt * 16 + l16];
#pragma unroll
  for (int mt = 0; mt < 4; ++mt)
#pragma unroll
    for (int reg = 0; reg < 4; ++reg) {
      const int row = mt * 16 + quad * 4 + reg;
      float stab = fmaxf(fmaxf(red[0][row], red[1][row]),
                         fmaxf(red[2][row], red[3][row]));
      float base = diag_s[row] + stab;
      float dsum = 0.f;
#pragma unroll
      for (int nt = 0; nt < 4; ++nt) {
        float p = RATIO * (__expf(acc[mt][nt][reg] - base) + EPSF);
        acc[mt][nt][reg] = p;
        dsum = fmaf(p, ksv[nt], dsum);
      }
      dsum += __shfl_xor(dsum, 1);
      dsum += __shfl_xor(dsum, 2);
      dsum += __shfl_xor(dsum, 4);
      dsum += __shfl_xor(dsum, 8);
      if (l16 == 0) dred[wid][row] = dsum;
#pragma unroll
      for (int nt = 0; nt < 4; ++nt)
        qp_s[row][wn0 + nt * 16 + l16] = f2h(acc[mt][nt][reg]);
    }
  __syncthreads();
  if (tid < 64)
    dinv_s[tid] = 1.0f / (dred[0][tid] + dred[1][tid] + dred[2][tid] + dred[3][tid]);

  /* PV: out[64 x wave's 16 d-cols] = qp[64x256] @ ctxT rows, K=256 */
  const int wn2 = wid * 16;
  f32x4 acc2[4];
#pragma unroll
  for (int mt = 0; mt < 4; ++mt) acc2[mt] = zf;
#pragma unroll
  for (int ksp = 0; ksp < 8; ++ksp) {
    fp16x8 bv = *(const fp16x8*)(ctxT_h + ((size_t)bh * DH + wn2 + l16) * MM + ksp * 32 + quad * 8);
    fp16x8 ap[4];
#pragma unroll
    for (int mt = 0; mt < 4; ++mt)
      ap[mt] = *(const fp16x8*)&qp_s[mt * 16 + l16][ksp * 32 + quad * 8];
#pragma unroll
    for (int mt = 0; mt < 4; ++mt)
      acc2[mt] = __builtin_amdgcn_mfma_f32_16x16x32_f16(ap[mt], bv, acc2[mt], 0, 0, 0);
  }
  __syncthreads();

  /* epilogue: scale by 1/dsum, store */
#pragma unroll
  for (int mt = 0; mt < 4; ++mt)
#pragma unroll
    for (int reg = 0; reg < 4; ++reg) {
      const int row = mt * 16 + quad * 4 + reg;
      Q[((size_t)(b * NN + n0 + row)) * DMM + h * DH + wn2 + l16] =
          acc2[mt][reg] * dinv_s[row];
    }
}

/* ---------------- launcher -------------------------------------------------- */
extern "C" void kernel_launch(void* const* d_in, const int* in_sizes, int n_in,
                              void* d_out, int out_size, void* d_ws, size_t ws_size,
                              hipStream_t stream)
{
  (void)in_sizes; (void)n_in; (void)out_size;
  const float* x    = (const float*)d_in[0];
  const float* Wq   = (const float*)d_in[2];
  const float* Wk   = (const float*)d_in[3];
  const float* Wv   = (const float*)d_in[4];
  const float* Wo   = (const float*)d_in[5];
  const float* bo   = (const float*)d_in[6];
  const float* proj = (const float*)d_in[7];
  float* out = (float*)d_out;

  const size_t WSZ = (size_t)DMM * DMM;
  const size_t XSP = (size_t)BB * NN * DMM;            /* elems per activation plane */
  const size_t wbuf_f = (8 * WSZ * 2 + 3) / 4;
  const size_t LSZ = (size_t)BB * LHH * NN * DH;       /* u16 elems per local buf */
  const size_t lbuf_f = (3 * LSZ * 2 + 3) / 4;
  const size_t fixed_f = (size_t)3 * XSP + (size_t)BB * GHH * MM * DH
                       + (size_t)BB * GHH * MM + 16 + MM * DH + MM * DH + 16
                       + wbuf_f + 16 + lbuf_f + 16;

  /* region: time-shared between ctxp/ksump (FAVOR phase) and xH/xL split
   * activation planes (GEMM phases) — live ranges are disjoint.            */
  int split = 8, use_pre = 0;
  for (int s = 32; s >= 8; s >>= 1) {
    size_t part = (size_t)BB * GHH * s * (MM * DH + MM);
    size_t region = part > XSP ? part : XSP;
    if ((fixed_f + region) * 4 <= ws_size) { split = s; use_pre = 1; break; }
  }
  if (!use_pre) {
    for (int s = 32; s >= 8; s >>= 1) {
      size_t need = (fixed_f + (size_t)BB * GHH * s * (MM * DH + MM)) * 4;
      if (need <= ws_size) { split = s; break; }
    }
  }
  size_t part_f = (size_t)BB * GHH * split * (MM * DH + MM);
  size_t region_f = (use_pre && XSP > part_f) ? XSP : part_f;

  float* Qb    = (float*)d_ws;
  float* Kb    = Qb + XSP;
  float* Vb    = Kb + XSP;
  float* region = Vb + XSP;
  float* ctxp  = region;
  float* ksump = ctxp + (size_t)BB * GHH * split * MM * DH;
  unsigned short* xH = (unsigned short*)region;
  unsigned short* xL = xH + XSP;
  float* ctx   = region + region_f;                 /* region holds ctxT fp16 */
  unsigned short* ctxT_h = (unsigned short*)ctx;
  float* ksum  = ctx + (size_t)BB * GHH * MM * DH;
  unsigned* stab = (unsigned*)(ksum + BB * GHH * MM);
  float* projT = (float*)(stab + 16);
  unsigned short* proj_hh = (unsigned short*)(projT + MM * DH);
  unsigned short* proj_hl = proj_hh + MM * DH;
  unsigned short* wsp = proj_hl + MM * DH;
  unsigned short* WqH = wsp;            unsigned short* WqL = wsp + WSZ;
  unsigned short* WkH = wsp + 2 * WSZ;  unsigned short* WkL = wsp + 3 * WSZ;
  unsigned short* WvH = wsp + 4 * WSZ;  unsigned short* WvL = wsp + 5 * WSZ;
  unsigned short* WoH = wsp + 6 * WSZ;  unsigned short* WoL = wsp + 7 * WSZ;
  unsigned short* Qlh = wsp + 8 * WSZ;
  unsigned short* Klh = Qlh + LSZ;
  unsigned short* Vtl = Klh + LSZ;

  dim3 blk(256);
  dim3 mg(DMM / 128, (BB * NN) / 128);
  const int wgrid = (int)(WSZ / 256);
  const int agrid = (int)(XSP / 1024);

  w_split<<<wgrid, blk, 0, stream>>>(Wq, WqH, WqL);
  w_split<<<wgrid, blk, 0, stream>>>(Wk, WkH, WkL);
  w_split<<<wgrid, blk, 0, stream>>>(Wv, WvH, WvL);
  w_split<<<wgrid, blk, 0, stream>>>(Wo, WoH, WoL);
  if (use_pre) {
    a_split<<<agrid, blk, 0, stream>>>(x, xH, xL);
    gemm_mfma_pre<<<mg, blk, 0, stream>>>(xH, xL, WqH, WqL, nullptr, Qb, DMM, DMM);
    gemm_mfma_pre<<<mg, blk, 0, stream>>>(xH, xL, WkH, WkL, nullptr, Kb, DMM, DMM);
    gemm_mfma_pre<<<mg, blk, 0, stream>>>(xH, xL, WvH, WvL, nullptr, Vb, DMM, DMM);
  } else {
    gemm_mfma<<<mg, blk, 0, stream>>>(x, WqH, WqL, nullptr, Qb, DMM, DMM);
    gemm_mfma<<<mg, blk, 0, stream>>>(x, WkH, WkL, nullptr, Kb, DMM, DMM);
    gemm_mfma<<<mg, blk, 0, stream>>>(x, WvH, WvL, nullptr, Vb, DMM, DMM);
  }
  rot_qk<<<(BB * LHH * NN) / 256, blk, 0, stream>>>(Qb, Kb, Qlh, Klh);
  v_trans<<<dim3(NN / 64, LHH, BB), blk, 0, stream>>>(Vb, Vtl);
  init_stab<<<1, 64, 0, stream>>>(stab);
  transpose_proj<<<64, blk, 0, stream>>>(proj, projT, proj_hh, proj_hl);
  favor_kstab2<<<BB * GHH * (NN / 64), blk, 0, stream>>>(Kb, projT, stab);
  favor_ctx2<<<BB * GHH * split, blk, 0, stream>>>(Kb, Vb, projT, stab, ctxp, ksump, split);
  favor_reduce<<<(BB * GHH * MM * DH) / 256, blk, 0, stream>>>(ctxp, ksump, ctxT_h, ksum, split);
  favor_out_mfma<<<BB * GHH * (NN / 64), blk, 0, stream>>>(Qb, proj_hh, proj_hl, ctxT_h, ksum);
  local_attn2<<<dim3(NWIN, LHH, BB), blk, 0, stream>>>(Qlh, Klh, Vtl, Qb);
  if (use_pre) {
    a_split<<<agrid, blk, 0, stream>>>(Qb, xH, xL);
    gemm_mfma_pre<<<mg, blk, 0, stream>>>(xH, xL, WoH, WoL, bo, out, DMM, DMM);
  } else {
    gemm_mfma<<<mg, blk, 0, stream>>>(Qb, WoH, WoL, bo, out, DMM, DMM);
  }
}

// Round 3
// 754.568 us; speedup vs baseline: 1.3389x; 1.2402x over previous
//
#include <hip/hip_runtime.h>
#include <hip/hip_fp16.h>
#include <math.h>

#define BB 4
#define NN 4096
#define DMM 768
#define HHH 12
#define LHH 4
#define GHH 8
#define DH 64
#define MM 256
#define WW 128
#define NWIN (NN/WW)
#define EPSF 1.0e-4f
#define NRM 0.35355339059327373f   /* 64^-0.25 */
#define NRM2 0.125f                /* 64^-0.5  */
#define RATIO 0.0625f              /* 256^-0.5 */
#define LN1E4_32 0.28782313662425572f  /* ln(10000)/32 */

using bf16x8 = __attribute__((ext_vector_type(8))) short;
using fp16x8 = __attribute__((ext_vector_type(8))) _Float16;
using f32x4  = __attribute__((ext_vector_type(4))) float;

static __device__ __forceinline__ unsigned enc_f32(float f) {
  unsigned u = __float_as_uint(f);
  return (u & 0x80000000u) ? ~u : (u | 0x80000000u);
}
static __device__ __forceinline__ float dec_f32(unsigned u) {
  unsigned b = (u & 0x80000000u) ? (u ^ 0x80000000u) : ~u;
  return __uint_as_float(b);
}
static __device__ __forceinline__ unsigned short f2h(float x) {
  return __half_as_ushort(__float2half(x));
}

/* ------- W prep: transpose to [n][k] and split into bf16 hi/lo planes ----- */
__global__ __launch_bounds__(256) void w_split(
    const float* __restrict__ W, unsigned short* __restrict__ Whi,
    unsigned short* __restrict__ Wlo)
{
  int o = blockIdx.x * 256 + threadIdx.x;     /* 768*768 */
  int k = o / DMM, n = o % DMM;
  float x = W[o];
  unsigned u = __float_as_uint(x);
  unsigned h = u & 0xFFFF0000u;
  float lf = x - __uint_as_float(h);
  Whi[(size_t)n * DMM + k] = (unsigned short)(u >> 16);
  Wlo[(size_t)n * DMM + k] = (unsigned short)(__float_as_uint(lf) >> 16);
}

/* ------- activation prep: split fp32 [M][K] into bf16 hi/lo planes -------- */
__global__ __launch_bounds__(256) void a_split(
    const float* __restrict__ A, unsigned short* __restrict__ Ahi,
    unsigned short* __restrict__ Alo)
{
  size_t o = ((size_t)blockIdx.x * 256 + threadIdx.x) * 4;
  float4 v = *(const float4*)(A + o);
  float f[4] = {v.x, v.y, v.z, v.w};
  unsigned short hi[4], lo[4];
#pragma unroll
  for (int i = 0; i < 4; ++i) {
    unsigned u = __float_as_uint(f[i]);
    unsigned h = u & 0xFFFF0000u;
    float l = f[i] - __uint_as_float(h);
    hi[i] = (unsigned short)(u >> 16);
    lo[i] = (unsigned short)(__float_as_uint(l) >> 16);
  }
  *(uint2*)(Ahi + o) = *(uint2*)&hi[0];
  *(uint2*)(Alo + o) = *(uint2*)&lo[0];
}

/* ------- split-bf16 MFMA GEMM (fallback: converts A in-kernel) ------------ */
__global__ __launch_bounds__(256) void gemm_mfma(
    const float* __restrict__ A,
    const unsigned short* __restrict__ Bhi, const unsigned short* __restrict__ Blo,
    const float* __restrict__ bias, float* __restrict__ C, int K, int Nc)
{
  __shared__ unsigned short Ah[128][40];
  __shared__ unsigned short Al[128][40];
  __shared__ unsigned short Bh[128][40];
  __shared__ unsigned short Bl[128][40];

  const int tid = threadIdx.x;
  const int wid = tid >> 6, lane = tid & 63;
  const int quad = lane >> 4, l16 = lane & 15;
  const int row0 = blockIdx.y * 128;
  const int col0 = blockIdx.x * 128;
  const int wm = (wid & 1) * 64, wn = (wid >> 1) * 64;
  const int sr = tid >> 1;
  const int sk = (tid & 1) * 16;

  f32x4 acc[4][4];
  const f32x4 zf = {0.f, 0.f, 0.f, 0.f};
#pragma unroll
  for (int i = 0; i < 4; ++i)
#pragma unroll
    for (int j = 0; j < 4; ++j) acc[i][j] = zf;

  for (int k0 = 0; k0 < K; k0 += 32) {
    __syncthreads();
    {
      const float* a = A + (size_t)(row0 + sr) * K + k0 + sk;
      float fv[16];
      *(float4*)&fv[0]  = *(const float4*)(a);
      *(float4*)&fv[4]  = *(const float4*)(a + 4);
      *(float4*)&fv[8]  = *(const float4*)(a + 8);
      *(float4*)&fv[12] = *(const float4*)(a + 12);
      unsigned hw[8], lw[8];
#pragma unroll
      for (int p = 0; p < 8; ++p) {
        float x0 = fv[2 * p], x1 = fv[2 * p + 1];
        unsigned u0 = __float_as_uint(x0), u1 = __float_as_uint(x1);
        unsigned h0 = u0 & 0xFFFF0000u, h1 = u1 & 0xFFFF0000u;
        float l0 = x0 - __uint_as_float(h0);
        float l1 = x1 - __uint_as_float(h1);
        hw[p] = (u0 >> 16) | h1;
        lw[p] = (__float_as_uint(l0) >> 16) | (__float_as_uint(l1) & 0xFFFF0000u);
      }
      *(uint4*)&Ah[sr][sk]     = *(uint4*)&hw[0];
      *(uint4*)&Ah[sr][sk + 8] = *(uint4*)&hw[4];
      *(uint4*)&Al[sr][sk]     = *(uint4*)&lw[0];
      *(uint4*)&Al[sr][sk + 8] = *(uint4*)&lw[4];
    }
    {
      const unsigned short* bh = Bhi + (size_t)(col0 + sr) * DMM + k0 + sk;
      const unsigned short* bl = Blo + (size_t)(col0 + sr) * DMM + k0 + sk;
      *(uint4*)&Bh[sr][sk]     = *(const uint4*)(bh);
      *(uint4*)&Bh[sr][sk + 8] = *(const uint4*)(bh + 8);
      *(uint4*)&Bl[sr][sk]     = *(const uint4*)(bl);
      *(uint4*)&Bl[sr][sk + 8] = *(const uint4*)(bl + 8);
    }
    __syncthreads();

    bf16x8 afh[4], afl[4], bfh[4], bfl[4];
#pragma unroll
    for (int t = 0; t < 4; ++t) {
      afh[t] = *(const bf16x8*)&Ah[wm + t * 16 + l16][quad * 8];
      afl[t] = *(const bf16x8*)&Al[wm + t * 16 + l16][quad * 8];
      bfh[t] = *(const bf16x8*)&Bh[wn + t * 16 + l16][quad * 8];
      bfl[t] = *(const bf16x8*)&Bl[wn + t * 16 + l16][quad * 8];
    }
#pragma unroll
    for (int ti = 0; ti < 4; ++ti)
#pragma unroll
      for (int tj = 0; tj < 4; ++tj) {
        acc[ti][tj] = __builtin_amdgcn_mfma_f32_16x16x32_bf16(afh[ti], bfh[tj], acc[ti][tj], 0, 0, 0);
        acc[ti][tj] = __builtin_amdgcn_mfma_f32_16x16x32_bf16(afh[ti], bfl[tj], acc[ti][tj], 0, 0, 0);
        acc[ti][tj] = __builtin_amdgcn_mfma_f32_16x16x32_bf16(afl[ti], bfh[tj], acc[ti][tj], 0, 0, 0);
      }
  }

  float bv[4] = {0.f, 0.f, 0.f, 0.f};
  if (bias) {
#pragma unroll
    for (int tj = 0; tj < 4; ++tj) bv[tj] = bias[col0 + wn + tj * 16 + l16];
  }
#pragma unroll
  for (int ti = 0; ti < 4; ++ti) {
    const int gr = row0 + wm + ti * 16 + quad * 4;
#pragma unroll
    for (int tj = 0; tj < 4; ++tj) {
      const int gc = col0 + wn + tj * 16 + l16;
      float* cp = C + (size_t)gr * Nc + gc;
#pragma unroll
      for (int r = 0; r < 4; ++r)
        cp[(size_t)r * Nc] = acc[ti][tj][r] + bv[tj];
    }
  }
}

/* ------- split-bf16 MFMA GEMM, pre-split A planes (hot path) --------------- */
__global__ __launch_bounds__(256) void gemm_mfma_pre(
    const unsigned short* __restrict__ Ahi, const unsigned short* __restrict__ Alo,
    const unsigned short* __restrict__ Bhi, const unsigned short* __restrict__ Blo,
    const float* __restrict__ bias, float* __restrict__ C, int K, int Nc)
{
  __shared__ unsigned short Ah[128][40];
  __shared__ unsigned short Al[128][40];
  __shared__ unsigned short Bh[128][40];
  __shared__ unsigned short Bl[128][40];

  const int tid = threadIdx.x;
  const int wid = tid >> 6, lane = tid & 63;
  const int quad = lane >> 4, l16 = lane & 15;
  const int row0 = blockIdx.y * 128;
  const int col0 = blockIdx.x * 128;
  const int wm = (wid & 1) * 64, wn = (wid >> 1) * 64;
  const int sr = tid >> 1;
  const int sk = (tid & 1) * 16;

  f32x4 acc[4][4];
  const f32x4 zf = {0.f, 0.f, 0.f, 0.f};
#pragma unroll
  for (int i = 0; i < 4; ++i)
#pragma unroll
    for (int j = 0; j < 4; ++j) acc[i][j] = zf;

  for (int k0 = 0; k0 < K; k0 += 32) {
    __syncthreads();
    {
      const unsigned short* ah = Ahi + (size_t)(row0 + sr) * K + k0 + sk;
      const unsigned short* al = Alo + (size_t)(row0 + sr) * K + k0 + sk;
      *(uint4*)&Ah[sr][sk]     = *(const uint4*)(ah);
      *(uint4*)&Ah[sr][sk + 8] = *(const uint4*)(ah + 8);
      *(uint4*)&Al[sr][sk]     = *(const uint4*)(al);
      *(uint4*)&Al[sr][sk + 8] = *(const uint4*)(al + 8);
      const unsigned short* bh = Bhi + (size_t)(col0 + sr) * K + k0 + sk;
      const unsigned short* bl = Blo + (size_t)(col0 + sr) * K + k0 + sk;
      *(uint4*)&Bh[sr][sk]     = *(const uint4*)(bh);
      *(uint4*)&Bh[sr][sk + 8] = *(const uint4*)(bh + 8);
      *(uint4*)&Bl[sr][sk]     = *(const uint4*)(bl);
      *(uint4*)&Bl[sr][sk + 8] = *(const uint4*)(bl + 8);
    }
    __syncthreads();

    bf16x8 afh[4], afl[4], bfh[4], bfl[4];
#pragma unroll
    for (int t = 0; t < 4; ++t) {
      afh[t] = *(const bf16x8*)&Ah[wm + t * 16 + l16][quad * 8];
      afl[t] = *(const bf16x8*)&Al[wm + t * 16 + l16][quad * 8];
      bfh[t] = *(const bf16x8*)&Bh[wn + t * 16 + l16][quad * 8];
      bfl[t] = *(const bf16x8*)&Bl[wn + t * 16 + l16][quad * 8];
    }
#pragma unroll
    for (int ti = 0; ti < 4; ++ti)
#pragma unroll
      for (int tj = 0; tj < 4; ++tj) {
        acc[ti][tj] = __builtin_amdgcn_mfma_f32_16x16x32_bf16(afh[ti], bfh[tj], acc[ti][tj], 0, 0, 0);
        acc[ti][tj] = __builtin_amdgcn_mfma_f32_16x16x32_bf16(afh[ti], bfl[tj], acc[ti][tj], 0, 0, 0);
        acc[ti][tj] = __builtin_amdgcn_mfma_f32_16x16x32_bf16(afl[ti], bfh[tj], acc[ti][tj], 0, 0, 0);
      }
  }

  float bv[4] = {0.f, 0.f, 0.f, 0.f};
  if (bias) {
#pragma unroll
    for (int tj = 0; tj < 4; ++tj) bv[tj] = bias[col0 + wn + tj * 16 + l16];
  }
#pragma unroll
  for (int ti = 0; ti < 4; ++ti) {
    const int gr = row0 + wm + ti * 16 + quad * 4;
#pragma unroll
    for (int tj = 0; tj < 4; ++tj) {
      const int gc = col0 + wn + tj * 16 + l16;
      float* cp = C + (size_t)gr * Nc + gc;
#pragma unroll
      for (int r = 0; r < 4; ++r)
        cp[(size_t)r * Nc] = acc[ti][tj][r] + bv[tj];
    }
  }
}

/* ---------------- init global stabilizer ---------------------------------- */
__global__ void init_stab(unsigned* stab_enc) {
  if (threadIdx.x == 0 && blockIdx.x == 0) *stab_enc = 0x00800000u; /* enc(-FLT_MAX) */
}

/* ---------------- proj prep: projT fp32 + [m][d] fp16 hi/lo planes --------- */
__global__ __launch_bounds__(256) void transpose_proj(
    const float* __restrict__ proj, float* __restrict__ projT,
    unsigned short* __restrict__ phh, unsigned short* __restrict__ phl)
{
  int o = blockIdx.x * 256 + threadIdx.x;   /* 16384 */
  int k = o >> 8, m = o & 255;
  float v = proj[m * 64 + k];
  projT[k * 256 + m] = v;
  __half hh = __float2half(v);
  float lf = v - __half2float(hh);
  phh[m * 64 + k] = __half_as_ushort(hh);
  phl[m * 64 + k] = f2h(lf);
}

/* ---------------- rotary prep for local heads: Q(scaled)/K -> fp16 --------- */
__global__ __launch_bounds__(256) void rot_qk(
    const float* __restrict__ Qb, const float* __restrict__ Kb,
    unsigned short* __restrict__ Qlh, unsigned short* __restrict__ Klh)
{
  int idx = blockIdx.x * 256 + threadIdx.x;    /* (b*LHH+h)*NN + n : 65536 */
  int n = idx & (NN - 1);
  int bh = idx >> 12;
  int b = bh >> 2, h = bh & 3;
  const float* qs = Qb + ((size_t)(b * NN + n)) * DMM + GHH * DH + h * DH;
  const float* ks = Kb + ((size_t)(b * NN + n)) * DMM + GHH * DH + h * DH;
  float q[64], k[64];
#pragma unroll
  for (int t = 0; t < 16; ++t) {
    *(float4*)&q[t * 4] = *(const float4*)(qs + t * 4);
    *(float4*)&k[t * 4] = *(const float4*)(ks + t * 4);
  }
  unsigned short qo[64], ko[64];
#pragma unroll
  for (int i = 0; i < 32; ++i) {
    float invf = __expf((float)i * -LN1E4_32);
    float th = (float)n * invf;
    float s, c;
    sincosf(th, &s, &c);
    qo[i]      = f2h(fmaf(q[i], c, -q[i + 32] * s) * NRM2);
    qo[i + 32] = f2h(fmaf(q[i + 32], c, q[i] * s) * NRM2);
    ko[i]      = f2h(fmaf(k[i], c, -k[i + 32] * s));
    ko[i + 32] = f2h(fmaf(k[i + 32], c, k[i] * s));
  }
  unsigned short* qd = Qlh + (size_t)idx * 64;
  unsigned short* kd = Klh + (size_t)idx * 64;
#pragma unroll
  for (int t = 0; t < 8; ++t) {
    *(uint4*)(qd + t * 8) = *(uint4*)&qo[t * 8];
    *(uint4*)(kd + t * 8) = *(uint4*)&ko[t * 8];
  }
}

/* ---------------- V transpose for local heads: fp16 [b][h][d][n] ----------- */
__global__ __launch_bounds__(256) void v_trans(
    const float* __restrict__ Vb, unsigned short* __restrict__ Vt)
{
  __shared__ unsigned short T[64][72];
  const int nb = blockIdx.x, h = blockIdx.y, b = blockIdx.z;
  const int n0 = nb * 64;
  const int tid = threadIdx.x;
  {
    int r = tid >> 2, g = tid & 3;
    const float* src = Vb + ((size_t)(b * NN + n0 + r)) * DMM + GHH * DH + h * DH + g * 16;
#pragma unroll
    for (int t = 0; t < 4; ++t) {
      float4 v = *(const float4*)(src + t * 4);
      T[g * 16 + t * 4 + 0][r] = f2h(v.x);
      T[g * 16 + t * 4 + 1][r] = f2h(v.y);
      T[g * 16 + t * 4 + 2][r] = f2h(v.z);
      T[g * 16 + t * 4 + 3][r] = f2h(v.w);
    }
  }
  __syncthreads();
  {
    int d = tid >> 2, g = tid & 3;
    unsigned short* dst = Vt + ((size_t)(b * LHH + h) * DH + d) * NN + n0 + g * 16;
    *(uint4*)dst       = *(uint4*)&T[d][g * 16];
    *(uint4*)(dst + 8) = *(uint4*)&T[d][g * 16 + 8];
  }
}

/* ---------------- local attention via f16 MFMA (flash-style) --------------- */
__global__ __launch_bounds__(256) void local_attn2(
    const unsigned short* __restrict__ Qlh, const unsigned short* __restrict__ Klh,
    const unsigned short* __restrict__ Vt, float* __restrict__ Qb)
{
  __shared__ unsigned short Pl[4][32][72];
  const int w = blockIdx.x, h = blockIdx.y, b = blockIdx.z;
  const int tid = threadIdx.x;
  const int wid = tid >> 6, lane = tid & 63;
  const int quad = lane >> 4, l16 = lane & 15;
  const int bh = b * LHH + h;
  const int qn0 = w * WW + wid * 32;

  fp16x8 Aq[2][2];
#pragma unroll
  for (int mt = 0; mt < 2; ++mt)
#pragma unroll
    for (int ks = 0; ks < 2; ++ks)
      Aq[mt][ks] = *(const fp16x8*)(Qlh + ((size_t)bh * NN + qn0 + mt * 16 + l16) * 64 + ks * 32 + quad * 8);

  float m_run[8], l_run[8];
  f32x4 Oacc[2][4];
  const f32x4 zf = {0.f, 0.f, 0.f, 0.f};
#pragma unroll
  for (int r = 0; r < 8; ++r) { m_run[r] = -3.4e38f; l_run[r] = 0.f; }
#pragma unroll
  for (int mt = 0; mt < 2; ++mt)
#pragma unroll
    for (int nt = 0; nt < 4; ++nt) Oacc[mt][nt] = zf;

  const int wb_lo = (w == 0) ? 0 : w - 1;
  const int wb_hi = (w == NWIN - 1) ? w : w + 1;
  for (int wb = wb_lo; wb <= wb_hi; ++wb) {
    for (int half = 0; half < 2; ++half) {
      const int kn0 = wb * WW + half * 64;
      f32x4 sacc[2][4];
#pragma unroll
      for (int mt = 0; mt < 2; ++mt)
#pragma unroll
        for (int nt = 0; nt < 4; ++nt) sacc[mt][nt] = zf;

#pragma unroll
      for (int ks = 0; ks < 2; ++ks) {
        fp16x8 Bk[4];
#pragma unroll
        for (int nt = 0; nt < 4; ++nt)
          Bk[nt] = *(const fp16x8*)(Klh + ((size_t)bh * NN + kn0 + nt * 16 + l16) * 64 + ks * 32 + quad * 8);
#pragma unroll
        for (int mt = 0; mt < 2; ++mt)
#pragma unroll
          for (int nt = 0; nt < 4; ++nt)
            sacc[mt][nt] = __builtin_amdgcn_mfma_f32_16x16x32_f16(Aq[mt][ks], Bk[nt], sacc[mt][nt], 0, 0, 0);
      }

      /* online softmax per row (row = mt*16 + quad*4 + reg) */
#pragma unroll
      for (int mt = 0; mt < 2; ++mt) {
#pragma unroll
        for (int reg = 0; reg < 4; ++reg) {
          const int r8 = mt * 4 + reg;
          float v = fmaxf(fmaxf(sacc[mt][0][reg], sacc[mt][1][reg]),
                          fmaxf(sacc[mt][2][reg], sacc[mt][3][reg]));
          v = fmaxf(v, __shfl_xor(v, 1));
          v = fmaxf(v, __shfl_xor(v, 2));
          v = fmaxf(v, __shfl_xor(v, 4));
          v = fmaxf(v, __shfl_xor(v, 8));
          float mnew = fmaxf(m_run[r8], v);
          float alpha = __expf(m_run[r8] - mnew);
          m_run[r8] = mnew;
          float ps = 0.f;
#pragma unroll
          for (int nt = 0; nt < 4; ++nt) {
            float p = __expf(sacc[mt][nt][reg] - mnew);
            sacc[mt][nt][reg] = p;
            ps += p;
          }
          ps += __shfl_xor(ps, 1);
          ps += __shfl_xor(ps, 2);
          ps += __shfl_xor(ps, 4);
          ps += __shfl_xor(ps, 8);
          l_run[r8] = l_run[r8] * alpha + ps;
#pragma unroll
          for (int nt = 0; nt < 4; ++nt) Oacc[mt][nt][reg] *= alpha;
        }
      }

      /* write P fp16 (C-layout -> [qrow][key] in LDS, wave-local) */
#pragma unroll
      for (int mt = 0; mt < 2; ++mt)
#pragma unroll
        for (int nt = 0; nt < 4; ++nt)
#pragma unroll
          for (int reg = 0; reg < 4; ++reg)
            Pl[wid][mt * 16 + quad * 4 + reg][nt * 16 + l16] = f2h(sacc[mt][nt][reg]);

      /* PV */
#pragma unroll
      for (int kstep = 0; kstep < 2; ++kstep) {
        fp16x8 Ap[2];
#pragma unroll
        for (int mt = 0; mt < 2; ++mt)
          Ap[mt] = *(const fp16x8*)&Pl[wid][mt * 16 + l16][kstep * 32 + quad * 8];
        fp16x8 Bv[4];
#pragma unroll
        for (int nt = 0; nt < 4; ++nt)
          Bv[nt] = *(const fp16x8*)(Vt + ((size_t)bh * DH + nt * 16 + l16) * NN + kn0 + kstep * 32 + quad * 8);
#pragma unroll
        for (int mt = 0; mt < 2; ++mt)
#pragma unroll
          for (int nt = 0; nt < 4; ++nt)
            Oacc[mt][nt] = __builtin_amdgcn_mfma_f32_16x16x32_f16(Ap[mt], Bv[nt], Oacc[mt][nt], 0, 0, 0);
      }
    }
  }

  /* epilogue: divide by l, store fp32 into Qb local-head columns */
#pragma unroll
  for (int mt = 0; mt < 2; ++mt)
#pragma unroll
    for (int reg = 0; reg < 4; ++reg) {
      const float inv = 1.0f / l_run[mt * 4 + reg];
      const int n = qn0 + mt * 16 + quad * 4 + reg;
      float* dst = Qb + ((size_t)(b * NN + n)) * DMM + GHH * DH + h * DH;
#pragma unroll
      for (int nt = 0; nt < 4; ++nt)
        dst[nt * 16 + l16] = Oacc[mt][nt][reg] * inv;
    }
}

/* ---------------- FAVOR: global max of dd_k via MFMA ----------------------- */
__global__ __launch_bounds__(256) void favor_kstab_mfma(
    const float* __restrict__ Kg, const unsigned short* __restrict__ phh,
    const unsigned short* __restrict__ phl, unsigned* __restrict__ stab_enc)
{
  __shared__ unsigned short Khh[64][72];
  __shared__ unsigned short Khl[64][72];
  __shared__ float wred[4];
  const int tid = threadIdx.x;
  const int wid = tid >> 6, lane = tid & 63;
  const int quad = lane >> 4, l16 = lane & 15;
  const int chunk = blockIdx.x & 63;
  const int bh = blockIdx.x >> 6;
  const int b = bh >> 3, h = bh & 7;
  const int n0 = chunk * 64;
  const f32x4 zf = {0.f, 0.f, 0.f, 0.f};

  {
    const int r = tid >> 2, s2 = tid & 3;
    const float* ksrc = Kg + ((size_t)(b * NN + n0 + r)) * DMM + h * DH + s2 * 16;
    unsigned short th[16], tl[16];
#pragma unroll
    for (int t = 0; t < 4; ++t) {
      float4 g = *(const float4*)(ksrc + t * 4);
      float f[4] = {g.x * NRM, g.y * NRM, g.z * NRM, g.w * NRM};
#pragma unroll
      for (int j = 0; j < 4; ++j) {
        __half hh = __float2half(f[j]);
        th[t * 4 + j] = __half_as_ushort(hh);
        tl[t * 4 + j] = f2h(f[j] - __half2float(hh));
      }
    }
    *(uint4*)&Khh[r][s2 * 16]     = *(uint4*)&th[0];
    *(uint4*)&Khh[r][s2 * 16 + 8] = *(uint4*)&th[8];
    *(uint4*)&Khl[r][s2 * 16]     = *(uint4*)&tl[0];
    *(uint4*)&Khl[r][s2 * 16 + 8] = *(uint4*)&tl[8];
  }
  __syncthreads();

  const int wn0 = wid * 64;
  f32x4 acc[4][4];
#pragma unroll
  for (int i = 0; i < 4; ++i)
#pragma unroll
    for (int j = 0; j < 4; ++j) acc[i][j] = zf;

#pragma unroll
  for (int ks = 0; ks < 2; ++ks) {
    fp16x8 afh[4], afl[4], bfh[4], bfl[4];
#pragma unroll
    for (int t = 0; t < 4; ++t) {
      afh[t] = *(const fp16x8*)&Khh[t * 16 + l16][ks * 32 + quad * 8];
      afl[t] = *(const fp16x8*)&Khl[t * 16 + l16][ks * 32 + quad * 8];
      const size_t po = (size_t)(wn0 + t * 16 + l16) * 64 + ks * 32 + quad * 8;
      bfh[t] = *(const fp16x8*)(phh + po);
      bfl[t] = *(const fp16x8*)(phl + po);
    }
#pragma unroll
    for (int mt = 0; mt < 4; ++mt)
#pragma unroll
      for (int nt = 0; nt < 4; ++nt) {
        acc[mt][nt] = __builtin_amdgcn_mfma_f32_16x16x32_f16(afh[mt], bfh[nt], acc[mt][nt], 0, 0, 0);
        acc[mt][nt] = __builtin_amdgcn_mfma_f32_16x16x32_f16(afh[mt], bfl[nt], acc[mt][nt], 0, 0, 0);
        acc[mt][nt] = __builtin_amdgcn_mfma_f32_16x16x32_f16(afl[mt], bfh[nt], acc[mt][nt], 0, 0, 0);
      }
  }

  float mx = -3.4e38f;
#pragma unroll
  for (int mt = 0; mt < 4; ++mt)
#pragma unroll
    for (int nt = 0; nt < 4; ++nt)
#pragma unroll
      for (int r = 0; r < 4; ++r) mx = fmaxf(mx, acc[mt][nt][r]);
#pragma unroll
  for (int off = 32; off; off >>= 1) mx = fmaxf(mx, __shfl_xor(mx, off));
  if (lane == 0) wred[wid] = mx;
  __syncthreads();
  if (tid == 0) {
    float m2 = fmaxf(fmaxf(wred[0], wred[1]), fmaxf(wred[2], wred[3]));
    atomicMax(stab_enc, enc_f32(m2));
  }
}

/* ---------------- FAVOR: context & k_sum partials via MFMA -----------------
 * Per 64-row chunk: dd = K[64x64] @ proj^T (split-fp16, 3-MFMA);
 * kp = RATIO*(exp(dd-diag-stab)+EPS) -> fp16 LDS [m][n]; ksum col-sums via
 * shfl(16/32); ctx^T[d][m] partial += (kp rows m) x (V^T rows d) fp16 MFMA.
 * Partials written in [d][m] layout (feeds ctxT directly).                  */
__global__ __launch_bounds__(256, 2) void favor_ctx_mfma(
    const float* __restrict__ Kg, const float* __restrict__ Vg,
    const unsigned short* __restrict__ phh, const unsigned short* __restrict__ phl,
    const unsigned* __restrict__ stab_enc,
    float* __restrict__ ctxp, float* __restrict__ ksump, int split)
{
  __shared__ unsigned short Khh[64][72];
  __shared__ unsigned short Khl[64][72];
  __shared__ unsigned short Vt_h[64][72];   /* [d][n] */
  __shared__ unsigned short kp_s[256][72];  /* [m][n] */
  __shared__ float diag_s[64];

  const int tid = threadIdx.x;
  const int wid = tid >> 6, lane = tid & 63;
  const int quad = lane >> 4, l16 = lane & 15;
  const int sidx = blockIdx.x % split;
  const int bh = blockIdx.x / split;
  const int b = bh >> 3, h = bh & 7;
  const int rows = NN / split, nch = rows / 64;
  const float stab = dec_f32(*stab_enc);
  const int wn0 = wid * 64;
  const f32x4 zf = {0.f, 0.f, 0.f, 0.f};

  f32x4 acc2[4][4];
#pragma unroll
  for (int i = 0; i < 4; ++i)
#pragma unroll
    for (int j = 0; j < 4; ++j) acc2[i][j] = zf;
  float ksacc[4] = {0.f, 0.f, 0.f, 0.f};

  for (int c = 0; c < nch; ++c) {
    const int n0 = sidx * rows + c * 64;
    __syncthreads();
    /* stage: K split-fp16 [n][d], V fp16 transposed [d][n], diag via shfl */
    {
      const int r = tid >> 2, s2 = tid & 3;
      const float* ksrc = Kg + ((size_t)(b * NN + n0 + r)) * DMM + h * DH + s2 * 16;
      const float* vsrc = Vg + ((size_t)(b * NN + n0 + r)) * DMM + h * DH + s2 * 16;
      float kq = 0.f;
      unsigned short th[16], tl[16];
#pragma unroll
      for (int t = 0; t < 4; ++t) {
        float4 g = *(const float4*)(ksrc + t * 4);
        float f[4] = {g.x * NRM, g.y * NRM, g.z * NRM, g.w * NRM};
#pragma unroll
        for (int j = 0; j < 4; ++j) {
          kq = fmaf(f[j], f[j], kq);
          __half hh = __float2half(f[j]);
          th[t * 4 + j] = __half_as_ushort(hh);
          tl[t * 4 + j] = f2h(f[j] - __half2float(hh));
        }
        float4 vv = *(const float4*)(vsrc + t * 4);
        Vt_h[s2 * 16 + t * 4 + 0][r] = f2h(vv.x);
        Vt_h[s2 * 16 + t * 4 + 1][r] = f2h(vv.y);
        Vt_h[s2 * 16 + t * 4 + 2][r] = f2h(vv.z);
        Vt_h[s2 * 16 + t * 4 + 3][r] = f2h(vv.w);
      }
      *(uint4*)&Khh[r][s2 * 16]     = *(uint4*)&th[0];
      *(uint4*)&Khh[r][s2 * 16 + 8] = *(uint4*)&th[8];
      *(uint4*)&Khl[r][s2 * 16]     = *(uint4*)&tl[0];
      *(uint4*)&Khl[r][s2 * 16 + 8] = *(uint4*)&tl[8];
      kq += __shfl_xor(kq, 1);
      kq += __shfl_xor(kq, 2);
      if (s2 == 0) diag_s[r] = 0.5f * kq;
    }
    __syncthreads();

    /* dd GEMM: rows n=64 x wave's m-block 64, K=64, split-fp16 */
    f32x4 acc[4][4];
#pragma unroll
    for (int i = 0; i < 4; ++i)
#pragma unroll
      for (int j = 0; j < 4; ++j) acc[i][j] = zf;
#pragma unroll
    for (int ks = 0; ks < 2; ++ks) {
      fp16x8 afh[4], afl[4], bfh[4], bfl[4];
#pragma unroll
      for (int t = 0; t < 4; ++t) {
        afh[t] = *(const fp16x8*)&Khh[t * 16 + l16][ks * 32 + quad * 8];
        afl[t] = *(const fp16x8*)&Khl[t * 16 + l16][ks * 32 + quad * 8];
        const size_t po = (size_t)(wn0 + t * 16 + l16) * 64 + ks * 32 + quad * 8;
        bfh[t] = *(const fp16x8*)(phh + po);
        bfl[t] = *(const fp16x8*)(phl + po);
      }
#pragma unroll
      for (int mt = 0; mt < 4; ++mt)
#pragma unroll
        for (int nt = 0; nt < 4; ++nt) {
          acc[mt][nt] = __builtin_amdgcn_mfma_f32_16x16x32_f16(afh[mt], bfh[nt], acc[mt][nt], 0, 0, 0);
          acc[mt][nt] = __builtin_amdgcn_mfma_f32_16x16x32_f16(afh[mt], bfl[nt], acc[mt][nt], 0, 0, 0);
          acc[mt][nt] = __builtin_amdgcn_mfma_f32_16x16x32_f16(afl[mt], bfh[nt], acc[mt][nt], 0, 0, 0);
        }
    }

    /* kp = RATIO*(exp(dd - diag - stab)+EPS); ksum col partials; kp -> LDS */
    float ks_i[4] = {0.f, 0.f, 0.f, 0.f};
#pragma unroll
    for (int mt = 0; mt < 4; ++mt) {
#pragma unroll
      for (int nt = 0; nt < 4; ++nt) {
        float pv[4];
#pragma unroll
        for (int reg = 0; reg < 4; ++reg) {
          const int n = mt * 16 + quad * 4 + reg;
          float p = RATIO * (__expf(acc[mt][nt][reg] - diag_s[n] - stab) + EPSF);
          pv[reg] = p;
          ks_i[nt] += p;
        }
        __half2 h0 = __floats2half2_rn(pv[0], pv[1]);
        __half2 h1 = __floats2half2_rn(pv[2], pv[3]);
        uint2 w;
        w.x = *(unsigned*)&h0;
        w.y = *(unsigned*)&h1;
        *(uint2*)&kp_s[wn0 + nt * 16 + l16][mt * 16 + quad * 4] = w;
      }
    }
#pragma unroll
    for (int nt = 0; nt < 4; ++nt) {
      float s = ks_i[nt];
      s += __shfl_xor(s, 16);
      s += __shfl_xor(s, 32);
      ksacc[nt] += s;
    }
    __syncthreads();

    /* ctx GEMM: wave's 64 m-rows x 64 d-cols, K=n=64, plain fp16 */
#pragma unroll
    for (int ks2 = 0; ks2 < 2; ++ks2) {
      fp16x8 ap[4], bv[4];
#pragma unroll
      for (int t = 0; t < 4; ++t) {
        ap[t] = *(const fp16x8*)&kp_s[wn0 + t * 16 + l16][ks2 * 32 + quad * 8];
        bv[t] = *(const fp16x8*)&Vt_h[t * 16 + l16][ks2 * 32 + quad * 8];
      }
#pragma unroll
      for (int mt = 0; mt < 4; ++mt)
#pragma unroll
        for (int nt = 0; nt < 4; ++nt)
          acc2[mt][nt] = __builtin_amdgcn_mfma_f32_16x16x32_f16(ap[mt], bv[nt], acc2[mt][nt], 0, 0, 0);
    }
  }

  /* write partials: ctxp [bh*split+sidx][d][m], ksump [bh*split+sidx][m] */
  {
    float* dst = ctxp + ((size_t)(bh * split + sidx)) * MM * DH;
#pragma unroll
    for (int mt = 0; mt < 4; ++mt)
#pragma unroll
      for (int nt = 0; nt < 4; ++nt) {
        const int m = wn0 + mt * 16 + quad * 4;
        const int d = nt * 16 + l16;
        *(f32x4*)(dst + (size_t)d * MM + m) = acc2[mt][nt];
      }
    if (quad == 0) {
      float* kd = ksump + (size_t)(bh * split + sidx) * MM;
#pragma unroll
      for (int nt = 0; nt < 4; ++nt) kd[wn0 + nt * 16 + l16] = ksacc[nt];
    }
  }
}

/* ---------------- FAVOR: reduce partials -> ctxT fp16 [bh][d][m] + ksum ---- */
__global__ __launch_bounds__(256) void favor_reduce(
    const float* __restrict__ ctxp, const float* __restrict__ ksump,
    unsigned short* __restrict__ ctxT_h, float* __restrict__ ksum, int split)
{
  int i = blockIdx.x * 256 + threadIdx.x;
  if (i < BB * GHH * MM * DH) {
    int bh = i / (MM * DH);
    int md = i % (MM * DH);           /* md = d*MM + m (partials already [d][m]) */
    float s = 0.f;
    for (int k = 0; k < split; ++k) s += ctxp[((size_t)(bh * split + k)) * MM * DH + md];
    ctxT_h[i] = f2h(s);
  }
  if (i < BB * GHH * MM) {
    int bh = i / MM, m = i % MM;
    float s = 0.f;
    for (int k = 0; k < split; ++k) s += ksump[(bh * split + k) * MM + m];
    ksum[i] = s;
  }
}

/* ---------------- FAVOR fused output via MFMA ------------------------------ */
__global__ __launch_bounds__(256, 2) void favor_out_mfma(
    float* __restrict__ Q, const unsigned short* __restrict__ phh,
    const unsigned short* __restrict__ phl,
    const unsigned short* __restrict__ ctxT_h, const float* __restrict__ ksum)
{
  __shared__ unsigned short Qhh[64][72];
  __shared__ unsigned short Qhl[64][72];
  __shared__ unsigned short qp_s[64][264];
  __shared__ float red[4][64];
  __shared__ float dred[4][64];
  __shared__ float diag4[64][4];
  __shared__ float diag_s[64];
  __shared__ float dinv_s[64];
  __shared__ float ksum_s[256];

  const int tid = threadIdx.x;
  const int wid = tid >> 6, lane = tid & 63;
  const int quad = lane >> 4, l16 = lane & 15;
  const int bh = blockIdx.x >> 6;
  const int chunk = blockIdx.x & 63;
  const int b = bh >> 3, h = bh & 7;
  const int n0 = chunk * 64;
  const f32x4 zf = {0.f, 0.f, 0.f, 0.f};

  /* load Q chunk: scale, split fp16 hi/lo, diag partials */
  {
    const int r = tid >> 2, s2 = tid & 3;
    const float* src = Q + ((size_t)(b * NN + n0 + r)) * DMM + h * DH + s2 * 16;
    float sq = 0.f;
    unsigned short th[16], tl[16];
#pragma unroll
    for (int t = 0; t < 4; ++t) {
      float4 g = *(const float4*)(src + t * 4);
      float f[4] = {g.x * NRM, g.y * NRM, g.z * NRM, g.w * NRM};
#pragma unroll
      for (int j = 0; j < 4; ++j) {
        sq = fmaf(f[j], f[j], sq);
        __half hh = __float2half(f[j]);
        th[t * 4 + j] = __half_as_ushort(hh);
        tl[t * 4 + j] = f2h(f[j] - __half2float(hh));
      }
    }
    diag4[r][s2] = sq;
    *(uint4*)&Qhh[r][s2 * 16]     = *(uint4*)&th[0];
    *(uint4*)&Qhh[r][s2 * 16 + 8] = *(uint4*)&th[8];
    *(uint4*)&Qhl[r][s2 * 16]     = *(uint4*)&tl[0];
    *(uint4*)&Qhl[r][s2 * 16 + 8] = *(uint4*)&tl[8];
    ksum_s[tid] = ksum[bh * MM + tid];
  }
  __syncthreads();
  if (tid < 64)
    diag_s[tid] = 0.5f * (diag4[tid][0] + diag4[tid][1] + diag4[tid][2] + diag4[tid][3]);

  /* dd GEMM: rows 64 x wave's 64 feature-cols, K=64, split-fp16 (hh+hl+lh) */
  const int wn0 = wid * 64;
  f32x4 acc[4][4];
#pragma unroll
  for (int i = 0; i < 4; ++i)
#pragma unroll
    for (int j = 0; j < 4; ++j) acc[i][j] = zf;

#pragma unroll
  for (int ks = 0; ks < 2; ++ks) {
    fp16x8 afh[4], afl[4], bfh[4], bfl[4];
#pragma unroll
    for (int t = 0; t < 4; ++t) {
      afh[t] = *(const fp16x8*)&Qhh[t * 16 + l16][ks * 32 + quad * 8];
      afl[t] = *(const fp16x8*)&Qhl[t * 16 + l16][ks * 32 + quad * 8];
      const size_t po = (size_t)(wn0 + t * 16 + l16) * 64 + ks * 32 + quad * 8;
      bfh[t] = *(const fp16x8*)(phh + po);
      bfl[t] = *(const fp16x8*)(phl + po);
    }
#pragma unroll
    for (int mt = 0; mt < 4; ++mt)
#pragma unroll
      for (int nt = 0; nt < 4; ++nt) {
        acc[mt][nt] = __builtin_amdgcn_mfma_f32_16x16x32_f16(afh[mt], bfh[nt], acc[mt][nt], 0, 0, 0);
        acc[mt][nt] = __builtin_amdgcn_mfma_f32_16x16x32_f16(afh[mt], bfl[nt], acc[mt][nt], 0, 0, 0);
        acc[mt][nt] = __builtin_amdgcn_mfma_f32_16x16x32_f16(afl[mt], bfh[nt], acc[mt][nt], 0, 0, 0);
      }
  }

  /* per-row wave-local max -> LDS */
#pragma unroll
  for (int mt = 0; mt < 4; ++mt)
#pragma unroll
    for (int reg = 0; reg < 4; ++reg) {
      float v = fmaxf(fmaxf(acc[mt][0][reg], acc[mt][1][reg]),
                      fmaxf(acc[mt][2][reg], acc[mt][3][reg]));
      v = fmaxf(v, __shfl_xor(v, 1));
      v = fmaxf(v, __shfl_xor(v, 2));
      v = fmaxf(v, __shfl_xor(v, 4));
      v = fmaxf(v, __shfl_xor(v, 8));
      if (l16 == 0) red[wid][mt * 16 + quad * 4 + reg] = v;
    }
  __syncthreads();

  /* qp = RATIO*(exp(dd - diag - stab) + EPS); dsum partials; qp -> fp16 LDS */
  float ksv[4];
#pragma unroll
  for (int nt = 0; nt < 4; ++nt) ksv[nt] = ksum_s[wn0 + nt * 16 + l16];
#pragma unroll
  for (int mt = 0; mt < 4; ++mt)
#pragma unroll
    for (int reg = 0; reg < 4; ++reg) {
      const int row = mt * 16 + quad * 4 + reg;
      float stab = fmaxf(fmaxf(red[0][row], red[1][row]),
                         fmaxf(red[2][row], red[3][row]));
      float base = diag_s[row] + stab;
      float dsum = 0.f;
#pragma unroll
      for (int nt = 0; nt < 4; ++nt) {
        float p = RATIO * (__expf(acc[mt][nt][reg] - base) + EPSF);
        acc[mt][nt][reg] = p;
        dsum = fmaf(p, ksv[nt], dsum);
      }
      dsum += __shfl_xor(dsum, 1);
      dsum += __shfl_xor(dsum, 2);
      dsum += __shfl_xor(dsum, 4);
      dsum += __shfl_xor(dsum, 8);
      if (l16 == 0) dred[wid][row] = dsum;
#pragma unroll
      for (int nt = 0; nt < 4; ++nt)
        qp_s[row][wn0 + nt * 16 + l16] = f2h(acc[mt][nt][reg]);
    }
  __syncthreads();
  if (tid < 64)
    dinv_s[tid] = 1.0f / (dred[0][tid] + dred[1][tid] + dred[2][tid] + dred[3][tid]);

  /* PV: out[64 x wave's 16 d-cols] = qp[64x256] @ ctxT rows, K=256 */
  const int wn2 = wid * 16;
  f32x4 acc2[4];
#pragma unroll
  for (int mt = 0; mt < 4; ++mt) acc2[mt] = zf;
#pragma unroll
  for (int ksp = 0; ksp < 8; ++ksp) {
    fp16x8 bv = *(const fp16x8*)(ctxT_h + ((size_t)bh * DH + wn2 + l16) * MM + ksp * 32 + quad * 8);
    fp16x8 ap[4];
#pragma unroll
    for (int mt = 0; mt < 4; ++mt)
      ap[mt] = *(const fp16x8*)&qp_s[mt * 16 + l16][ksp * 32 + quad * 8];
#pragma unroll
    for (int mt = 0; mt < 4; ++mt)
      acc2[mt] = __builtin_amdgcn_mfma_f32_16x16x32_f16(ap[mt], bv, acc2[mt], 0, 0, 0);
  }
  __syncthreads();

  /* epilogue: scale by 1/dsum, store */
#pragma unroll
  for (int mt = 0; mt < 4; ++mt)
#pragma unroll
    for (int reg = 0; reg < 4; ++reg) {
      const int row = mt * 16 + quad * 4 + reg;
      Q[((size_t)(b * NN + n0 + row)) * DMM + h * DH + wn2 + l16] =
          acc2[mt][reg] * dinv_s[row];
    }
}

/* ---------------- launcher -------------------------------------------------- */
extern "C" void kernel_launch(void* const* d_in, const int* in_sizes, int n_in,
                              void* d_out, int out_size, void* d_ws, size_t ws_size,
                              hipStream_t stream)
{
  (void)in_sizes; (void)n_in; (void)out_size;
  const float* x    = (const float*)d_in[0];
  const float* Wq   = (const float*)d_in[2];
  const float* Wk   = (const float*)d_in[3];
  const float* Wv   = (const float*)d_in[4];
  const float* Wo   = (const float*)d_in[5];
  const float* bo   = (const float*)d_in[6];
  const float* proj = (const float*)d_in[7];
  float* out = (float*)d_out;

  const size_t WSZ = (size_t)DMM * DMM;
  const size_t XSP = (size_t)BB * NN * DMM;            /* elems per activation plane */
  const size_t wbuf_f = (8 * WSZ * 2 + 3) / 4;
  const size_t LSZ = (size_t)BB * LHH * NN * DH;       /* u16 elems per local buf */
  const size_t lbuf_f = (3 * LSZ * 2 + 3) / 4;
  const size_t fixed_f = (size_t)3 * XSP + (size_t)BB * GHH * MM * DH
                       + (size_t)BB * GHH * MM + 16 + MM * DH + MM * DH + 16
                       + wbuf_f + 16 + lbuf_f + 16;

  /* region: time-shared between ctxp/ksump (FAVOR phase) and xH/xL split
   * activation planes (GEMM phases) — live ranges are disjoint.            */
  int split = 8, use_pre = 0;
  for (int s = 32; s >= 8; s >>= 1) {
    size_t part = (size_t)BB * GHH * s * (MM * DH + MM);
    size_t region = part > XSP ? part : XSP;
    if ((fixed_f + region) * 4 <= ws_size) { split = s; use_pre = 1; break; }
  }
  if (!use_pre) {
    for (int s = 32; s >= 8; s >>= 1) {
      size_t need = (fixed_f + (size_t)BB * GHH * s * (MM * DH + MM)) * 4;
      if (need <= ws_size) { split = s; break; }
    }
  }
  size_t part_f = (size_t)BB * GHH * split * (MM * DH + MM);
  size_t region_f = (use_pre && XSP > part_f) ? XSP : part_f;

  float* Qb    = (float*)d_ws;
  float* Kb    = Qb + XSP;
  float* Vb    = Kb + XSP;
  float* region = Vb + XSP;
  float* ctxp  = region;
  float* ksump = ctxp + (size_t)BB * GHH * split * MM * DH;
  unsigned short* xH = (unsigned short*)region;
  unsigned short* xL = xH + XSP;
  float* ctx   = region + region_f;                 /* region holds ctxT fp16 */
  unsigned short* ctxT_h = (unsigned short*)ctx;
  float* ksum  = ctx + (size_t)BB * GHH * MM * DH;
  unsigned* stab = (unsigned*)(ksum + BB * GHH * MM);
  float* projT = (float*)(stab + 16);
  unsigned short* proj_hh = (unsigned short*)(projT + MM * DH);
  unsigned short* proj_hl = proj_hh + MM * DH;
  unsigned short* wsp = proj_hl + MM * DH;
  unsigned short* WqH = wsp;            unsigned short* WqL = wsp + WSZ;
  unsigned short* WkH = wsp + 2 * WSZ;  unsigned short* WkL = wsp + 3 * WSZ;
  unsigned short* WvH = wsp + 4 * WSZ;  unsigned short* WvL = wsp + 5 * WSZ;
  unsigned short* WoH = wsp + 6 * WSZ;  unsigned short* WoL = wsp + 7 * WSZ;
  unsigned short* Qlh = wsp + 8 * WSZ;
  unsigned short* Klh = Qlh + LSZ;
  unsigned short* Vtl = Klh + LSZ;

  dim3 blk(256);
  dim3 mg(DMM / 128, (BB * NN) / 128);
  const int wgrid = (int)(WSZ / 256);
  const int agrid = (int)(XSP / 1024);

  w_split<<<wgrid, blk, 0, stream>>>(Wq, WqH, WqL);
  w_split<<<wgrid, blk, 0, stream>>>(Wk, WkH, WkL);
  w_split<<<wgrid, blk, 0, stream>>>(Wv, WvH, WvL);
  w_split<<<wgrid, blk, 0, stream>>>(Wo, WoH, WoL);
  if (use_pre) {
    a_split<<<agrid, blk, 0, stream>>>(x, xH, xL);
    gemm_mfma_pre<<<mg, blk, 0, stream>>>(xH, xL, WqH, WqL, nullptr, Qb, DMM, DMM);
    gemm_mfma_pre<<<mg, blk, 0, stream>>>(xH, xL, WkH, WkL, nullptr, Kb, DMM, DMM);
    gemm_mfma_pre<<<mg, blk, 0, stream>>>(xH, xL, WvH, WvL, nullptr, Vb, DMM, DMM);
  } else {
    gemm_mfma<<<mg, blk, 0, stream>>>(x, WqH, WqL, nullptr, Qb, DMM, DMM);
    gemm_mfma<<<mg, blk, 0, stream>>>(x, WkH, WkL, nullptr, Kb, DMM, DMM);
    gemm_mfma<<<mg, blk, 0, stream>>>(x, WvH, WvL, nullptr, Vb, DMM, DMM);
  }
  rot_qk<<<(BB * LHH * NN) / 256, blk, 0, stream>>>(Qb, Kb, Qlh, Klh);
  v_trans<<<dim3(NN / 64, LHH, BB), blk, 0, stream>>>(Vb, Vtl);
  init_stab<<<1, 64, 0, stream>>>(stab);
  transpose_proj<<<64, blk, 0, stream>>>(proj, projT, proj_hh, proj_hl);
  favor_kstab_mfma<<<BB * GHH * (NN / 64), blk, 0, stream>>>(Kb, proj_hh, proj_hl, stab);
  favor_ctx_mfma<<<BB * GHH * split, blk, 0, stream>>>(Kb, Vb, proj_hh, proj_hl, stab, ctxp, ksump, split);
  favor_reduce<<<(BB * GHH * MM * DH) / 256, blk, 0, stream>>>(ctxp, ksump, ctxT_h, ksum, split);
  favor_out_mfma<<<BB * GHH * (NN / 64), blk, 0, stream>>>(Qb, proj_hh, proj_hl, ctxT_h, ksum);
  local_attn2<<<dim3(NWIN, LHH, BB), blk, 0, stream>>>(Qlh, Klh, Vtl, Qb);
  if (use_pre) {
    a_split<<<agrid, blk, 0, stream>>>(Qb, xH, xL);
    gemm_mfma_pre<<<mg, blk, 0, stream>>>(xH, xL, WoH, WoL, bo, out, DMM, DMM);
  } else {
    gemm_mfma<<<mg, blk, 0, stream>>>(Qb, WoH, WoL, bo, out, DMM, DMM);
  }
}

// Round 4
// 672.033 us; speedup vs baseline: 1.5033x; 1.1228x over previous
//
#include <hip/hip_runtime.h>
#include <hip/hip_fp16.h>
#include <math.h>

#define BB 4
#define NN 4096
#define DMM 768
#define HHH 12
#define LHH 4
#define GHH 8
#define DH 64
#define MM 256
#define WW 128
#define NWIN (NN/WW)
#define EPSF 1.0e-4f
#define NRM 0.35355339059327373f   /* 64^-0.25 */
#define NRM2 0.125f                /* 64^-0.5  */
#define RATIO 0.0625f              /* 256^-0.5 */
#define LN1E4_32 0.28782313662425572f  /* ln(10000)/32 */

using bf16x8 = __attribute__((ext_vector_type(8))) short;
using fp16x8 = __attribute__((ext_vector_type(8))) _Float16;
using f32x4  = __attribute__((ext_vector_type(4))) float;

static __device__ __forceinline__ unsigned enc_f32(float f) {
  unsigned u = __float_as_uint(f);
  return (u & 0x80000000u) ? ~u : (u | 0x80000000u);
}
static __device__ __forceinline__ float dec_f32(unsigned u) {
  unsigned b = (u & 0x80000000u) ? (u ^ 0x80000000u) : ~u;
  return __uint_as_float(b);
}
static __device__ __forceinline__ unsigned short f2h(float x) {
  return __half_as_ushort(__float2half(x));
}
/* direct global->LDS 16B DMA (linear LDS dest: wave-uniform base + lane*16) */
static __device__ __forceinline__ void gload16(const unsigned short* g, unsigned short* l) {
  __builtin_amdgcn_global_load_lds(
      (const __attribute__((address_space(1))) void*)g,
      (__attribute__((address_space(3))) void*)l, 16, 0, 0);
}

/* ------- W prep: transpose to [n][k] and split into bf16 hi/lo planes ----- */
__global__ __launch_bounds__(256) void w_split(
    const float* __restrict__ W, unsigned short* __restrict__ Whi,
    unsigned short* __restrict__ Wlo)
{
  int o = blockIdx.x * 256 + threadIdx.x;     /* 768*768 */
  int k = o / DMM, n = o % DMM;
  float x = W[o];
  unsigned u = __float_as_uint(x);
  unsigned h = u & 0xFFFF0000u;
  float lf = x - __uint_as_float(h);
  Whi[(size_t)n * DMM + k] = (unsigned short)(u >> 16);
  Wlo[(size_t)n * DMM + k] = (unsigned short)(__float_as_uint(lf) >> 16);
}

/* ------- activation prep: split fp32 [M][K] into bf16 hi/lo planes -------- */
__global__ __launch_bounds__(256) void a_split(
    const float* __restrict__ A, unsigned short* __restrict__ Ahi,
    unsigned short* __restrict__ Alo)
{
  size_t o = ((size_t)blockIdx.x * 256 + threadIdx.x) * 4;
  float4 v = *(const float4*)(A + o);
  float f[4] = {v.x, v.y, v.z, v.w};
  unsigned short hi[4], lo[4];
#pragma unroll
  for (int i = 0; i < 4; ++i) {
    unsigned u = __float_as_uint(f[i]);
    unsigned h = u & 0xFFFF0000u;
    float l = f[i] - __uint_as_float(h);
    hi[i] = (unsigned short)(u >> 16);
    lo[i] = (unsigned short)(__float_as_uint(l) >> 16);
  }
  *(uint2*)(Ahi + o) = *(uint2*)&hi[0];
  *(uint2*)(Alo + o) = *(uint2*)&lo[0];
}

/* ------- split-bf16 MFMA GEMM (fallback: converts A in-kernel) ------------ */
__global__ __launch_bounds__(256) void gemm_mfma(
    const float* __restrict__ A,
    const unsigned short* __restrict__ Bhi, const unsigned short* __restrict__ Blo,
    const float* __restrict__ bias, float* __restrict__ C, int K, int Nc)
{
  __shared__ unsigned short Ah[128][40];
  __shared__ unsigned short Al[128][40];
  __shared__ unsigned short Bh[128][40];
  __shared__ unsigned short Bl[128][40];

  const int tid = threadIdx.x;
  const int wid = tid >> 6, lane = tid & 63;
  const int quad = lane >> 4, l16 = lane & 15;
  const int row0 = blockIdx.y * 128;
  const int col0 = blockIdx.x * 128;
  const int wm = (wid & 1) * 64, wn = (wid >> 1) * 64;
  const int sr = tid >> 1;
  const int sk = (tid & 1) * 16;

  f32x4 acc[4][4];
  const f32x4 zf = {0.f, 0.f, 0.f, 0.f};
#pragma unroll
  for (int i = 0; i < 4; ++i)
#pragma unroll
    for (int j = 0; j < 4; ++j) acc[i][j] = zf;

  for (int k0 = 0; k0 < K; k0 += 32) {
    __syncthreads();
    {
      const float* a = A + (size_t)(row0 + sr) * K + k0 + sk;
      float fv[16];
      *(float4*)&fv[0]  = *(const float4*)(a);
      *(float4*)&fv[4]  = *(const float4*)(a + 4);
      *(float4*)&fv[8]  = *(const float4*)(a + 8);
      *(float4*)&fv[12] = *(const float4*)(a + 12);
      unsigned hw[8], lw[8];
#pragma unroll
      for (int p = 0; p < 8; ++p) {
        float x0 = fv[2 * p], x1 = fv[2 * p + 1];
        unsigned u0 = __float_as_uint(x0), u1 = __float_as_uint(x1);
        unsigned h0 = u0 & 0xFFFF0000u, h1 = u1 & 0xFFFF0000u;
        float l0 = x0 - __uint_as_float(h0);
        float l1 = x1 - __uint_as_float(h1);
        hw[p] = (u0 >> 16) | h1;
        lw[p] = (__float_as_uint(l0) >> 16) | (__float_as_uint(l1) & 0xFFFF0000u);
      }
      *(uint4*)&Ah[sr][sk]     = *(uint4*)&hw[0];
      *(uint4*)&Ah[sr][sk + 8] = *(uint4*)&hw[4];
      *(uint4*)&Al[sr][sk]     = *(uint4*)&lw[0];
      *(uint4*)&Al[sr][sk + 8] = *(uint4*)&lw[4];
    }
    {
      const unsigned short* bh = Bhi + (size_t)(col0 + sr) * DMM + k0 + sk;
      const unsigned short* bl = Blo + (size_t)(col0 + sr) * DMM + k0 + sk;
      *(uint4*)&Bh[sr][sk]     = *(const uint4*)(bh);
      *(uint4*)&Bh[sr][sk + 8] = *(const uint4*)(bh + 8);
      *(uint4*)&Bl[sr][sk]     = *(const uint4*)(bl);
      *(uint4*)&Bl[sr][sk + 8] = *(const uint4*)(bl + 8);
    }
    __syncthreads();

    bf16x8 afh[4], afl[4], bfh[4], bfl[4];
#pragma unroll
    for (int t = 0; t < 4; ++t) {
      afh[t] = *(const bf16x8*)&Ah[wm + t * 16 + l16][quad * 8];
      afl[t] = *(const bf16x8*)&Al[wm + t * 16 + l16][quad * 8];
      bfh[t] = *(const bf16x8*)&Bh[wn + t * 16 + l16][quad * 8];
      bfl[t] = *(const bf16x8*)&Bl[wn + t * 16 + l16][quad * 8];
    }
#pragma unroll
    for (int ti = 0; ti < 4; ++ti)
#pragma unroll
      for (int tj = 0; tj < 4; ++tj) {
        acc[ti][tj] = __builtin_amdgcn_mfma_f32_16x16x32_bf16(afh[ti], bfh[tj], acc[ti][tj], 0, 0, 0);
        acc[ti][tj] = __builtin_amdgcn_mfma_f32_16x16x32_bf16(afh[ti], bfl[tj], acc[ti][tj], 0, 0, 0);
        acc[ti][tj] = __builtin_amdgcn_mfma_f32_16x16x32_bf16(afl[ti], bfh[tj], acc[ti][tj], 0, 0, 0);
      }
  }

  float bv[4] = {0.f, 0.f, 0.f, 0.f};
  if (bias) {
#pragma unroll
    for (int tj = 0; tj < 4; ++tj) bv[tj] = bias[col0 + wn + tj * 16 + l16];
  }
#pragma unroll
  for (int ti = 0; ti < 4; ++ti) {
    const int gr = row0 + wm + ti * 16 + quad * 4;
#pragma unroll
    for (int tj = 0; tj < 4; ++tj) {
      const int gc = col0 + wn + tj * 16 + l16;
      float* cp = C + (size_t)gr * Nc + gc;
#pragma unroll
      for (int r = 0; r < 4; ++r)
        cp[(size_t)r * Nc] = acc[ti][tj][r] + bv[tj];
    }
  }
}

/* ------- split-bf16 MFMA GEMM, pre-split A planes (hot path) ---------------
 * global_load_lds(16B) staging into linear LDS; XOR-swizzled k-chunk
 * (pre-swizzled source + swizzled read); XCD-contiguous block remap.       */
__global__ __launch_bounds__(256) void gemm_mfma_pre(
    const unsigned short* __restrict__ Ahi, const unsigned short* __restrict__ Alo,
    const unsigned short* __restrict__ Bhi, const unsigned short* __restrict__ Blo,
    const float* __restrict__ bias, float* __restrict__ C, int K, int Nc)
{
  __shared__ unsigned short Ah[128][32];
  __shared__ unsigned short Al[128][32];
  __shared__ unsigned short Bh[128][32];
  __shared__ unsigned short Bl[128][32];

  const int tid = threadIdx.x;
  const int wid = tid >> 6, lane = tid & 63;
  const int quad = lane >> 4, l16 = lane & 15;

  /* XCD-contiguous remap: each XCD gets a contiguous range of row-panels   */
  const int nwg = gridDim.x * gridDim.y;
  int hw = blockIdx.y * gridDim.x + blockIdx.x;
  int logical = ((nwg & 7) == 0) ? ((hw & 7) * (nwg >> 3) + (hw >> 3)) : hw;
  const int col0 = (logical % gridDim.x) * 128;
  const int row0 = (logical / gridDim.x) * 128;

  const int wm = (wid & 1) * 64, wn = (wid >> 1) * 64;
  const int sw8 = (quad ^ ((l16 >> 1) & 3)) * 8;   /* swizzled read col (shorts) */

  /* staging geometry: LDS dest linear tid*16B; source k-chunk pre-swizzled */
  const int rr = tid >> 2;
  const int cg8 = ((tid & 3) ^ ((tid >> 3) & 3)) * 8;

  f32x4 acc[4][4];
  const f32x4 zf = {0.f, 0.f, 0.f, 0.f};
#pragma unroll
  for (int i = 0; i < 4; ++i)
#pragma unroll
    for (int j = 0; j < 4; ++j) acc[i][j] = zf;

  for (int k0 = 0; k0 < K; k0 += 32) {
    __syncthreads();
    {
      const size_t ro0 = (size_t)(row0 + rr) * K + k0 + cg8;
      const size_t ro1 = (size_t)(row0 + 64 + rr) * K + k0 + cg8;
      const size_t co0 = (size_t)(col0 + rr) * K + k0 + cg8;
      const size_t co1 = (size_t)(col0 + 64 + rr) * K + k0 + cg8;
      unsigned short* la = &Ah[0][0] + tid * 8;
      unsigned short* lal = &Al[0][0] + tid * 8;
      unsigned short* lb = &Bh[0][0] + tid * 8;
      unsigned short* lbl = &Bl[0][0] + tid * 8;
      gload16(Ahi + ro0, la);
      gload16(Ahi + ro1, la + 2048);
      gload16(Alo + ro0, lal);
      gload16(Alo + ro1, lal + 2048);
      gload16(Bhi + co0, lb);
      gload16(Bhi + co1, lb + 2048);
      gload16(Blo + co0, lbl);
      gload16(Blo + co1, lbl + 2048);
    }
    __syncthreads();

    bf16x8 afh[4], afl[4], bfh[4], bfl[4];
#pragma unroll
    for (int t = 0; t < 4; ++t) {
      afh[t] = *(const bf16x8*)&Ah[wm + t * 16 + l16][sw8];
      afl[t] = *(const bf16x8*)&Al[wm + t * 16 + l16][sw8];
      bfh[t] = *(const bf16x8*)&Bh[wn + t * 16 + l16][sw8];
      bfl[t] = *(const bf16x8*)&Bl[wn + t * 16 + l16][sw8];
    }
#pragma unroll
    for (int ti = 0; ti < 4; ++ti)
#pragma unroll
      for (int tj = 0; tj < 4; ++tj) {
        acc[ti][tj] = __builtin_amdgcn_mfma_f32_16x16x32_bf16(afh[ti], bfh[tj], acc[ti][tj], 0, 0, 0);
        acc[ti][tj] = __builtin_amdgcn_mfma_f32_16x16x32_bf16(afh[ti], bfl[tj], acc[ti][tj], 0, 0, 0);
        acc[ti][tj] = __builtin_amdgcn_mfma_f32_16x16x32_bf16(afl[ti], bfh[tj], acc[ti][tj], 0, 0, 0);
      }
  }

  float bv[4] = {0.f, 0.f, 0.f, 0.f};
  if (bias) {
#pragma unroll
    for (int tj = 0; tj < 4; ++tj) bv[tj] = bias[col0 + wn + tj * 16 + l16];
  }
#pragma unroll
  for (int ti = 0; ti < 4; ++ti) {
    const int gr = row0 + wm + ti * 16 + quad * 4;
#pragma unroll
    for (int tj = 0; tj < 4; ++tj) {
      const int gc = col0 + wn + tj * 16 + l16;
      float* cp = C + (size_t)gr * Nc + gc;
#pragma unroll
      for (int r = 0; r < 4; ++r)
        cp[(size_t)r * Nc] = acc[ti][tj][r] + bv[tj];
    }
  }
}

/* ---------------- init global stabilizer ---------------------------------- */
__global__ void init_stab(unsigned* stab_enc) {
  if (threadIdx.x == 0 && blockIdx.x == 0) *stab_enc = 0x00800000u; /* enc(-FLT_MAX) */
}

/* ---------------- proj prep: projT fp32 + [m][d] fp16 hi/lo planes --------- */
__global__ __launch_bounds__(256) void transpose_proj(
    const float* __restrict__ proj, float* __restrict__ projT,
    unsigned short* __restrict__ phh, unsigned short* __restrict__ phl)
{
  int o = blockIdx.x * 256 + threadIdx.x;   /* 16384 */
  int k = o >> 8, m = o & 255;
  float v = proj[m * 64 + k];
  projT[k * 256 + m] = v;
  __half hh = __float2half(v);
  float lf = v - __half2float(hh);
  phh[m * 64 + k] = __half_as_ushort(hh);
  phl[m * 64 + k] = f2h(lf);
}

/* ---------------- rotary prep for local heads: Q(scaled)/K -> fp16 --------- */
__global__ __launch_bounds__(256) void rot_qk(
    const float* __restrict__ Qb, const float* __restrict__ Kb,
    unsigned short* __restrict__ Qlh, unsigned short* __restrict__ Klh)
{
  int idx = blockIdx.x * 256 + threadIdx.x;    /* (b*LHH+h)*NN + n : 65536 */
  int n = idx & (NN - 1);
  int bh = idx >> 12;
  int b = bh >> 2, h = bh & 3;
  const float* qs = Qb + ((size_t)(b * NN + n)) * DMM + GHH * DH + h * DH;
  const float* ks = Kb + ((size_t)(b * NN + n)) * DMM + GHH * DH + h * DH;
  float q[64], k[64];
#pragma unroll
  for (int t = 0; t < 16; ++t) {
    *(float4*)&q[t * 4] = *(const float4*)(qs + t * 4);
    *(float4*)&k[t * 4] = *(const float4*)(ks + t * 4);
  }
  unsigned short qo[64], ko[64];
#pragma unroll
  for (int i = 0; i < 32; ++i) {
    float invf = __expf((float)i * -LN1E4_32);
    float th = (float)n * invf;
    float s, c;
    sincosf(th, &s, &c);
    qo[i]      = f2h(fmaf(q[i], c, -q[i + 32] * s) * NRM2);
    qo[i + 32] = f2h(fmaf(q[i + 32], c, q[i] * s) * NRM2);
    ko[i]      = f2h(fmaf(k[i], c, -k[i + 32] * s));
    ko[i + 32] = f2h(fmaf(k[i + 32], c, k[i] * s));
  }
  unsigned short* qd = Qlh + (size_t)idx * 64;
  unsigned short* kd = Klh + (size_t)idx * 64;
#pragma unroll
  for (int t = 0; t < 8; ++t) {
    *(uint4*)(qd + t * 8) = *(uint4*)&qo[t * 8];
    *(uint4*)(kd + t * 8) = *(uint4*)&ko[t * 8];
  }
}

/* ---------------- V transpose for local heads: fp16 [b][h][d][n] ----------- */
__global__ __launch_bounds__(256) void v_trans(
    const float* __restrict__ Vb, unsigned short* __restrict__ Vt)
{
  __shared__ unsigned short T[64][72];
  const int nb = blockIdx.x, h = blockIdx.y, b = blockIdx.z;
  const int n0 = nb * 64;
  const int tid = threadIdx.x;
  {
    int r = tid >> 2, g = tid & 3;
    const float* src = Vb + ((size_t)(b * NN + n0 + r)) * DMM + GHH * DH + h * DH + g * 16;
#pragma unroll
    for (int t = 0; t < 4; ++t) {
      float4 v = *(const float4*)(src + t * 4);
      T[g * 16 + t * 4 + 0][r] = f2h(v.x);
      T[g * 16 + t * 4 + 1][r] = f2h(v.y);
      T[g * 16 + t * 4 + 2][r] = f2h(v.z);
      T[g * 16 + t * 4 + 3][r] = f2h(v.w);
    }
  }
  __syncthreads();
  {
    int d = tid >> 2, g = tid & 3;
    unsigned short* dst = Vt + ((size_t)(b * LHH + h) * DH + d) * NN + n0 + g * 16;
    *(uint4*)dst       = *(uint4*)&T[d][g * 16];
    *(uint4*)(dst + 8) = *(uint4*)&T[d][g * 16 + 8];
  }
}

/* ---------------- local attention via f16 MFMA (flash-style) --------------- */
__global__ __launch_bounds__(256) void local_attn2(
    const unsigned short* __restrict__ Qlh, const unsigned short* __restrict__ Klh,
    const unsigned short* __restrict__ Vt, float* __restrict__ Qb)
{
  __shared__ unsigned short Pl[4][32][72];
  const int w = blockIdx.x, h = blockIdx.y, b = blockIdx.z;
  const int tid = threadIdx.x;
  const int wid = tid >> 6, lane = tid & 63;
  const int quad = lane >> 4, l16 = lane & 15;
  const int bh = b * LHH + h;
  const int qn0 = w * WW + wid * 32;

  fp16x8 Aq[2][2];
#pragma unroll
  for (int mt = 0; mt < 2; ++mt)
#pragma unroll
    for (int ks = 0; ks < 2; ++ks)
      Aq[mt][ks] = *(const fp16x8*)(Qlh + ((size_t)bh * NN + qn0 + mt * 16 + l16) * 64 + ks * 32 + quad * 8);

  float m_run[8], l_run[8];
  f32x4 Oacc[2][4];
  const f32x4 zf = {0.f, 0.f, 0.f, 0.f};
#pragma unroll
  for (int r = 0; r < 8; ++r) { m_run[r] = -3.4e38f; l_run[r] = 0.f; }
#pragma unroll
  for (int mt = 0; mt < 2; ++mt)
#pragma unroll
    for (int nt = 0; nt < 4; ++nt) Oacc[mt][nt] = zf;

  const int wb_lo = (w == 0) ? 0 : w - 1;
  const int wb_hi = (w == NWIN - 1) ? w : w + 1;
  for (int wb = wb_lo; wb <= wb_hi; ++wb) {
    for (int half = 0; half < 2; ++half) {
      const int kn0 = wb * WW + half * 64;
      f32x4 sacc[2][4];
#pragma unroll
      for (int mt = 0; mt < 2; ++mt)
#pragma unroll
        for (int nt = 0; nt < 4; ++nt) sacc[mt][nt] = zf;

#pragma unroll
      for (int ks = 0; ks < 2; ++ks) {
        fp16x8 Bk[4];
#pragma unroll
        for (int nt = 0; nt < 4; ++nt)
          Bk[nt] = *(const fp16x8*)(Klh + ((size_t)bh * NN + kn0 + nt * 16 + l16) * 64 + ks * 32 + quad * 8);
#pragma unroll
        for (int mt = 0; mt < 2; ++mt)
#pragma unroll
          for (int nt = 0; nt < 4; ++nt)
            sacc[mt][nt] = __builtin_amdgcn_mfma_f32_16x16x32_f16(Aq[mt][ks], Bk[nt], sacc[mt][nt], 0, 0, 0);
      }

      /* online softmax per row (row = mt*16 + quad*4 + reg) */
#pragma unroll
      for (int mt = 0; mt < 2; ++mt) {
#pragma unroll
        for (int reg = 0; reg < 4; ++reg) {
          const int r8 = mt * 4 + reg;
          float v = fmaxf(fmaxf(sacc[mt][0][reg], sacc[mt][1][reg]),
                          fmaxf(sacc[mt][2][reg], sacc[mt][3][reg]));
          v = fmaxf(v, __shfl_xor(v, 1));
          v = fmaxf(v, __shfl_xor(v, 2));
          v = fmaxf(v, __shfl_xor(v, 4));
          v = fmaxf(v, __shfl_xor(v, 8));
          float mnew = fmaxf(m_run[r8], v);
          float alpha = __expf(m_run[r8] - mnew);
          m_run[r8] = mnew;
          float ps = 0.f;
#pragma unroll
          for (int nt = 0; nt < 4; ++nt) {
            float p = __expf(sacc[mt][nt][reg] - mnew);
            sacc[mt][nt][reg] = p;
            ps += p;
          }
          ps += __shfl_xor(ps, 1);
          ps += __shfl_xor(ps, 2);
          ps += __shfl_xor(ps, 4);
          ps += __shfl_xor(ps, 8);
          l_run[r8] = l_run[r8] * alpha + ps;
#pragma unroll
          for (int nt = 0; nt < 4; ++nt) Oacc[mt][nt][reg] *= alpha;
        }
      }

      /* write P fp16 (C-layout -> [qrow][key] in LDS, wave-local) */
#pragma unroll
      for (int mt = 0; mt < 2; ++mt)
#pragma unroll
        for (int nt = 0; nt < 4; ++nt)
#pragma unroll
          for (int reg = 0; reg < 4; ++reg)
            Pl[wid][mt * 16 + quad * 4 + reg][nt * 16 + l16] = f2h(sacc[mt][nt][reg]);

      /* PV */
#pragma unroll
      for (int kstep = 0; kstep < 2; ++kstep) {
        fp16x8 Ap[2];
#pragma unroll
        for (int mt = 0; mt < 2; ++mt)
          Ap[mt] = *(const fp16x8*)&Pl[wid][mt * 16 + l16][kstep * 32 + quad * 8];
        fp16x8 Bv[4];
#pragma unroll
        for (int nt = 0; nt < 4; ++nt)
          Bv[nt] = *(const fp16x8*)(Vt + ((size_t)bh * DH + nt * 16 + l16) * NN + kn0 + kstep * 32 + quad * 8);
#pragma unroll
        for (int mt = 0; mt < 2; ++mt)
#pragma unroll
          for (int nt = 0; nt < 4; ++nt)
            Oacc[mt][nt] = __builtin_amdgcn_mfma_f32_16x16x32_f16(Ap[mt], Bv[nt], Oacc[mt][nt], 0, 0, 0);
      }
    }
  }

  /* epilogue: divide by l, store fp32 into Qb local-head columns */
#pragma unroll
  for (int mt = 0; mt < 2; ++mt)
#pragma unroll
    for (int reg = 0; reg < 4; ++reg) {
      const float inv = 1.0f / l_run[mt * 4 + reg];
      const int n = qn0 + mt * 16 + quad * 4 + reg;
      float* dst = Qb + ((size_t)(b * NN + n)) * DMM + GHH * DH + h * DH;
#pragma unroll
      for (int nt = 0; nt < 4; ++nt)
        dst[nt * 16 + l16] = Oacc[mt][nt][reg] * inv;
    }
}

/* ---------------- FAVOR: global max of dd_k via MFMA ----------------------- */
__global__ __launch_bounds__(256) void favor_kstab_mfma(
    const float* __restrict__ Kg, const unsigned short* __restrict__ phh,
    const unsigned short* __restrict__ phl, unsigned* __restrict__ stab_enc)
{
  __shared__ unsigned short Khh[64][72];
  __shared__ unsigned short Khl[64][72];
  __shared__ float wred[4];
  const int tid = threadIdx.x;
  const int wid = tid >> 6, lane = tid & 63;
  const int quad = lane >> 4, l16 = lane & 15;
  const int chunk = blockIdx.x & 63;
  const int bh = blockIdx.x >> 6;
  const int b = bh >> 3, h = bh & 7;
  const int n0 = chunk * 64;
  const f32x4 zf = {0.f, 0.f, 0.f, 0.f};

  {
    const int r = tid >> 2, s2 = tid & 3;
    const float* ksrc = Kg + ((size_t)(b * NN + n0 + r)) * DMM + h * DH + s2 * 16;
    unsigned short th[16], tl[16];
#pragma unroll
    for (int t = 0; t < 4; ++t) {
      float4 g = *(const float4*)(ksrc + t * 4);
      float f[4] = {g.x * NRM, g.y * NRM, g.z * NRM, g.w * NRM};
#pragma unroll
      for (int j = 0; j < 4; ++j) {
        __half hh = __float2half(f[j]);
        th[t * 4 + j] = __half_as_ushort(hh);
        tl[t * 4 + j] = f2h(f[j] - __half2float(hh));
      }
    }
    *(uint4*)&Khh[r][s2 * 16]     = *(uint4*)&th[0];
    *(uint4*)&Khh[r][s2 * 16 + 8] = *(uint4*)&th[8];
    *(uint4*)&Khl[r][s2 * 16]     = *(uint4*)&tl[0];
    *(uint4*)&Khl[r][s2 * 16 + 8] = *(uint4*)&tl[8];
  }
  __syncthreads();

  const int wn0 = wid * 64;
  f32x4 acc[4][4];
#pragma unroll
  for (int i = 0; i < 4; ++i)
#pragma unroll
    for (int j = 0; j < 4; ++j) acc[i][j] = zf;

#pragma unroll
  for (int ks = 0; ks < 2; ++ks) {
    fp16x8 afh[4], afl[4], bfh[4], bfl[4];
#pragma unroll
    for (int t = 0; t < 4; ++t) {
      afh[t] = *(const fp16x8*)&Khh[t * 16 + l16][ks * 32 + quad * 8];
      afl[t] = *(const fp16x8*)&Khl[t * 16 + l16][ks * 32 + quad * 8];
      const size_t po = (size_t)(wn0 + t * 16 + l16) * 64 + ks * 32 + quad * 8;
      bfh[t] = *(const fp16x8*)(phh + po);
      bfl[t] = *(const fp16x8*)(phl + po);
    }
#pragma unroll
    for (int mt = 0; mt < 4; ++mt)
#pragma unroll
      for (int nt = 0; nt < 4; ++nt) {
        acc[mt][nt] = __builtin_amdgcn_mfma_f32_16x16x32_f16(afh[mt], bfh[nt], acc[mt][nt], 0, 0, 0);
        acc[mt][nt] = __builtin_amdgcn_mfma_f32_16x16x32_f16(afh[mt], bfl[nt], acc[mt][nt], 0, 0, 0);
        acc[mt][nt] = __builtin_amdgcn_mfma_f32_16x16x32_f16(afl[mt], bfh[nt], acc[mt][nt], 0, 0, 0);
      }
  }

  float mx = -3.4e38f;
#pragma unroll
  for (int mt = 0; mt < 4; ++mt)
#pragma unroll
    for (int nt = 0; nt < 4; ++nt)
#pragma unroll
      for (int r = 0; r < 4; ++r) mx = fmaxf(mx, acc[mt][nt][r]);
#pragma unroll
  for (int off = 32; off; off >>= 1) mx = fmaxf(mx, __shfl_xor(mx, off));
  if (lane == 0) wred[wid] = mx;
  __syncthreads();
  if (tid == 0) {
    float m2 = fmaxf(fmaxf(wred[0], wred[1]), fmaxf(wred[2], wred[3]));
    atomicMax(stab_enc, enc_f32(m2));
  }
}

/* ---------------- FAVOR: context & k_sum partials via MFMA ----------------- */
__global__ __launch_bounds__(256, 2) void favor_ctx_mfma(
    const float* __restrict__ Kg, const float* __restrict__ Vg,
    const unsigned short* __restrict__ phh, const unsigned short* __restrict__ phl,
    const unsigned* __restrict__ stab_enc,
    float* __restrict__ ctxp, float* __restrict__ ksump, int split)
{
  __shared__ unsigned short Khh[64][72];
  __shared__ unsigned short Khl[64][72];
  __shared__ unsigned short Vt_h[64][72];   /* [d][n] */
  __shared__ unsigned short kp_s[256][72];  /* [m][n] */
  __shared__ float diag_s[64];

  const int tid = threadIdx.x;
  const int wid = tid >> 6, lane = tid & 63;
  const int quad = lane >> 4, l16 = lane & 15;
  const int sidx = blockIdx.x % split;
  const int bh = blockIdx.x / split;
  const int b = bh >> 3, h = bh & 7;
  const int rows = NN / split, nch = rows / 64;
  const float stab = dec_f32(*stab_enc);
  const int wn0 = wid * 64;
  const f32x4 zf = {0.f, 0.f, 0.f, 0.f};

  f32x4 acc2[4][4];
#pragma unroll
  for (int i = 0; i < 4; ++i)
#pragma unroll
    for (int j = 0; j < 4; ++j) acc2[i][j] = zf;
  float ksacc[4] = {0.f, 0.f, 0.f, 0.f};

  for (int c = 0; c < nch; ++c) {
    const int n0 = sidx * rows + c * 64;
    __syncthreads();
    /* stage: K split-fp16 [n][d], V fp16 transposed [d][n], diag via shfl */
    {
      const int r = tid >> 2, s2 = tid & 3;
      const float* ksrc = Kg + ((size_t)(b * NN + n0 + r)) * DMM + h * DH + s2 * 16;
      const float* vsrc = Vg + ((size_t)(b * NN + n0 + r)) * DMM + h * DH + s2 * 16;
      float kq = 0.f;
      unsigned short th[16], tl[16];
#pragma unroll
      for (int t = 0; t < 4; ++t) {
        float4 g = *(const float4*)(ksrc + t * 4);
        float f[4] = {g.x * NRM, g.y * NRM, g.z * NRM, g.w * NRM};
#pragma unroll
        for (int j = 0; j < 4; ++j) {
          kq = fmaf(f[j], f[j], kq);
          __half hh = __float2half(f[j]);
          th[t * 4 + j] = __half_as_ushort(hh);
          tl[t * 4 + j] = f2h(f[j] - __half2float(hh));
        }
        float4 vv = *(const float4*)(vsrc + t * 4);
        Vt_h[s2 * 16 + t * 4 + 0][r] = f2h(vv.x);
        Vt_h[s2 * 16 + t * 4 + 1][r] = f2h(vv.y);
        Vt_h[s2 * 16 + t * 4 + 2][r] = f2h(vv.z);
        Vt_h[s2 * 16 + t * 4 + 3][r] = f2h(vv.w);
      }
      *(uint4*)&Khh[r][s2 * 16]     = *(uint4*)&th[0];
      *(uint4*)&Khh[r][s2 * 16 + 8] = *(uint4*)&th[8];
      *(uint4*)&Khl[r][s2 * 16]     = *(uint4*)&tl[0];
      *(uint4*)&Khl[r][s2 * 16 + 8] = *(uint4*)&tl[8];
      kq += __shfl_xor(kq, 1);
      kq += __shfl_xor(kq, 2);
      if (s2 == 0) diag_s[r] = 0.5f * kq;
    }
    __syncthreads();

    /* dd GEMM: rows n=64 x wave's m-block 64, K=64, split-fp16 */
    f32x4 acc[4][4];
#pragma unroll
    for (int i = 0; i < 4; ++i)
#pragma unroll
      for (int j = 0; j < 4; ++j) acc[i][j] = zf;
#pragma unroll
    for (int ks = 0; ks < 2; ++ks) {
      fp16x8 afh[4], afl[4], bfh[4], bfl[4];
#pragma unroll
      for (int t = 0; t < 4; ++t) {
        afh[t] = *(const fp16x8*)&Khh[t * 16 + l16][ks * 32 + quad * 8];
        afl[t] = *(const fp16x8*)&Khl[t * 16 + l16][ks * 32 + quad * 8];
        const size_t po = (size_t)(wn0 + t * 16 + l16) * 64 + ks * 32 + quad * 8;
        bfh[t] = *(const fp16x8*)(phh + po);
        bfl[t] = *(const fp16x8*)(phl + po);
      }
#pragma unroll
      for (int mt = 0; mt < 4; ++mt)
#pragma unroll
        for (int nt = 0; nt < 4; ++nt) {
          acc[mt][nt] = __builtin_amdgcn_mfma_f32_16x16x32_f16(afh[mt], bfh[nt], acc[mt][nt], 0, 0, 0);
          acc[mt][nt] = __builtin_amdgcn_mfma_f32_16x16x32_f16(afh[mt], bfl[nt], acc[mt][nt], 0, 0, 0);
          acc[mt][nt] = __builtin_amdgcn_mfma_f32_16x16x32_f16(afl[mt], bfh[nt], acc[mt][nt], 0, 0, 0);
        }
    }

    /* kp = RATIO*(exp(dd - diag - stab)+EPS); ksum col partials; kp -> LDS */
    float ks_i[4] = {0.f, 0.f, 0.f, 0.f};
#pragma unroll
    for (int mt = 0; mt < 4; ++mt) {
#pragma unroll
      for (int nt = 0; nt < 4; ++nt) {
        float pv[4];
#pragma unroll
        for (int reg = 0; reg < 4; ++reg) {
          const int n = mt * 16 + quad * 4 + reg;
          float p = RATIO * (__expf(acc[mt][nt][reg] - diag_s[n] - stab) + EPSF);
          pv[reg] = p;
          ks_i[nt] += p;
        }
        __half2 h0 = __floats2half2_rn(pv[0], pv[1]);
        __half2 h1 = __floats2half2_rn(pv[2], pv[3]);
        uint2 w;
        w.x = *(unsigned*)&h0;
        w.y = *(unsigned*)&h1;
        *(uint2*)&kp_s[wn0 + nt * 16 + l16][mt * 16 + quad * 4] = w;
      }
    }
#pragma unroll
    for (int nt = 0; nt < 4; ++nt) {
      float s = ks_i[nt];
      s += __shfl_xor(s, 16);
      s += __shfl_xor(s, 32);
      ksacc[nt] += s;
    }
    __syncthreads();

    /* ctx GEMM: wave's 64 m-rows x 64 d-cols, K=n=64, plain fp16 */
#pragma unroll
    for (int ks2 = 0; ks2 < 2; ++ks2) {
      fp16x8 ap[4], bv[4];
#pragma unroll
      for (int t = 0; t < 4; ++t) {
        ap[t] = *(const fp16x8*)&kp_s[wn0 + t * 16 + l16][ks2 * 32 + quad * 8];
        bv[t] = *(const fp16x8*)&Vt_h[t * 16 + l16][ks2 * 32 + quad * 8];
      }
#pragma unroll
      for (int mt = 0; mt < 4; ++mt)
#pragma unroll
        for (int nt = 0; nt < 4; ++nt)
          acc2[mt][nt] = __builtin_amdgcn_mfma_f32_16x16x32_f16(ap[mt], bv[nt], acc2[mt][nt], 0, 0, 0);
    }
  }

  /* write partials: ctxp [bh*split+sidx][d][m], ksump [bh*split+sidx][m] */
  {
    float* dst = ctxp + ((size_t)(bh * split + sidx)) * MM * DH;
#pragma unroll
    for (int mt = 0; mt < 4; ++mt)
#pragma unroll
      for (int nt = 0; nt < 4; ++nt) {
        const int m = wn0 + mt * 16 + quad * 4;
        const int d = nt * 16 + l16;
        *(f32x4*)(dst + (size_t)d * MM + m) = acc2[mt][nt];
      }
    if (quad == 0) {
      float* kd = ksump + (size_t)(bh * split + sidx) * MM;
#pragma unroll
      for (int nt = 0; nt < 4; ++nt) kd[wn0 + nt * 16 + l16] = ksacc[nt];
    }
  }
}

/* ---------------- FAVOR: reduce partials -> ctxT fp16 [bh][d][m] + ksum ---- */
__global__ __launch_bounds__(256) void favor_reduce(
    const float* __restrict__ ctxp, const float* __restrict__ ksump,
    unsigned short* __restrict__ ctxT_h, float* __restrict__ ksum, int split)
{
  int i = blockIdx.x * 256 + threadIdx.x;
  if (i < BB * GHH * MM * DH) {
    int bh = i / (MM * DH);
    int md = i % (MM * DH);           /* md = d*MM + m (partials already [d][m]) */
    float s = 0.f;
    for (int k = 0; k < split; ++k) s += ctxp[((size_t)(bh * split + k)) * MM * DH + md];
    ctxT_h[i] = f2h(s);
  }
  if (i < BB * GHH * MM) {
    int bh = i / MM, m = i % MM;
    float s = 0.f;
    for (int k = 0; k < split; ++k) s += ksump[(bh * split + k) * MM + m];
    ksum[i] = s;
  }
}

/* ---------------- FAVOR fused output via MFMA ------------------------------ */
__global__ __launch_bounds__(256, 2) void favor_out_mfma(
    float* __restrict__ Q, const unsigned short* __restrict__ phh,
    const unsigned short* __restrict__ phl,
    const unsigned short* __restrict__ ctxT_h, const float* __restrict__ ksum)
{
  __shared__ unsigned short Qhh[64][72];
  __shared__ unsigned short Qhl[64][72];
  __shared__ unsigned short qp_s[64][264];
  __shared__ float red[4][64];
  __shared__ float dred[4][64];
  __shared__ float diag4[64][4];
  __shared__ float diag_s[64];
  __shared__ float dinv_s[64];
  __shared__ float ksum_s[256];

  const int tid = threadIdx.x;
  const int wid = tid >> 6, lane = tid & 63;
  const int quad = lane >> 4, l16 = lane & 15;
  const int bh = blockIdx.x >> 6;
  const int chunk = blockIdx.x & 63;
  const int b = bh >> 3, h = bh & 7;
  const int n0 = chunk * 64;
  const f32x4 zf = {0.f, 0.f, 0.f, 0.f};

  /* load Q chunk: scale, split fp16 hi/lo, diag partials */
  {
    const int r = tid >> 2, s2 = tid & 3;
    const float* src = Q + ((size_t)(b * NN + n0 + r)) * DMM + h * DH + s2 * 16;
    float sq = 0.f;
    unsigned short th[16], tl[16];
#pragma unroll
    for (int t = 0; t < 4; ++t) {
      float4 g = *(const float4*)(src + t * 4);
      float f[4] = {g.x * NRM, g.y * NRM, g.z * NRM, g.w * NRM};
#pragma unroll
      for (int j = 0; j < 4; ++j) {
        sq = fmaf(f[j], f[j], sq);
        __half hh = __float2half(f[j]);
        th[t * 4 + j] = __half_as_ushort(hh);
        tl[t * 4 + j] = f2h(f[j] - __half2float(hh));
      }
    }
    diag4[r][s2] = sq;
    *(uint4*)&Qhh[r][s2 * 16]     = *(uint4*)&th[0];
    *(uint4*)&Qhh[r][s2 * 16 + 8] = *(uint4*)&th[8];
    *(uint4*)&Qhl[r][s2 * 16]     = *(uint4*)&tl[0];
    *(uint4*)&Qhl[r][s2 * 16 + 8] = *(uint4*)&tl[8];
    ksum_s[tid] = ksum[bh * MM + tid];
  }
  __syncthreads();
  if (tid < 64)
    diag_s[tid] = 0.5f * (diag4[tid][0] + diag4[tid][1] + diag4[tid][2] + diag4[tid][3]);

  /* dd GEMM: rows 64 x wave's 64 feature-cols, K=64, split-fp16 (hh+hl+lh) */
  const int wn0 = wid * 64;
  f32x4 acc[4][4];
#pragma unroll
  for (int i = 0; i < 4; ++i)
#pragma unroll
    for (int j = 0; j < 4; ++j) acc[i][j] = zf;

#pragma unroll
  for (int ks = 0; ks < 2; ++ks) {
    fp16x8 afh[4], afl[4], bfh[4], bfl[4];
#pragma unroll
    for (int t = 0; t < 4; ++t) {
      afh[t] = *(const fp16x8*)&Qhh[t * 16 + l16][ks * 32 + quad * 8];
      afl[t] = *(const fp16x8*)&Qhl[t * 16 + l16][ks * 32 + quad * 8];
      const size_t po = (size_t)(wn0 + t * 16 + l16) * 64 + ks * 32 + quad * 8;
      bfh[t] = *(const fp16x8*)(phh + po);
      bfl[t] = *(const fp16x8*)(phl + po);
    }
#pragma unroll
    for (int mt = 0; mt < 4; ++mt)
#pragma unroll
      for (int nt = 0; nt < 4; ++nt) {
        acc[mt][nt] = __builtin_amdgcn_mfma_f32_16x16x32_f16(afh[mt], bfh[nt], acc[mt][nt], 0, 0, 0);
        acc[mt][nt] = __builtin_amdgcn_mfma_f32_16x16x32_f16(afh[mt], bfl[nt], acc[mt][nt], 0, 0, 0);
        acc[mt][nt] = __builtin_amdgcn_mfma_f32_16x16x32_f16(afl[mt], bfh[nt], acc[mt][nt], 0, 0, 0);
      }
  }

  /* per-row wave-local max -> LDS */
#pragma unroll
  for (int mt = 0; mt < 4; ++mt)
#pragma unroll
    for (int reg = 0; reg < 4; ++reg) {
      float v = fmaxf(fmaxf(acc[mt][0][reg], acc[mt][1][reg]),
                      fmaxf(acc[mt][2][reg], acc[mt][3][reg]));
      v = fmaxf(v, __shfl_xor(v, 1));
      v = fmaxf(v, __shfl_xor(v, 2));
      v = fmaxf(v, __shfl_xor(v, 4));
      v = fmaxf(v, __shfl_xor(v, 8));
      if (l16 == 0) red[wid][mt * 16 + quad * 4 + reg] = v;
    }
  __syncthreads();

  /* qp = RATIO*(exp(dd - diag - stab) + EPS); dsum partials; qp -> fp16 LDS */
  float ksv[4];
#pragma unroll
  for (int nt = 0; nt < 4; ++nt) ksv[nt] = ksum_s[wn0 + nt * 16 + l16];
#pragma unroll
  for (int mt = 0; mt < 4; ++mt)
#pragma unroll
    for (int reg = 0; reg < 4; ++reg) {
      const int row = mt * 16 + quad * 4 + reg;
      float stab = fmaxf(fmaxf(red[0][row], red[1][row]),
                         fmaxf(red[2][row], red[3][row]));
      float base = diag_s[row] + stab;
      float dsum = 0.f;
#pragma unroll
      for (int nt = 0; nt < 4; ++nt) {
        float p = RATIO * (__expf(acc[mt][nt][reg] - base) + EPSF);
        acc[mt][nt][reg] = p;
        dsum = fmaf(p, ksv[nt], dsum);
      }
      dsum += __shfl_xor(dsum, 1);
      dsum += __shfl_xor(dsum, 2);
      dsum += __shfl_xor(dsum, 4);
      dsum += __shfl_xor(dsum, 8);
      if (l16 == 0) dred[wid][row] = dsum;
#pragma unroll
      for (int nt = 0; nt < 4; ++nt)
        qp_s[row][wn0 + nt * 16 + l16] = f2h(acc[mt][nt][reg]);
    }
  __syncthreads();
  if (tid < 64)
    dinv_s[tid] = 1.0f / (dred[0][tid] + dred[1][tid] + dred[2][tid] + dred[3][tid]);

  /* PV: out[64 x wave's 16 d-cols] = qp[64x256] @ ctxT rows, K=256 */
  const int wn2 = wid * 16;
  f32x4 acc2[4];
#pragma unroll
  for (int mt = 0; mt < 4; ++mt) acc2[mt] = zf;
#pragma unroll
  for (int ksp = 0; ksp < 8; ++ksp) {
    fp16x8 bv = *(const fp16x8*)(ctxT_h + ((size_t)bh * DH + wn2 + l16) * MM + ksp * 32 + quad * 8);
    fp16x8 ap[4];
#pragma unroll
    for (int mt = 0; mt < 4; ++mt)
      ap[mt] = *(const fp16x8*)&qp_s[mt * 16 + l16][ksp * 32 + quad * 8];
#pragma unroll
    for (int mt = 0; mt < 4; ++mt)
      acc2[mt] = __builtin_amdgcn_mfma_f32_16x16x32_f16(ap[mt], bv, acc2[mt], 0, 0, 0);
  }
  __syncthreads();

  /* epilogue: scale by 1/dsum, store */
#pragma unroll
  for (int mt = 0; mt < 4; ++mt)
#pragma unroll
    for (int reg = 0; reg < 4; ++reg) {
      const int row = mt * 16 + quad * 4 + reg;
      Q[((size_t)(b * NN + n0 + row)) * DMM + h * DH + wn2 + l16] =
          acc2[mt][reg] * dinv_s[row];
    }
}

/* ---------------- launcher -------------------------------------------------- */
extern "C" void kernel_launch(void* const* d_in, const int* in_sizes, int n_in,
                              void* d_out, int out_size, void* d_ws, size_t ws_size,
                              hipStream_t stream)
{
  (void)in_sizes; (void)n_in; (void)out_size;
  const float* x    = (const float*)d_in[0];
  const float* Wq   = (const float*)d_in[2];
  const float* Wk   = (const float*)d_in[3];
  const float* Wv   = (const float*)d_in[4];
  const float* Wo   = (const float*)d_in[5];
  const float* bo   = (const float*)d_in[6];
  const float* proj = (const float*)d_in[7];
  float* out = (float*)d_out;

  const size_t WSZ = (size_t)DMM * DMM;
  const size_t XSP = (size_t)BB * NN * DMM;            /* elems per activation plane */
  const size_t wbuf_f = (8 * WSZ * 2 + 3) / 4;
  const size_t LSZ = (size_t)BB * LHH * NN * DH;       /* u16 elems per local buf */
  const size_t lbuf_f = (3 * LSZ * 2 + 3) / 4;
  const size_t fixed_f = (size_t)3 * XSP + (size_t)BB * GHH * MM * DH
                       + (size_t)BB * GHH * MM + 16 + MM * DH + MM * DH + 16
                       + wbuf_f + 16 + lbuf_f + 16;

  /* region: time-shared between ctxp/ksump (FAVOR phase) and xH/xL split
   * activation planes (GEMM phases) — live ranges are disjoint.            */
  int split = 8, use_pre = 0;
  for (int s = 32; s >= 8; s >>= 1) {
    size_t part = (size_t)BB * GHH * s * (MM * DH + MM);
    size_t region = part > XSP ? part : XSP;
    if ((fixed_f + region) * 4 <= ws_size) { split = s; use_pre = 1; break; }
  }
  if (!use_pre) {
    for (int s = 32; s >= 8; s >>= 1) {
      size_t need = (fixed_f + (size_t)BB * GHH * s * (MM * DH + MM)) * 4;
      if (need <= ws_size) { split = s; break; }
    }
  }
  size_t part_f = (size_t)BB * GHH * split * (MM * DH + MM);
  size_t region_f = (use_pre && XSP > part_f) ? XSP : part_f;

  float* Qb    = (float*)d_ws;
  float* Kb    = Qb + XSP;
  float* Vb    = Kb + XSP;
  float* region = Vb + XSP;
  float* ctxp  = region;
  float* ksump = ctxp + (size_t)BB * GHH * split * MM * DH;
  unsigned short* xH = (unsigned short*)region;
  unsigned short* xL = xH + XSP;
  float* ctx   = region + region_f;                 /* region holds ctxT fp16 */
  unsigned short* ctxT_h = (unsigned short*)ctx;
  float* ksum  = ctx + (size_t)BB * GHH * MM * DH;
  unsigned* stab = (unsigned*)(ksum + BB * GHH * MM);
  float* projT = (float*)(stab + 16);
  unsigned short* proj_hh = (unsigned short*)(projT + MM * DH);
  unsigned short* proj_hl = proj_hh + MM * DH;
  unsigned short* wsp = proj_hl + MM * DH;
  unsigned short* WqH = wsp;            unsigned short* WqL = wsp + WSZ;
  unsigned short* WkH = wsp + 2 * WSZ;  unsigned short* WkL = wsp + 3 * WSZ;
  unsigned short* WvH = wsp + 4 * WSZ;  unsigned short* WvL = wsp + 5 * WSZ;
  unsigned short* WoH = wsp + 6 * WSZ;  unsigned short* WoL = wsp + 7 * WSZ;
  unsigned short* Qlh = wsp + 8 * WSZ;
  unsigned short* Klh = Qlh + LSZ;
  unsigned short* Vtl = Klh + LSZ;

  dim3 blk(256);
  dim3 mg(DMM / 128, (BB * NN) / 128);
  const int wgrid = (int)(WSZ / 256);
  const int agrid = (int)(XSP / 1024);

  w_split<<<wgrid, blk, 0, stream>>>(Wq, WqH, WqL);
  w_split<<<wgrid, blk, 0, stream>>>(Wk, WkH, WkL);
  w_split<<<wgrid, blk, 0, stream>>>(Wv, WvH, WvL);
  w_split<<<wgrid, blk, 0, stream>>>(Wo, WoH, WoL);
  if (use_pre) {
    a_split<<<agrid, blk, 0, stream>>>(x, xH, xL);
    gemm_mfma_pre<<<mg, blk, 0, stream>>>(xH, xL, WqH, WqL, nullptr, Qb, DMM, DMM);
    gemm_mfma_pre<<<mg, blk, 0, stream>>>(xH, xL, WkH, WkL, nullptr, Kb, DMM, DMM);
    gemm_mfma_pre<<<mg, blk, 0, stream>>>(xH, xL, WvH, WvL, nullptr, Vb, DMM, DMM);
  } else {
    gemm_mfma<<<mg, blk, 0, stream>>>(x, WqH, WqL, nullptr, Qb, DMM, DMM);
    gemm_mfma<<<mg, blk, 0, stream>>>(x, WkH, WkL, nullptr, Kb, DMM, DMM);
    gemm_mfma<<<mg, blk, 0, stream>>>(x, WvH, WvL, nullptr, Vb, DMM, DMM);
  }
  rot_qk<<<(BB * LHH * NN) / 256, blk, 0, stream>>>(Qb, Kb, Qlh, Klh);
  v_trans<<<dim3(NN / 64, LHH, BB), blk, 0, stream>>>(Vb, Vtl);
  init_stab<<<1, 64, 0, stream>>>(stab);
  transpose_proj<<<64, blk, 0, stream>>>(proj, projT, proj_hh, proj_hl);
  favor_kstab_mfma<<<BB * GHH * (NN / 64), blk, 0, stream>>>(Kb, proj_hh, proj_hl, stab);
  favor_ctx_mfma<<<BB * GHH * split, blk, 0, stream>>>(Kb, Vb, proj_hh, proj_hl, stab, ctxp, ksump, split);
  favor_reduce<<<(BB * GHH * MM * DH) / 256, blk, 0, stream>>>(ctxp, ksump, ctxT_h, ksum, split);
  favor_out_mfma<<<BB * GHH * (NN / 64), blk, 0, stream>>>(Qb, proj_hh, proj_hl, ctxT_h, ksum);
  local_attn2<<<dim3(NWIN, LHH, BB), blk, 0, stream>>>(Qlh, Klh, Vtl, Qb);
  if (use_pre) {
    a_split<<<agrid, blk, 0, stream>>>(Qb, xH, xL);
    gemm_mfma_pre<<<mg, blk, 0, stream>>>(xH, xL, WoH, WoL, bo, out, DMM, DMM);
  } else {
    gemm_mfma<<<mg, blk, 0, stream>>>(Qb, WoH, WoL, bo, out, DMM, DMM);
  }
}

// Round 5
// 546.420 us; speedup vs baseline: 1.8489x; 1.2299x over previous
//
#include <hip/hip_runtime.h>
#include <hip/hip_fp16.h>
#include <math.h>

#define BB 4
#define NN 4096
#define DMM 768
#define HHH 12
#define LHH 4
#define GHH 8
#define DH 64
#define MM 256
#define WW 128
#define NWIN (NN/WW)
#define EPSF 1.0e-4f
#define NRM 0.35355339059327373f   /* 64^-0.25 */
#define NRM2 0.125f                /* 64^-0.5  */
#define RATIO 0.0625f              /* 256^-0.5 */
#define LN1E4_32 0.28782313662425572f  /* ln(10000)/32 */

using bf16x8 = __attribute__((ext_vector_type(8))) short;
using fp16x8 = __attribute__((ext_vector_type(8))) _Float16;
using f32x4  = __attribute__((ext_vector_type(4))) float;

static __device__ __forceinline__ unsigned enc_f32(float f) {
  unsigned u = __float_as_uint(f);
  return (u & 0x80000000u) ? ~u : (u | 0x80000000u);
}
static __device__ __forceinline__ float dec_f32(unsigned u) {
  unsigned b = (u & 0x80000000u) ? (u ^ 0x80000000u) : ~u;
  return __uint_as_float(b);
}
static __device__ __forceinline__ unsigned short f2h(float x) {
  return __half_as_ushort(__float2half(x));
}
/* direct global->LDS 16B DMA (linear LDS dest: wave-uniform base + lane*16) */
static __device__ __forceinline__ void gload16(const unsigned short* g, unsigned short* l) {
  __builtin_amdgcn_global_load_lds(
      (const __attribute__((address_space(1))) void*)g,
      (__attribute__((address_space(3))) void*)l, 16, 0, 0);
}

/* ------- W prep: transpose to [n][k], fp16 RN hi plane (lo not needed:
 * GEMM keeps only the l_a*h_b cross term of the fp16 split) --------------- */
__global__ __launch_bounds__(256) void w_split(
    const float* __restrict__ W, unsigned short* __restrict__ Whi)
{
  int o = blockIdx.x * 256 + threadIdx.x;     /* 768*768 */
  int k = o / DMM, n = o % DMM;
  Whi[(size_t)n * DMM + k] = f2h(W[o]);
}

/* ------- activation prep: split fp32 [M][K] into fp16 hi/lo planes -------- */
__global__ __launch_bounds__(256) void a_split(
    const float* __restrict__ A, unsigned short* __restrict__ Ahi,
    unsigned short* __restrict__ Alo)
{
  size_t o = ((size_t)blockIdx.x * 256 + threadIdx.x) * 4;
  float4 v = *(const float4*)(A + o);
  float f[4] = {v.x, v.y, v.z, v.w};
  unsigned short hi[4], lo[4];
#pragma unroll
  for (int i = 0; i < 4; ++i) {
    __half h = __float2half(f[i]);
    hi[i] = __half_as_ushort(h);
    lo[i] = f2h(f[i] - __half2float(h));
  }
  *(uint2*)(Ahi + o) = *(uint2*)&hi[0];
  *(uint2*)(Alo + o) = *(uint2*)&lo[0];
}

/* ------- split-fp16 MFMA GEMM (fallback: converts A in-kernel) ------------ */
__global__ __launch_bounds__(256) void gemm_mfma(
    const float* __restrict__ A, const unsigned short* __restrict__ Bhi,
    const float* __restrict__ bias, float* __restrict__ C, int K, int Nc)
{
  __shared__ unsigned short Ah[128][40];
  __shared__ unsigned short Al[128][40];
  __shared__ unsigned short Bh[128][40];

  const int tid = threadIdx.x;
  const int wid = tid >> 6, lane = tid & 63;
  const int quad = lane >> 4, l16 = lane & 15;
  const int row0 = blockIdx.y * 128;
  const int col0 = blockIdx.x * 128;
  const int wm = (wid & 1) * 64, wn = (wid >> 1) * 64;
  const int sr = tid >> 1;
  const int sk = (tid & 1) * 16;

  f32x4 acc[4][4];
  const f32x4 zf = {0.f, 0.f, 0.f, 0.f};
#pragma unroll
  for (int i = 0; i < 4; ++i)
#pragma unroll
    for (int j = 0; j < 4; ++j) acc[i][j] = zf;

  for (int k0 = 0; k0 < K; k0 += 32) {
    __syncthreads();
    {
      const float* a = A + (size_t)(row0 + sr) * K + k0 + sk;
      float fv[16];
      *(float4*)&fv[0]  = *(const float4*)(a);
      *(float4*)&fv[4]  = *(const float4*)(a + 4);
      *(float4*)&fv[8]  = *(const float4*)(a + 8);
      *(float4*)&fv[12] = *(const float4*)(a + 12);
      unsigned hw[8], lw[8];
#pragma unroll
      for (int p = 0; p < 8; ++p) {
        float x0 = fv[2 * p], x1 = fv[2 * p + 1];
        __half h0 = __float2half(x0), h1 = __float2half(x1);
        unsigned short l0 = f2h(x0 - __half2float(h0));
        unsigned short l1 = f2h(x1 - __half2float(h1));
        hw[p] = (unsigned)__half_as_ushort(h0) | ((unsigned)__half_as_ushort(h1) << 16);
        lw[p] = (unsigned)l0 | ((unsigned)l1 << 16);
      }
      *(uint4*)&Ah[sr][sk]     = *(uint4*)&hw[0];
      *(uint4*)&Ah[sr][sk + 8] = *(uint4*)&hw[4];
      *(uint4*)&Al[sr][sk]     = *(uint4*)&lw[0];
      *(uint4*)&Al[sr][sk + 8] = *(uint4*)&lw[4];
    }
    {
      const unsigned short* bh = Bhi + (size_t)(col0 + sr) * DMM + k0 + sk;
      *(uint4*)&Bh[sr][sk]     = *(const uint4*)(bh);
      *(uint4*)&Bh[sr][sk + 8] = *(const uint4*)(bh + 8);
    }
    __syncthreads();

    fp16x8 afh[4], afl[4], bfh[4];
#pragma unroll
    for (int t = 0; t < 4; ++t) {
      afh[t] = *(const fp16x8*)&Ah[wm + t * 16 + l16][quad * 8];
      afl[t] = *(const fp16x8*)&Al[wm + t * 16 + l16][quad * 8];
      bfh[t] = *(const fp16x8*)&Bh[wn + t * 16 + l16][quad * 8];
    }
#pragma unroll
    for (int ti = 0; ti < 4; ++ti)
#pragma unroll
      for (int tj = 0; tj < 4; ++tj) {
        acc[ti][tj] = __builtin_amdgcn_mfma_f32_16x16x32_f16(afh[ti], bfh[tj], acc[ti][tj], 0, 0, 0);
        acc[ti][tj] = __builtin_amdgcn_mfma_f32_16x16x32_f16(afl[ti], bfh[tj], acc[ti][tj], 0, 0, 0);
      }
  }

  float bv[4] = {0.f, 0.f, 0.f, 0.f};
  if (bias) {
#pragma unroll
    for (int tj = 0; tj < 4; ++tj) bv[tj] = bias[col0 + wn + tj * 16 + l16];
  }
#pragma unroll
  for (int ti = 0; ti < 4; ++ti) {
    const int gr = row0 + wm + ti * 16 + quad * 4;
#pragma unroll
    for (int tj = 0; tj < 4; ++tj) {
      const int gc = col0 + wn + tj * 16 + l16;
      float* cp = C + (size_t)gr * Nc + gc;
#pragma unroll
      for (int r = 0; r < 4; ++r)
        cp[(size_t)r * Nc] = acc[ti][tj][r] + bv[tj];
    }
  }
}

/* ------- split-fp16 MFMA GEMM, pre-split A planes (hot path) ---------------
 * 2 MFMAs per product (hh + lo_A*h_B; h_A*lo_B term ~8e-5, dropped).
 * global_load_lds(16B) staging, 3 planes, XOR-swizzled k-chunks,
 * XCD-contiguous block remap.                                              */
__global__ __launch_bounds__(256) void gemm_mfma_pre(
    const unsigned short* __restrict__ Ahi, const unsigned short* __restrict__ Alo,
    const unsigned short* __restrict__ Bhi,
    const float* __restrict__ bias, float* __restrict__ C, int K, int Nc)
{
  __shared__ unsigned short Ah[128][32];
  __shared__ unsigned short Al[128][32];
  __shared__ unsigned short Bh[128][32];

  const int tid = threadIdx.x;
  const int wid = tid >> 6, lane = tid & 63;
  const int quad = lane >> 4, l16 = lane & 15;

  /* XCD-contiguous remap: each XCD gets a contiguous range of row-panels   */
  const int nwg = gridDim.x * gridDim.y;
  int hw = blockIdx.y * gridDim.x + blockIdx.x;
  int logical = ((nwg & 7) == 0) ? ((hw & 7) * (nwg >> 3) + (hw >> 3)) : hw;
  const int col0 = (logical % gridDim.x) * 128;
  const int row0 = (logical / gridDim.x) * 128;

  const int wm = (wid & 1) * 64, wn = (wid >> 1) * 64;
  const int sw8 = (quad ^ ((l16 >> 1) & 3)) * 8;   /* swizzled read col (shorts) */

  /* staging geometry: LDS dest linear tid*16B; source k-chunk pre-swizzled */
  const int rr = tid >> 2;
  const int cg8 = ((tid & 3) ^ ((tid >> 3) & 3)) * 8;

  f32x4 acc[4][4];
  const f32x4 zf = {0.f, 0.f, 0.f, 0.f};
#pragma unroll
  for (int i = 0; i < 4; ++i)
#pragma unroll
    for (int j = 0; j < 4; ++j) acc[i][j] = zf;

  for (int k0 = 0; k0 < K; k0 += 32) {
    __syncthreads();
    {
      const size_t ro0 = (size_t)(row0 + rr) * K + k0 + cg8;
      const size_t ro1 = (size_t)(row0 + 64 + rr) * K + k0 + cg8;
      const size_t co0 = (size_t)(col0 + rr) * K + k0 + cg8;
      const size_t co1 = (size_t)(col0 + 64 + rr) * K + k0 + cg8;
      unsigned short* la  = &Ah[0][0] + tid * 8;
      unsigned short* lal = &Al[0][0] + tid * 8;
      unsigned short* lb  = &Bh[0][0] + tid * 8;
      gload16(Ahi + ro0, la);
      gload16(Ahi + ro1, la + 2048);
      gload16(Alo + ro0, lal);
      gload16(Alo + ro1, lal + 2048);
      gload16(Bhi + co0, lb);
      gload16(Bhi + co1, lb + 2048);
    }
    __syncthreads();

    fp16x8 afh[4], afl[4], bfh[4];
#pragma unroll
    for (int t = 0; t < 4; ++t) {
      afh[t] = *(const fp16x8*)&Ah[wm + t * 16 + l16][sw8];
      afl[t] = *(const fp16x8*)&Al[wm + t * 16 + l16][sw8];
      bfh[t] = *(const fp16x8*)&Bh[wn + t * 16 + l16][sw8];
    }
#pragma unroll
    for (int ti = 0; ti < 4; ++ti)
#pragma unroll
      for (int tj = 0; tj < 4; ++tj) {
        acc[ti][tj] = __builtin_amdgcn_mfma_f32_16x16x32_f16(afh[ti], bfh[tj], acc[ti][tj], 0, 0, 0);
        acc[ti][tj] = __builtin_amdgcn_mfma_f32_16x16x32_f16(afl[ti], bfh[tj], acc[ti][tj], 0, 0, 0);
      }
  }

  float bv[4] = {0.f, 0.f, 0.f, 0.f};
  if (bias) {
#pragma unroll
    for (int tj = 0; tj < 4; ++tj) bv[tj] = bias[col0 + wn + tj * 16 + l16];
  }
#pragma unroll
  for (int ti = 0; ti < 4; ++ti) {
    const int gr = row0 + wm + ti * 16 + quad * 4;
#pragma unroll
    for (int tj = 0; tj < 4; ++tj) {
      const int gc = col0 + wn + tj * 16 + l16;
      float* cp = C + (size_t)gr * Nc + gc;
#pragma unroll
      for (int r = 0; r < 4; ++r)
        cp[(size_t)r * Nc] = acc[ti][tj][r] + bv[tj];
    }
  }
}

/* ---------------- init global stabilizer ---------------------------------- */
__global__ void init_stab(unsigned* stab_enc) {
  if (threadIdx.x == 0 && blockIdx.x == 0) *stab_enc = 0x00800000u; /* enc(-FLT_MAX) */
}

/* ---------------- proj prep: projT fp32 + [m][d] fp16 hi/lo planes --------- */
__global__ __launch_bounds__(256) void transpose_proj(
    const float* __restrict__ proj, float* __restrict__ projT,
    unsigned short* __restrict__ phh, unsigned short* __restrict__ phl)
{
  int o = blockIdx.x * 256 + threadIdx.x;   /* 16384 */
  int k = o >> 8, m = o & 255;
  float v = proj[m * 64 + k];
  projT[k * 256 + m] = v;
  __half hh = __float2half(v);
  float lf = v - __half2float(hh);
  phh[m * 64 + k] = __half_as_ushort(hh);
  phl[m * 64 + k] = f2h(lf);
}

/* ---------------- rotary prep for local heads: Q(scaled)/K -> fp16 --------- */
__global__ __launch_bounds__(256) void rot_qk(
    const float* __restrict__ Qb, const float* __restrict__ Kb,
    unsigned short* __restrict__ Qlh, unsigned short* __restrict__ Klh)
{
  int idx = blockIdx.x * 256 + threadIdx.x;    /* (b*LHH+h)*NN + n : 65536 */
  int n = idx & (NN - 1);
  int bh = idx >> 12;
  int b = bh >> 2, h = bh & 3;
  const float* qs = Qb + ((size_t)(b * NN + n)) * DMM + GHH * DH + h * DH;
  const float* ks = Kb + ((size_t)(b * NN + n)) * DMM + GHH * DH + h * DH;
  float q[64], k[64];
#pragma unroll
  for (int t = 0; t < 16; ++t) {
    *(float4*)&q[t * 4] = *(const float4*)(qs + t * 4);
    *(float4*)&k[t * 4] = *(const float4*)(ks + t * 4);
  }
  unsigned short qo[64], ko[64];
#pragma unroll
  for (int i = 0; i < 32; ++i) {
    float invf = __expf((float)i * -LN1E4_32);
    float th = (float)n * invf;
    float s, c;
    sincosf(th, &s, &c);
    qo[i]      = f2h(fmaf(q[i], c, -q[i + 32] * s) * NRM2);
    qo[i + 32] = f2h(fmaf(q[i + 32], c, q[i] * s) * NRM2);
    ko[i]      = f2h(fmaf(k[i], c, -k[i + 32] * s));
    ko[i + 32] = f2h(fmaf(k[i + 32], c, k[i] * s));
  }
  unsigned short* qd = Qlh + (size_t)idx * 64;
  unsigned short* kd = Klh + (size_t)idx * 64;
#pragma unroll
  for (int t = 0; t < 8; ++t) {
    *(uint4*)(qd + t * 8) = *(uint4*)&qo[t * 8];
    *(uint4*)(kd + t * 8) = *(uint4*)&ko[t * 8];
  }
}

/* ---------------- V transpose for local heads: fp16 [b][h][d][n] ----------- */
__global__ __launch_bounds__(256) void v_trans(
    const float* __restrict__ Vb, unsigned short* __restrict__ Vt)
{
  __shared__ unsigned short T[64][72];
  const int nb = blockIdx.x, h = blockIdx.y, b = blockIdx.z;
  const int n0 = nb * 64;
  const int tid = threadIdx.x;
  {
    int r = tid >> 2, g = tid & 3;
    const float* src = Vb + ((size_t)(b * NN + n0 + r)) * DMM + GHH * DH + h * DH + g * 16;
#pragma unroll
    for (int t = 0; t < 4; ++t) {
      float4 v = *(const float4*)(src + t * 4);
      T[g * 16 + t * 4 + 0][r] = f2h(v.x);
      T[g * 16 + t * 4 + 1][r] = f2h(v.y);
      T[g * 16 + t * 4 + 2][r] = f2h(v.z);
      T[g * 16 + t * 4 + 3][r] = f2h(v.w);
    }
  }
  __syncthreads();
  {
    int d = tid >> 2, g = tid & 3;
    unsigned short* dst = Vt + ((size_t)(b * LHH + h) * DH + d) * NN + n0 + g * 16;
    *(uint4*)dst       = *(uint4*)&T[d][g * 16];
    *(uint4*)(dst + 8) = *(uint4*)&T[d][g * 16 + 8];
  }
}

/* ---------------- local attention via f16 MFMA (flash-style) --------------- */
__global__ __launch_bounds__(256) void local_attn2(
    const unsigned short* __restrict__ Qlh, const unsigned short* __restrict__ Klh,
    const unsigned short* __restrict__ Vt, float* __restrict__ Qb)
{
  __shared__ unsigned short Pl[4][32][72];
  const int w = blockIdx.x, h = blockIdx.y, b = blockIdx.z;
  const int tid = threadIdx.x;
  const int wid = tid >> 6, lane = tid & 63;
  const int quad = lane >> 4, l16 = lane & 15;
  const int bh = b * LHH + h;
  const int qn0 = w * WW + wid * 32;

  fp16x8 Aq[2][2];
#pragma unroll
  for (int mt = 0; mt < 2; ++mt)
#pragma unroll
    for (int ks = 0; ks < 2; ++ks)
      Aq[mt][ks] = *(const fp16x8*)(Qlh + ((size_t)bh * NN + qn0 + mt * 16 + l16) * 64 + ks * 32 + quad * 8);

  float m_run[8], l_run[8];
  f32x4 Oacc[2][4];
  const f32x4 zf = {0.f, 0.f, 0.f, 0.f};
#pragma unroll
  for (int r = 0; r < 8; ++r) { m_run[r] = -3.4e38f; l_run[r] = 0.f; }
#pragma unroll
  for (int mt = 0; mt < 2; ++mt)
#pragma unroll
    for (int nt = 0; nt < 4; ++nt) Oacc[mt][nt] = zf;

  const int wb_lo = (w == 0) ? 0 : w - 1;
  const int wb_hi = (w == NWIN - 1) ? w : w + 1;
  for (int wb = wb_lo; wb <= wb_hi; ++wb) {
    for (int half = 0; half < 2; ++half) {
      const int kn0 = wb * WW + half * 64;
      f32x4 sacc[2][4];
#pragma unroll
      for (int mt = 0; mt < 2; ++mt)
#pragma unroll
        for (int nt = 0; nt < 4; ++nt) sacc[mt][nt] = zf;

#pragma unroll
      for (int ks = 0; ks < 2; ++ks) {
        fp16x8 Bk[4];
#pragma unroll
        for (int nt = 0; nt < 4; ++nt)
          Bk[nt] = *(const fp16x8*)(Klh + ((size_t)bh * NN + kn0 + nt * 16 + l16) * 64 + ks * 32 + quad * 8);
#pragma unroll
        for (int mt = 0; mt < 2; ++mt)
#pragma unroll
          for (int nt = 0; nt < 4; ++nt)
            sacc[mt][nt] = __builtin_amdgcn_mfma_f32_16x16x32_f16(Aq[mt][ks], Bk[nt], sacc[mt][nt], 0, 0, 0);
      }

      /* online softmax per row (row = mt*16 + quad*4 + reg) */
#pragma unroll
      for (int mt = 0; mt < 2; ++mt) {
#pragma unroll
        for (int reg = 0; reg < 4; ++reg) {
          const int r8 = mt * 4 + reg;
          float v = fmaxf(fmaxf(sacc[mt][0][reg], sacc[mt][1][reg]),
                          fmaxf(sacc[mt][2][reg], sacc[mt][3][reg]));
          v = fmaxf(v, __shfl_xor(v, 1));
          v = fmaxf(v, __shfl_xor(v, 2));
          v = fmaxf(v, __shfl_xor(v, 4));
          v = fmaxf(v, __shfl_xor(v, 8));
          float mnew = fmaxf(m_run[r8], v);
          float alpha = __expf(m_run[r8] - mnew);
          m_run[r8] = mnew;
          float ps = 0.f;
#pragma unroll
          for (int nt = 0; nt < 4; ++nt) {
            float p = __expf(sacc[mt][nt][reg] - mnew);
            sacc[mt][nt][reg] = p;
            ps += p;
          }
          ps += __shfl_xor(ps, 1);
          ps += __shfl_xor(ps, 2);
          ps += __shfl_xor(ps, 4);
          ps += __shfl_xor(ps, 8);
          l_run[r8] = l_run[r8] * alpha + ps;
#pragma unroll
          for (int nt = 0; nt < 4; ++nt) Oacc[mt][nt][reg] *= alpha;
        }
      }

      /* write P fp16 (C-layout -> [qrow][key] in LDS, wave-local) */
#pragma unroll
      for (int mt = 0; mt < 2; ++mt)
#pragma unroll
        for (int nt = 0; nt < 4; ++nt)
#pragma unroll
          for (int reg = 0; reg < 4; ++reg)
            Pl[wid][mt * 16 + quad * 4 + reg][nt * 16 + l16] = f2h(sacc[mt][nt][reg]);

      /* PV */
#pragma unroll
      for (int kstep = 0; kstep < 2; ++kstep) {
        fp16x8 Ap[2];
#pragma unroll
        for (int mt = 0; mt < 2; ++mt)
          Ap[mt] = *(const fp16x8*)&Pl[wid][mt * 16 + l16][kstep * 32 + quad * 8];
        fp16x8 Bv[4];
#pragma unroll
        for (int nt = 0; nt < 4; ++nt)
          Bv[nt] = *(const fp16x8*)(Vt + ((size_t)bh * DH + nt * 16 + l16) * NN + kn0 + kstep * 32 + quad * 8);
#pragma unroll
        for (int mt = 0; mt < 2; ++mt)
#pragma unroll
          for (int nt = 0; nt < 4; ++nt)
            Oacc[mt][nt] = __builtin_amdgcn_mfma_f32_16x16x32_f16(Ap[mt], Bv[nt], Oacc[mt][nt], 0, 0, 0);
      }
    }
  }

  /* epilogue: divide by l, store fp32 into Qb local-head columns */
#pragma unroll
  for (int mt = 0; mt < 2; ++mt)
#pragma unroll
    for (int reg = 0; reg < 4; ++reg) {
      const float inv = 1.0f / l_run[mt * 4 + reg];
      const int n = qn0 + mt * 16 + quad * 4 + reg;
      float* dst = Qb + ((size_t)(b * NN + n)) * DMM + GHH * DH + h * DH;
#pragma unroll
      for (int nt = 0; nt < 4; ++nt)
        dst[nt * 16 + l16] = Oacc[mt][nt][reg] * inv;
    }
}

/* ---------------- FAVOR: global max of dd_k via MFMA ----------------------- */
__global__ __launch_bounds__(256) void favor_kstab_mfma(
    const float* __restrict__ Kg, const unsigned short* __restrict__ phh,
    const unsigned short* __restrict__ phl, unsigned* __restrict__ stab_enc)
{
  __shared__ unsigned short Khh[64][72];
  __shared__ unsigned short Khl[64][72];
  __shared__ float wred[4];
  const int tid = threadIdx.x;
  const int wid = tid >> 6, lane = tid & 63;
  const int quad = lane >> 4, l16 = lane & 15;
  const int chunk = blockIdx.x & 63;
  const int bh = blockIdx.x >> 6;
  const int b = bh >> 3, h = bh & 7;
  const int n0 = chunk * 64;
  const f32x4 zf = {0.f, 0.f, 0.f, 0.f};

  {
    const int r = tid >> 2, s2 = tid & 3;
    const float* ksrc = Kg + ((size_t)(b * NN + n0 + r)) * DMM + h * DH + s2 * 16;
    unsigned short th[16], tl[16];
#pragma unroll
    for (int t = 0; t < 4; ++t) {
      float4 g = *(const float4*)(ksrc + t * 4);
      float f[4] = {g.x * NRM, g.y * NRM, g.z * NRM, g.w * NRM};
#pragma unroll
      for (int j = 0; j < 4; ++j) {
        __half hh = __float2half(f[j]);
        th[t * 4 + j] = __half_as_ushort(hh);
        tl[t * 4 + j] = f2h(f[j] - __half2float(hh));
      }
    }
    *(uint4*)&Khh[r][s2 * 16]     = *(uint4*)&th[0];
    *(uint4*)&Khh[r][s2 * 16 + 8] = *(uint4*)&th[8];
    *(uint4*)&Khl[r][s2 * 16]     = *(uint4*)&tl[0];
    *(uint4*)&Khl[r][s2 * 16 + 8] = *(uint4*)&tl[8];
  }
  __syncthreads();

  const int wn0 = wid * 64;
  f32x4 acc[4][4];
#pragma unroll
  for (int i = 0; i < 4; ++i)
#pragma unroll
    for (int j = 0; j < 4; ++j) acc[i][j] = zf;

#pragma unroll
  for (int ks = 0; ks < 2; ++ks) {
    fp16x8 afh[4], afl[4], bfh[4], bfl[4];
#pragma unroll
    for (int t = 0; t < 4; ++t) {
      afh[t] = *(const fp16x8*)&Khh[t * 16 + l16][ks * 32 + quad * 8];
      afl[t] = *(const fp16x8*)&Khl[t * 16 + l16][ks * 32 + quad * 8];
      const size_t po = (size_t)(wn0 + t * 16 + l16) * 64 + ks * 32 + quad * 8;
      bfh[t] = *(const fp16x8*)(phh + po);
      bfl[t] = *(const fp16x8*)(phl + po);
    }
#pragma unroll
    for (int mt = 0; mt < 4; ++mt)
#pragma unroll
      for (int nt = 0; nt < 4; ++nt) {
        acc[mt][nt] = __builtin_amdgcn_mfma_f32_16x16x32_f16(afh[mt], bfh[nt], acc[mt][nt], 0, 0, 0);
        acc[mt][nt] = __builtin_amdgcn_mfma_f32_16x16x32_f16(afh[mt], bfl[nt], acc[mt][nt], 0, 0, 0);
        acc[mt][nt] = __builtin_amdgcn_mfma_f32_16x16x32_f16(afl[mt], bfh[nt], acc[mt][nt], 0, 0, 0);
      }
  }

  float mx = -3.4e38f;
#pragma unroll
  for (int mt = 0; mt < 4; ++mt)
#pragma unroll
    for (int nt = 0; nt < 4; ++nt)
#pragma unroll
      for (int r = 0; r < 4; ++r) mx = fmaxf(mx, acc[mt][nt][r]);
#pragma unroll
  for (int off = 32; off; off >>= 1) mx = fmaxf(mx, __shfl_xor(mx, off));
  if (lane == 0) wred[wid] = mx;
  __syncthreads();
  if (tid == 0) {
    float m2 = fmaxf(fmaxf(wred[0], wred[1]), fmaxf(wred[2], wred[3]));
    atomicMax(stab_enc, enc_f32(m2));
  }
}

/* ---------------- FAVOR: context & k_sum partials via MFMA ----------------- */
__global__ __launch_bounds__(256, 2) void favor_ctx_mfma(
    const float* __restrict__ Kg, const float* __restrict__ Vg,
    const unsigned short* __restrict__ phh, const unsigned short* __restrict__ phl,
    const unsigned* __restrict__ stab_enc,
    float* __restrict__ ctxp, float* __restrict__ ksump, int split)
{
  __shared__ unsigned short Khh[64][72];
  __shared__ unsigned short Khl[64][72];
  __shared__ unsigned short Vt_h[64][72];   /* [d][n] */
  __shared__ unsigned short kp_s[256][72];  /* [m][n] */
  __shared__ float diag_s[64];

  const int tid = threadIdx.x;
  const int wid = tid >> 6, lane = tid & 63;
  const int quad = lane >> 4, l16 = lane & 15;
  const int sidx = blockIdx.x % split;
  const int bh = blockIdx.x / split;
  const int b = bh >> 3, h = bh & 7;
  const int rows = NN / split, nch = rows / 64;
  const float stab = dec_f32(*stab_enc);
  const int wn0 = wid * 64;
  const f32x4 zf = {0.f, 0.f, 0.f, 0.f};

  f32x4 acc2[4][4];
#pragma unroll
  for (int i = 0; i < 4; ++i)
#pragma unroll
    for (int j = 0; j < 4; ++j) acc2[i][j] = zf;
  float ksacc[4] = {0.f, 0.f, 0.f, 0.f};

  for (int c = 0; c < nch; ++c) {
    const int n0 = sidx * rows + c * 64;
    __syncthreads();
    /* stage: K split-fp16 [n][d], V fp16 transposed [d][n], diag via shfl */
    {
      const int r = tid >> 2, s2 = tid & 3;
      const float* ksrc = Kg + ((size_t)(b * NN + n0 + r)) * DMM + h * DH + s2 * 16;
      const float* vsrc = Vg + ((size_t)(b * NN + n0 + r)) * DMM + h * DH + s2 * 16;
      float kq = 0.f;
      unsigned short th[16], tl[16];
#pragma unroll
      for (int t = 0; t < 4; ++t) {
        float4 g = *(const float4*)(ksrc + t * 4);
        float f[4] = {g.x * NRM, g.y * NRM, g.z * NRM, g.w * NRM};
#pragma unroll
        for (int j = 0; j < 4; ++j) {
          kq = fmaf(f[j], f[j], kq);
          __half hh = __float2half(f[j]);
          th[t * 4 + j] = __half_as_ushort(hh);
          tl[t * 4 + j] = f2h(f[j] - __half2float(hh));
        }
        float4 vv = *(const float4*)(vsrc + t * 4);
        Vt_h[s2 * 16 + t * 4 + 0][r] = f2h(vv.x);
        Vt_h[s2 * 16 + t * 4 + 1][r] = f2h(vv.y);
        Vt_h[s2 * 16 + t * 4 + 2][r] = f2h(vv.z);
        Vt_h[s2 * 16 + t * 4 + 3][r] = f2h(vv.w);
      }
      *(uint4*)&Khh[r][s2 * 16]     = *(uint4*)&th[0];
      *(uint4*)&Khh[r][s2 * 16 + 8] = *(uint4*)&th[8];
      *(uint4*)&Khl[r][s2 * 16]     = *(uint4*)&tl[0];
      *(uint4*)&Khl[r][s2 * 16 + 8] = *(uint4*)&tl[8];
      kq += __shfl_xor(kq, 1);
      kq += __shfl_xor(kq, 2);
      if (s2 == 0) diag_s[r] = 0.5f * kq;
    }
    __syncthreads();

    /* dd GEMM: rows n=64 x wave's m-block 64, K=64, split-fp16 */
    f32x4 acc[4][4];
#pragma unroll
    for (int i = 0; i < 4; ++i)
#pragma unroll
      for (int j = 0; j < 4; ++j) acc[i][j] = zf;
#pragma unroll
    for (int ks = 0; ks < 2; ++ks) {
      fp16x8 afh[4], afl[4], bfh[4], bfl[4];
#pragma unroll
      for (int t = 0; t < 4; ++t) {
        afh[t] = *(const fp16x8*)&Khh[t * 16 + l16][ks * 32 + quad * 8];
        afl[t] = *(const fp16x8*)&Khl[t * 16 + l16][ks * 32 + quad * 8];
        const size_t po = (size_t)(wn0 + t * 16 + l16) * 64 + ks * 32 + quad * 8;
        bfh[t] = *(const fp16x8*)(phh + po);
        bfl[t] = *(const fp16x8*)(phl + po);
      }
#pragma unroll
      for (int mt = 0; mt < 4; ++mt)
#pragma unroll
        for (int nt = 0; nt < 4; ++nt) {
          acc[mt][nt] = __builtin_amdgcn_mfma_f32_16x16x32_f16(afh[mt], bfh[nt], acc[mt][nt], 0, 0, 0);
          acc[mt][nt] = __builtin_amdgcn_mfma_f32_16x16x32_f16(afh[mt], bfl[nt], acc[mt][nt], 0, 0, 0);
          acc[mt][nt] = __builtin_amdgcn_mfma_f32_16x16x32_f16(afl[mt], bfh[nt], acc[mt][nt], 0, 0, 0);
        }
    }

    /* kp = RATIO*(exp(dd - diag - stab)+EPS); ksum col partials; kp -> LDS */
    float ks_i[4] = {0.f, 0.f, 0.f, 0.f};
#pragma unroll
    for (int mt = 0; mt < 4; ++mt) {
#pragma unroll
      for (int nt = 0; nt < 4; ++nt) {
        float pv[4];
#pragma unroll
        for (int reg = 0; reg < 4; ++reg) {
          const int n = mt * 16 + quad * 4 + reg;
          float p = RATIO * (__expf(acc[mt][nt][reg] - diag_s[n] - stab) + EPSF);
          pv[reg] = p;
          ks_i[nt] += p;
        }
        __half2 h0 = __floats2half2_rn(pv[0], pv[1]);
        __half2 h1 = __floats2half2_rn(pv[2], pv[3]);
        uint2 w;
        w.x = *(unsigned*)&h0;
        w.y = *(unsigned*)&h1;
        *(uint2*)&kp_s[wn0 + nt * 16 + l16][mt * 16 + quad * 4] = w;
      }
    }
#pragma unroll
    for (int nt = 0; nt < 4; ++nt) {
      float s = ks_i[nt];
      s += __shfl_xor(s, 16);
      s += __shfl_xor(s, 32);
      ksacc[nt] += s;
    }
    __syncthreads();

    /* ctx GEMM: wave's 64 m-rows x 64 d-cols, K=n=64, plain fp16 */
#pragma unroll
    for (int ks2 = 0; ks2 < 2; ++ks2) {
      fp16x8 ap[4], bv[4];
#pragma unroll
      for (int t = 0; t < 4; ++t) {
        ap[t] = *(const fp16x8*)&kp_s[wn0 + t * 16 + l16][ks2 * 32 + quad * 8];
        bv[t] = *(const fp16x8*)&Vt_h[t * 16 + l16][ks2 * 32 + quad * 8];
      }
#pragma unroll
      for (int mt = 0; mt < 4; ++mt)
#pragma unroll
        for (int nt = 0; nt < 4; ++nt)
          acc2[mt][nt] = __builtin_amdgcn_mfma_f32_16x16x32_f16(ap[mt], bv[nt], acc2[mt][nt], 0, 0, 0);
    }
  }

  /* write partials: ctxp [bh*split+sidx][d][m], ksump [bh*split+sidx][m] */
  {
    float* dst = ctxp + ((size_t)(bh * split + sidx)) * MM * DH;
#pragma unroll
    for (int mt = 0; mt < 4; ++mt)
#pragma unroll
      for (int nt = 0; nt < 4; ++nt) {
        const int m = wn0 + mt * 16 + quad * 4;
        const int d = nt * 16 + l16;
        *(f32x4*)(dst + (size_t)d * MM + m) = acc2[mt][nt];
      }
    if (quad == 0) {
      float* kd = ksump + (size_t)(bh * split + sidx) * MM;
#pragma unroll
      for (int nt = 0; nt < 4; ++nt) kd[wn0 + nt * 16 + l16] = ksacc[nt];
    }
  }
}

/* ---------------- FAVOR: reduce partials -> ctxT fp16 [bh][d][m] + ksum ---- */
__global__ __launch_bounds__(256) void favor_reduce(
    const float* __restrict__ ctxp, const float* __restrict__ ksump,
    unsigned short* __restrict__ ctxT_h, float* __restrict__ ksum, int split)
{
  int i = blockIdx.x * 256 + threadIdx.x;
  if (i < BB * GHH * MM * DH) {
    int bh = i / (MM * DH);
    int md = i % (MM * DH);           /* md = d*MM + m (partials already [d][m]) */
    float s = 0.f;
    for (int k = 0; k < split; ++k) s += ctxp[((size_t)(bh * split + k)) * MM * DH + md];
    ctxT_h[i] = f2h(s);
  }
  if (i < BB * GHH * MM) {
    int bh = i / MM, m = i % MM;
    float s = 0.f;
    for (int k = 0; k < split; ++k) s += ksump[(bh * split + k) * MM + m];
    ksum[i] = s;
  }
}

/* ---------------- FAVOR fused output via MFMA ------------------------------ */
__global__ __launch_bounds__(256, 2) void favor_out_mfma(
    float* __restrict__ Q, const unsigned short* __restrict__ phh,
    const unsigned short* __restrict__ phl,
    const unsigned short* __restrict__ ctxT_h, const float* __restrict__ ksum)
{
  __shared__ unsigned short Qhh[64][72];
  __shared__ unsigned short Qhl[64][72];
  __shared__ unsigned short qp_s[64][264];
  __shared__ float red[4][64];
  __shared__ float dred[4][64];
  __shared__ float diag4[64][4];
  __shared__ float diag_s[64];
  __shared__ float dinv_s[64];
  __shared__ float ksum_s[256];

  const int tid = threadIdx.x;
  const int wid = tid >> 6, lane = tid & 63;
  const int quad = lane >> 4, l16 = lane & 15;
  const int bh = blockIdx.x >> 6;
  const int chunk = blockIdx.x & 63;
  const int b = bh >> 3, h = bh & 7;
  const int n0 = chunk * 64;
  const f32x4 zf = {0.f, 0.f, 0.f, 0.f};

  /* load Q chunk: scale, split fp16 hi/lo, diag partials */
  {
    const int r = tid >> 2, s2 = tid & 3;
    const float* src = Q + ((size_t)(b * NN + n0 + r)) * DMM + h * DH + s2 * 16;
    float sq = 0.f;
    unsigned short th[16], tl[16];
#pragma unroll
    for (int t = 0; t < 4; ++t) {
      float4 g = *(const float4*)(src + t * 4);
      float f[4] = {g.x * NRM, g.y * NRM, g.z * NRM, g.w * NRM};
#pragma unroll
      for (int j = 0; j < 4; ++j) {
        sq = fmaf(f[j], f[j], sq);
        __half hh = __float2half(f[j]);
        th[t * 4 + j] = __half_as_ushort(hh);
        tl[t * 4 + j] = f2h(f[j] - __half2float(hh));
      }
    }
    diag4[r][s2] = sq;
    *(uint4*)&Qhh[r][s2 * 16]     = *(uint4*)&th[0];
    *(uint4*)&Qhh[r][s2 * 16 + 8] = *(uint4*)&th[8];
    *(uint4*)&Qhl[r][s2 * 16]     = *(uint4*)&tl[0];
    *(uint4*)&Qhl[r][s2 * 16 + 8] = *(uint4*)&tl[8];
    ksum_s[tid] = ksum[bh * MM + tid];
  }
  __syncthreads();
  if (tid < 64)
    diag_s[tid] = 0.5f * (diag4[tid][0] + diag4[tid][1] + diag4[tid][2] + diag4[tid][3]);

  /* dd GEMM: rows 64 x wave's 64 feature-cols, K=64, split-fp16 (hh+hl+lh) */
  const int wn0 = wid * 64;
  f32x4 acc[4][4];
#pragma unroll
  for (int i = 0; i < 4; ++i)
#pragma unroll
    for (int j = 0; j < 4; ++j) acc[i][j] = zf;

#pragma unroll
  for (int ks = 0; ks < 2; ++ks) {
    fp16x8 afh[4], afl[4], bfh[4], bfl[4];
#pragma unroll
    for (int t = 0; t < 4; ++t) {
      afh[t] = *(const fp16x8*)&Qhh[t * 16 + l16][ks * 32 + quad * 8];
      afl[t] = *(const fp16x8*)&Qhl[t * 16 + l16][ks * 32 + quad * 8];
      const size_t po = (size_t)(wn0 + t * 16 + l16) * 64 + ks * 32 + quad * 8;
      bfh[t] = *(const fp16x8*)(phh + po);
      bfl[t] = *(const fp16x8*)(phl + po);
    }
#pragma unroll
    for (int mt = 0; mt < 4; ++mt)
#pragma unroll
      for (int nt = 0; nt < 4; ++nt) {
        acc[mt][nt] = __builtin_amdgcn_mfma_f32_16x16x32_f16(afh[mt], bfh[nt], acc[mt][nt], 0, 0, 0);
        acc[mt][nt] = __builtin_amdgcn_mfma_f32_16x16x32_f16(afh[mt], bfl[nt], acc[mt][nt], 0, 0, 0);
        acc[mt][nt] = __builtin_amdgcn_mfma_f32_16x16x32_f16(afl[mt], bfh[nt], acc[mt][nt], 0, 0, 0);
      }
  }

  /* per-row wave-local max -> LDS */
#pragma unroll
  for (int mt = 0; mt < 4; ++mt)
#pragma unroll
    for (int reg = 0; reg < 4; ++reg) {
      float v = fmaxf(fmaxf(acc[mt][0][reg], acc[mt][1][reg]),
                      fmaxf(acc[mt][2][reg], acc[mt][3][reg]));
      v = fmaxf(v, __shfl_xor(v, 1));
      v = fmaxf(v, __shfl_xor(v, 2));
      v = fmaxf(v, __shfl_xor(v, 4));
      v = fmaxf(v, __shfl_xor(v, 8));
      if (l16 == 0) red[wid][mt * 16 + quad * 4 + reg] = v;
    }
  __syncthreads();

  /* qp = RATIO*(exp(dd - diag - stab) + EPS); dsum partials; qp -> fp16 LDS */
  float ksv[4];
#pragma unroll
  for (int nt = 0; nt < 4; ++nt) ksv[nt] = ksum_s[wn0 + nt * 16 + l16];
#pragma unroll
  for (int mt = 0; mt < 4; ++mt)
#pragma unroll
    for (int reg = 0; reg < 4; ++reg) {
      const int row = mt * 16 + quad * 4 + reg;
      float stab = fmaxf(fmaxf(red[0][row], red[1][row]),
                         fmaxf(red[2][row], red[3][row]));
      float base = diag_s[row] + stab;
      float dsum = 0.f;
#pragma unroll
      for (int nt = 0; nt < 4; ++nt) {
        float p = RATIO * (__expf(acc[mt][nt][reg] - base) + EPSF);
        acc[mt][nt][reg] = p;
        dsum = fmaf(p, ksv[nt], dsum);
      }
      dsum += __shfl_xor(dsum, 1);
      dsum += __shfl_xor(dsum, 2);
      dsum += __shfl_xor(dsum, 4);
      dsum += __shfl_xor(dsum, 8);
      if (l16 == 0) dred[wid][row] = dsum;
#pragma unroll
      for (int nt = 0; nt < 4; ++nt)
        qp_s[row][wn0 + nt * 16 + l16] = f2h(acc[mt][nt][reg]);
    }
  __syncthreads();
  if (tid < 64)
    dinv_s[tid] = 1.0f / (dred[0][tid] + dred[1][tid] + dred[2][tid] + dred[3][tid]);

  /* PV: out[64 x wave's 16 d-cols] = qp[64x256] @ ctxT rows, K=256 */
  const int wn2 = wid * 16;
  f32x4 acc2[4];
#pragma unroll
  for (int mt = 0; mt < 4; ++mt) acc2[mt] = zf;
#pragma unroll
  for (int ksp = 0; ksp < 8; ++ksp) {
    fp16x8 bv = *(const fp16x8*)(ctxT_h + ((size_t)bh * DH + wn2 + l16) * MM + ksp * 32 + quad * 8);
    fp16x8 ap[4];
#pragma unroll
    for (int mt = 0; mt < 4; ++mt)
      ap[mt] = *(const fp16x8*)&qp_s[mt * 16 + l16][ksp * 32 + quad * 8];
#pragma unroll
    for (int mt = 0; mt < 4; ++mt)
      acc2[mt] = __builtin_amdgcn_mfma_f32_16x16x32_f16(ap[mt], bv, acc2[mt], 0, 0, 0);
  }
  __syncthreads();

  /* epilogue: scale by 1/dsum, store */
#pragma unroll
  for (int mt = 0; mt < 4; ++mt)
#pragma unroll
    for (int reg = 0; reg < 4; ++reg) {
      const int row = mt * 16 + quad * 4 + reg;
      Q[((size_t)(b * NN + n0 + row)) * DMM + h * DH + wn2 + l16] =
          acc2[mt][reg] * dinv_s[row];
    }
}

/* ---------------- launcher -------------------------------------------------- */
extern "C" void kernel_launch(void* const* d_in, const int* in_sizes, int n_in,
                              void* d_out, int out_size, void* d_ws, size_t ws_size,
                              hipStream_t stream)
{
  (void)in_sizes; (void)n_in; (void)out_size;
  const float* x    = (const float*)d_in[0];
  const float* Wq   = (const float*)d_in[2];
  const float* Wk   = (const float*)d_in[3];
  const float* Wv   = (const float*)d_in[4];
  const float* Wo   = (const float*)d_in[5];
  const float* bo   = (const float*)d_in[6];
  const float* proj = (const float*)d_in[7];
  float* out = (float*)d_out;

  const size_t WSZ = (size_t)DMM * DMM;
  const size_t XSP = (size_t)BB * NN * DMM;            /* elems per activation plane */
  const size_t wbuf_f = (8 * WSZ * 2 + 3) / 4;
  const size_t LSZ = (size_t)BB * LHH * NN * DH;       /* u16 elems per local buf */
  const size_t lbuf_f = (3 * LSZ * 2 + 3) / 4;
  const size_t fixed_f = (size_t)3 * XSP + (size_t)BB * GHH * MM * DH
                       + (size_t)BB * GHH * MM + 16 + MM * DH + MM * DH + 16
                       + wbuf_f + 16 + lbuf_f + 16;

  /* region: time-shared between ctxp/ksump (FAVOR phase) and xH/xL split
   * activation planes (GEMM phases) — live ranges are disjoint.            */
  int split = 8, use_pre = 0;
  for (int s = 32; s >= 8; s >>= 1) {
    size_t part = (size_t)BB * GHH * s * (MM * DH + MM);
    size_t region = part > XSP ? part : XSP;
    if ((fixed_f + region) * 4 <= ws_size) { split = s; use_pre = 1; break; }
  }
  if (!use_pre) {
    for (int s = 32; s >= 8; s >>= 1) {
      size_t need = (fixed_f + (size_t)BB * GHH * s * (MM * DH + MM)) * 4;
      if (need <= ws_size) { split = s; break; }
    }
  }
  size_t part_f = (size_t)BB * GHH * split * (MM * DH + MM);
  size_t region_f = (use_pre && XSP > part_f) ? XSP : part_f;

  float* Qb    = (float*)d_ws;
  float* Kb    = Qb + XSP;
  float* Vb    = Kb + XSP;
  float* region = Vb + XSP;
  float* ctxp  = region;
  float* ksump = ctxp + (size_t)BB * GHH * split * MM * DH;
  unsigned short* xH = (unsigned short*)region;
  unsigned short* xL = xH + XSP;
  float* ctx   = region + region_f;                 /* region holds ctxT fp16 */
  unsigned short* ctxT_h = (unsigned short*)ctx;
  float* ksum  = ctx + (size_t)BB * GHH * MM * DH;
  unsigned* stab = (unsigned*)(ksum + BB * GHH * MM);
  float* projT = (float*)(stab + 16);
  unsigned short* proj_hh = (unsigned short*)(projT + MM * DH);
  unsigned short* proj_hl = proj_hh + MM * DH;
  unsigned short* wsp = proj_hl + MM * DH;
  unsigned short* WqH = wsp;
  unsigned short* WkH = wsp + 2 * WSZ;
  unsigned short* WvH = wsp + 4 * WSZ;
  unsigned short* WoH = wsp + 6 * WSZ;
  unsigned short* Qlh = wsp + 8 * WSZ;
  unsigned short* Klh = Qlh + LSZ;
  unsigned short* Vtl = Klh + LSZ;

  dim3 blk(256);
  dim3 mg(DMM / 128, (BB * NN) / 128);
  const int wgrid = (int)(WSZ / 256);
  const int agrid = (int)(XSP / 1024);

  w_split<<<wgrid, blk, 0, stream>>>(Wq, WqH);
  w_split<<<wgrid, blk, 0, stream>>>(Wk, WkH);
  w_split<<<wgrid, blk, 0, stream>>>(Wv, WvH);
  w_split<<<wgrid, blk, 0, stream>>>(Wo, WoH);
  if (use_pre) {
    a_split<<<agrid, blk, 0, stream>>>(x, xH, xL);
    gemm_mfma_pre<<<mg, blk, 0, stream>>>(xH, xL, WqH, nullptr, Qb, DMM, DMM);
    gemm_mfma_pre<<<mg, blk, 0, stream>>>(xH, xL, WkH, nullptr, Kb, DMM, DMM);
    gemm_mfma_pre<<<mg, blk, 0, stream>>>(xH, xL, WvH, nullptr, Vb, DMM, DMM);
  } else {
    gemm_mfma<<<mg, blk, 0, stream>>>(x, WqH, nullptr, Qb, DMM, DMM);
    gemm_mfma<<<mg, blk, 0, stream>>>(x, WkH, nullptr, Kb, DMM, DMM);
    gemm_mfma<<<mg, blk, 0, stream>>>(x, WvH, nullptr, Vb, DMM, DMM);
  }
  rot_qk<<<(BB * LHH * NN) / 256, blk, 0, stream>>>(Qb, Kb, Qlh, Klh);
  v_trans<<<dim3(NN / 64, LHH, BB), blk, 0, stream>>>(Vb, Vtl);
  init_stab<<<1, 64, 0, stream>>>(stab);
  transpose_proj<<<64, blk, 0, stream>>>(proj, projT, proj_hh, proj_hl);
  favor_kstab_mfma<<<BB * GHH * (NN / 64), blk, 0, stream>>>(Kb, proj_hh, proj_hl, stab);
  favor_ctx_mfma<<<BB * GHH * split, blk, 0, stream>>>(Kb, Vb, proj_hh, proj_hl, stab, ctxp, ksump, split);
  favor_reduce<<<(BB * GHH * MM * DH) / 256, blk, 0, stream>>>(ctxp, ksump, ctxT_h, ksum, split);
  favor_out_mfma<<<BB * GHH * (NN / 64), blk, 0, stream>>>(Qb, proj_hh, proj_hl, ctxT_h, ksum);
  local_attn2<<<dim3(NWIN, LHH, BB), blk, 0, stream>>>(Qlh, Klh, Vtl, Qb);
  if (use_pre) {
    a_split<<<agrid, blk, 0, stream>>>(Qb, xH, xL);
    gemm_mfma_pre<<<mg, blk, 0, stream>>>(xH, xL, WoH, bo, out, DMM, DMM);
  } else {
    gemm_mfma<<<mg, blk, 0, stream>>>(Qb, WoH, bo, out, DMM, DMM);
  }
}